// Round 1
// baseline (3393.248 us; speedup 1.0000x reference)
//
#include <hip/hip_runtime.h>
#include <math.h>

#define TSEQ   2048
#define DIMM   512
#define NHEAD  8
#define DHD    64
#define BHD    16      // BATCH*HEADS
#define NHASHK 4
#define CHUNKS 128     // NHASHK * (TSEQ/64)
#define FFD    2048
#define NROWS  4096    // BATCH*TSEQ

// ---------------- embed ----------------
__global__ __launch_bounds__(128) void k_embed(const int* __restrict__ x, const float* __restrict__ emb,
                                               float* __restrict__ x1, float* __restrict__ x2) {
  int row = blockIdx.x;
  int tok = x[row];
  float4 v = ((const float4*)(emb + (size_t)tok * DIMM))[threadIdx.x];
  ((float4*)(x1 + (size_t)row * DIMM))[threadIdx.x] = v;
  ((float4*)(x2 + (size_t)row * DIMM))[threadIdx.x] = v;
}

// ---------------- sin/cos tables ----------------
__global__ __launch_bounds__(256) void k_sincos(float* __restrict__ sin_t, float* __restrict__ cos_t) {
  int idx = blockIdx.x * 256 + threadIdx.x;   // TSEQ*32
  int t = idx >> 5, i = idx & 31;
  float inv = powf(10000.0f, -(float)(2 * i) / 64.0f);
  float ang = (float)t * inv;
  sin_t[idx] = sinf(ang);
  cos_t[idx] = cosf(ang);
}

// ---------------- layernorm (row = 512) ----------------
__global__ __launch_bounds__(256) void k_layernorm(const float* __restrict__ x, const float* __restrict__ g,
                                                   const float* __restrict__ b, float* __restrict__ dst) {
  int row = blockIdx.x, tid = threadIdx.x;
  const float* xr = x + (size_t)row * DIMM;
  float v0 = xr[tid], v1 = xr[tid + 256];
  int lane = tid & 63, w = tid >> 6;
  __shared__ float red[8];
  float s = v0 + v1;
#pragma unroll
  for (int o = 32; o; o >>= 1) s += __shfl_xor(s, o);
  if (lane == 0) red[w] = s;
  __syncthreads();
  float mu = (red[0] + red[1] + red[2] + red[3]) * (1.0f / DIMM);
  float d0 = v0 - mu, d1 = v1 - mu;
  float q = d0 * d0 + d1 * d1;
#pragma unroll
  for (int o = 32; o; o >>= 1) q += __shfl_xor(q, o);
  if (lane == 0) red[4 + w] = q;
  __syncthreads();
  float var = (red[4] + red[5] + red[6] + red[7]) * (1.0f / DIMM);
  float rstd = 1.0f / sqrtf(var + 1e-5f);
  dst[(size_t)row * DIMM + tid] = d0 * rstd * g[tid] + b[tid];
  dst[(size_t)row * DIMM + tid + 256] = d1 * rstd * g[tid + 256] + b[tid + 256];
}

__device__ inline float gelu_exact(float v) {
  return 0.5f * v * (1.0f + erff(v * 0.70710678118654752f));
}

// ---------------- generic fp32 GEMM, 64x64 tile, BK=16 ----------------
// STORE: 0 plain (+bias,+act), 1 residual-add into out (+bias), 2 head-major + rotary (qk), 3 head-major (v)
template <int STORE, int ACT>
__global__ __launch_bounds__(256) void k_gemm(const float* __restrict__ A, const float* __restrict__ W,
                                              const float* __restrict__ bias, float* __restrict__ out,
                                              int K, int N,
                                              const float* __restrict__ sin_t, const float* __restrict__ cos_t) {
  __shared__ float As[16][68];   // [k][m]
  __shared__ float Bs[16][68];   // [k][n]
  int bm = blockIdx.x << 6, bn = blockIdx.y << 6;
  int tid = threadIdx.x;
  int tx = tid & 15, ty = tid >> 4;
  int ra = tid >> 2, ka = (tid & 3) << 2;
  int kb = tid >> 4, nb2 = (tid & 15) << 2;
  float acc[4][4] = {};
  for (int k0 = 0; k0 < K; k0 += 16) {
    float4 a4 = *(const float4*)&A[(size_t)(bm + ra) * K + k0 + ka];
    float4 b4 = *(const float4*)&W[(size_t)(k0 + kb) * N + bn + nb2];
    As[ka + 0][ra] = a4.x; As[ka + 1][ra] = a4.y; As[ka + 2][ra] = a4.z; As[ka + 3][ra] = a4.w;
    *(float4*)&Bs[kb][nb2] = b4;
    __syncthreads();
#pragma unroll
    for (int k = 0; k < 16; ++k) {
      float4 av = *(const float4*)&As[k][ty << 2];
      float4 bv = *(const float4*)&Bs[k][tx << 2];
      acc[0][0] += av.x * bv.x; acc[0][1] += av.x * bv.y; acc[0][2] += av.x * bv.z; acc[0][3] += av.x * bv.w;
      acc[1][0] += av.y * bv.x; acc[1][1] += av.y * bv.y; acc[1][2] += av.y * bv.z; acc[1][3] += av.y * bv.w;
      acc[2][0] += av.z * bv.x; acc[2][1] += av.z * bv.y; acc[2][2] += av.z * bv.z; acc[2][3] += av.z * bv.w;
      acc[3][0] += av.w * bv.x; acc[3][1] += av.w * bv.y; acc[3][2] += av.w * bv.z; acc[3][3] += av.w * bv.w;
    }
    __syncthreads();
  }
  int gn0 = bn + (tx << 2);
#pragma unroll
  for (int i = 0; i < 4; ++i) {
    int gm = bm + (ty << 2) + i;
    float v0 = acc[i][0], v1 = acc[i][1], v2 = acc[i][2], v3 = acc[i][3];
    if (STORE == 0 || STORE == 1) {
      if (bias) { v0 += bias[gn0]; v1 += bias[gn0 + 1]; v2 += bias[gn0 + 2]; v3 += bias[gn0 + 3]; }
      if (ACT == 1) { v0 = gelu_exact(v0); v1 = gelu_exact(v1); v2 = gelu_exact(v2); v3 = gelu_exact(v3); }
      float4* dst = (float4*)&out[(size_t)gm * N + gn0];
      if (STORE == 1) { float4 o = *dst; v0 += o.x; v1 += o.y; v2 += o.z; v3 += o.w; }
      *dst = make_float4(v0, v1, v2, v3);
    } else {
      int bb = gm >> 11, tt = gm & (TSEQ - 1);
      int hh = gn0 >> 6, d0 = gn0 & 63;
      float* dst = out + ((size_t)((bb * NHEAD + hh) * TSEQ + tt)) * DHD + d0;
      if (STORE == 2) {
        int ip = d0 >> 1;
        float c0 = cos_t[tt * 32 + ip],     s0 = sin_t[tt * 32 + ip];
        float c1 = cos_t[tt * 32 + ip + 1], s1 = sin_t[tt * 32 + ip + 1];
        float o0 = v0 * c0 - v1 * s0;
        float o1 = v1 * c0 + v0 * s0;
        float o2 = v2 * c1 - v3 * s1;
        float o3 = v3 * c1 + v2 * s1;
        *(float4*)dst = make_float4(o0, o1, o2, o3);
      } else {
        *(float4*)dst = make_float4(v0, v1, v2, v3);
      }
    }
  }
}

// ---------------- LSH bucket ----------------
__global__ __launch_bounds__(256) void k_bucket(const float* __restrict__ qk, const float* __restrict__ rot,
                                                int* __restrict__ bucket) {
  int idx = blockIdx.x * 256 + threadIdx.x;   // bh*8192 + h*2048 + t
  int t = idx & (TSEQ - 1);
  int h = (idx >> 11) & 3;
  int bh = idx >> 13;
  const float* q = qk + ((size_t)bh * TSEQ + t) * DHD;
  float acc[16];
#pragma unroll
  for (int j = 0; j < 16; ++j) acc[j] = 0.0f;
  for (int d = 0; d < 64; ++d) {
    float qv = q[d];
    const float* rp = rot + d * 64 + h * 16;
#pragma unroll
    for (int j = 0; j < 16; ++j) acc[j] += qv * rp[j];
  }
  float best = acc[0]; int bi = 0;
#pragma unroll
  for (int j = 1; j < 16; ++j) if (acc[j] > best) { best = acc[j]; bi = j; }
#pragma unroll
  for (int j = 0; j < 16; ++j) { float nv = -acc[j]; if (nv > best) { best = nv; bi = 16 + j; } }
  bucket[idx] = bi;
}

// ---------------- stable counting sort per (bh,h): 32 buckets, 2048 items ----------------
__global__ __launch_bounds__(64) void k_sort(const int* __restrict__ bucket, int* __restrict__ st) {
  int seg = blockIdx.x;                 // bh*4 + h
  const int* bk = bucket + (size_t)seg * TSEQ;
  int lane = threadIdx.x;
  __shared__ int cnt[32];
  __shared__ int off[32];
  if (lane < 32) {
    int c = 0;
    for (int t = 0; t < TSEQ; ++t) c += (bk[t] == lane);
    cnt[lane] = c;
  }
  __syncthreads();
  if (lane == 0) {
    int s = 0;
    for (int j = 0; j < 32; ++j) { off[j] = s; s += cnt[j]; }
  }
  __syncthreads();
  if (lane < 32) {
    int pos = off[lane];
    int* dst = st + (size_t)seg * TSEQ;
    for (int t = 0; t < TSEQ; ++t)
      if (bk[t] == lane) dst[pos++] = t;
  }
}

// ---------------- chunked LSH attention ----------------
__global__ __launch_bounds__(256) void k_attn(const float* __restrict__ qk, const float* __restrict__ v,
                                              const int* __restrict__ st, float* __restrict__ o4,
                                              float* __restrict__ lg) {
  __shared__ float raw[128][68];
  __shared__ float vv[128][68];
  __shared__ float inv_norm[128];
  __shared__ int tids[128];
  __shared__ float prow4[4][4][128];
  int blk = blockIdx.x;
  int c = blk & (CHUNKS - 1), bh = blk >> 7;
  int h = c >> 5;
  int tid = threadIdx.x, lane = tid & 63, w = tid >> 6;
  if (tid < 128) {
    int cc = (tid < 64) ? c : ((c + CHUNKS - 1) & (CHUNKS - 1));  // rows 0..63 current chunk, 64..127 prev
    tids[tid] = st[(size_t)bh * (NHASHK * TSEQ) + cc * 64 + (tid & 63)];
  }
  __syncthreads();
  const float* qbase = qk + (size_t)bh * TSEQ * DHD;
  const float* vbase = v + (size_t)bh * TSEQ * DHD;
  for (int e = tid; e < 128 * 16; e += 256) {
    int r = e >> 4, d4 = e & 15;
    int t = tids[r];
    float4 a = ((const float4*)(qbase + (size_t)t * DHD))[d4];
    float4 b = ((const float4*)(vbase + (size_t)t * DHD))[d4];
    *(float4*)&raw[r][d4 << 2] = a;
    *(float4*)&vv[r][d4 << 2] = b;
  }
  __syncthreads();
  for (int rr = 0; rr < 32; ++rr) {
    int r = (w << 5) + rr;
    float xv = raw[r][lane];
    float ss = xv * xv;
#pragma unroll
    for (int o = 32; o; o >>= 1) ss += __shfl_xor(ss, o);
    if (lane == 0) inv_norm[r] = 1.0f / fmaxf(sqrtf(ss), 1e-12f);
  }
  __syncthreads();
  int tk0 = tids[lane], tk1 = tids[64 + lane];
  float in0 = inv_norm[lane] * 0.125f, in1 = inv_norm[64 + lane] * 0.125f;
  size_t obase = (size_t)(bh * NHASHK + h) * TSEQ;
  for (int qg = 0; qg < 4; ++qg) {
    float acc[4][2] = {};
#pragma unroll 4
    for (int d4 = 0; d4 < 16; ++d4) {
      float4 k0 = *(const float4*)&raw[lane][d4 << 2];
      float4 k1 = *(const float4*)&raw[64 + lane][d4 << 2];
#pragma unroll
      for (int qi = 0; qi < 4; ++qi) {
        int i = (w << 4) + (qg << 2) + qi;
        float4 a = *(const float4*)&raw[i][d4 << 2];
        acc[qi][0] += a.x * k0.x + a.y * k0.y + a.z * k0.z + a.w * k0.w;
        acc[qi][1] += a.x * k1.x + a.y * k1.y + a.z * k1.z + a.w * k1.w;
      }
    }
#pragma unroll
    for (int qi = 0; qi < 4; ++qi) {
      int i = (w << 4) + (qg << 2) + qi;
      int tq = tids[i];
      float d0 = acc[qi][0] * in0;
      float d1 = acc[qi][1] * in1;
      if (tq == tk0) d0 = -5e4f;
      if (tq == tk1) d1 = -5e4f;
      float m = fmaxf(d0, d1);
#pragma unroll
      for (int o = 32; o; o >>= 1) m = fmaxf(m, __shfl_xor(m, o));
      float sum = expf(d0 - m) + expf(d1 - m);
#pragma unroll
      for (int o = 32; o; o >>= 1) sum += __shfl_xor(sum, o);
      float lse = logf(sum) + m;
      prow4[w][qi][lane] = expf(d0 - lse);
      prow4[w][qi][64 + lane] = expf(d1 - lse);
      if (lane == 0) lg[obase + tq] = lse;
    }
    // PV: lane = output dim
    float ov0 = 0, ov1 = 0, ov2 = 0, ov3 = 0;
    for (int j = 0; j < 128; ++j) {
      float vj = vv[j][lane];
      ov0 += prow4[w][0][j] * vj;
      ov1 += prow4[w][1][j] * vj;
      ov2 += prow4[w][2][j] * vj;
      ov3 += prow4[w][3][j] * vj;
    }
    float ovs[4] = {ov0, ov1, ov2, ov3};
#pragma unroll
    for (int qi = 0; qi < 4; ++qi) {
      int i = (w << 4) + (qg << 2) + qi;
      int tq = tids[i];
      o4[(obase + tq) * DHD + lane] = ovs[qi];
    }
  }
}

// ---------------- combine hash rounds -> ctx [B,T,512] ----------------
__global__ __launch_bounds__(256) void k_combine(const float* __restrict__ o4, const float* __restrict__ lg,
                                                 float* __restrict__ ctx) {
  int tok = blockIdx.x * 4 + (threadIdx.x >> 6);   // over BHD*TSEQ
  int dd = threadIdx.x & 63;
  int bh = tok >> 11, t = tok & (TSEQ - 1);
  size_t base = (size_t)bh * NHASHK * TSEQ + t;
  float l0 = lg[base], l1 = lg[base + TSEQ], l2 = lg[base + 2 * TSEQ], l3 = lg[base + 3 * TSEQ];
  float m = fmaxf(fmaxf(l0, l1), fmaxf(l2, l3));
  float e0 = expf(l0 - m), e1 = expf(l1 - m), e2 = expf(l2 - m), e3 = expf(l3 - m);
  float inv = 1.0f / (e0 + e1 + e2 + e3);
  float o = (e0 * o4[base * 64 + dd] + e1 * o4[(base + TSEQ) * 64 + dd] +
             e2 * o4[(base + 2 * TSEQ) * 64 + dd] + e3 * o4[(base + 3 * TSEQ) * 64 + dd]) * inv;
  int b = bh >> 3, hh = bh & 7;
  ctx[((size_t)(b * TSEQ + t)) * DIMM + hh * DHD + dd] = o;
}

// ---------------- final LN stats on (x1+x2)/2 ----------------
__global__ __launch_bounds__(256) void k_final_stats(const float* __restrict__ x1, const float* __restrict__ x2,
                                                     float2* __restrict__ stats) {
  int row = blockIdx.x, tid = threadIdx.x;
  const float* p1 = x1 + (size_t)row * DIMM;
  const float* p2 = x2 + (size_t)row * DIMM;
  float v0 = 0.5f * (p1[tid] + p2[tid]);
  float v1 = 0.5f * (p1[tid + 256] + p2[tid + 256]);
  int lane = tid & 63, w = tid >> 6;
  __shared__ float red[8];
  float s = v0 + v1;
#pragma unroll
  for (int o = 32; o; o >>= 1) s += __shfl_xor(s, o);
  if (lane == 0) red[w] = s;
  __syncthreads();
  float mu = (red[0] + red[1] + red[2] + red[3]) * (1.0f / DIMM);
  float d0 = v0 - mu, d1 = v1 - mu;
  float q = d0 * d0 + d1 * d1;
#pragma unroll
  for (int o = 32; o; o >>= 1) q += __shfl_xor(q, o);
  if (lane == 0) red[4 + w] = q;
  __syncthreads();
  if (tid == 0) {
    float var = (red[4] + red[5] + red[6] + red[7]) * (1.0f / DIMM);
    stats[row] = make_float2(mu, 1.0f / sqrtf(var + 1e-5f));
  }
}

// ---------------- LN + mean over T -> hm[2][512] ----------------
__global__ __launch_bounds__(256) void k_colmean(const float* __restrict__ x1, const float* __restrict__ x2,
                                                 const float2* __restrict__ stats,
                                                 const float* __restrict__ g, const float* __restrict__ b,
                                                 float* __restrict__ hm) {
  int idx = blockIdx.x * 256 + threadIdx.x;   // 1024
  int bb = idx >> 9, d = idx & 511;
  float gd = g[d], bd = b[d];
  float acc = 0;
  for (int t = 0; t < TSEQ; ++t) {
    int row = bb * TSEQ + t;
    float2 sr = stats[row];
    float a = 0.5f * (x1[(size_t)row * DIMM + d] + x2[(size_t)row * DIMM + d]);
    acc += (a - sr.x) * sr.y * gd + bd;
  }
  hm[idx] = acc * (1.0f / TSEQ);
}

// ---------------- head ----------------
__global__ __launch_bounds__(256) void k_head1(const float* __restrict__ hm, const float* __restrict__ Wf1,
                                               const float* __restrict__ bf1, float* __restrict__ r1) {
  int b = blockIdx.x, j = threadIdx.x;   // 2 x 256
  float acc = 0;
  for (int k = 0; k < DIMM; ++k) acc += hm[b * DIMM + k] * Wf1[k * 256 + j];
  r1[b * 256 + j] = fmaxf(acc + bf1[j], 0.0f);
}

__global__ __launch_bounds__(256) void k_head2(const float* __restrict__ r1, const float* __restrict__ Wout,
                                               const float* __restrict__ bout, float* __restrict__ outp) {
  int b = blockIdx.x;
  int tid = threadIdx.x, lane = tid & 63, w = tid >> 6;
  float v = r1[b * 256 + tid] * Wout[tid];
#pragma unroll
  for (int o = 32; o; o >>= 1) v += __shfl_xor(v, o);
  __shared__ float red[4];
  if (lane == 0) red[w] = v;
  __syncthreads();
  if (tid == 0) outp[b] = red[0] + red[1] + red[2] + red[3] + bout[0];
}

extern "C" void kernel_launch(void* const* d_in, const int* in_sizes, int n_in,
                              void* d_out, int out_size, void* d_ws, size_t ws_size,
                              hipStream_t stream) {
  const int*   x         = (const int*)d_in[0];
  const float* token_emb = (const float*)d_in[1];
  const float* ln1_s     = (const float*)d_in[2];
  const float* ln1_b     = (const float*)d_in[3];
  const float* Wqk       = (const float*)d_in[4];
  const float* Wv        = (const float*)d_in[5];
  const float* Wo        = (const float*)d_in[6];
  const float* bo        = (const float*)d_in[7];
  const float* ln2_s     = (const float*)d_in[8];
  const float* ln2_b     = (const float*)d_in[9];
  const float* W1        = (const float*)d_in[10];
  const float* b1        = (const float*)d_in[11];
  const float* W2        = (const float*)d_in[12];
  const float* b2        = (const float*)d_in[13];
  const float* rotations = (const float*)d_in[14];
  const float* lnf_s     = (const float*)d_in[15];
  const float* lnf_b     = (const float*)d_in[16];
  const float* Wf1       = (const float*)d_in[17];
  const float* bf1       = (const float*)d_in[18];
  const float* Wout      = (const float*)d_in[19];
  const float* bout      = (const float*)d_in[20];
  float* out = (float*)d_out;

  char* ws = (char*)d_ws;
  size_t off = 0;
  auto alloc = [&](size_t nbytes) {
    char* p = ws + off;
    off += (nbytes + 255) & ~(size_t)255;
    return p;
  };
  float*  x1    = (float*)alloc((size_t)NROWS * DIMM * 4);
  float*  x2    = (float*)alloc((size_t)NROWS * DIMM * 4);
  float*  xn    = (float*)alloc((size_t)NROWS * DIMM * 4);
  float*  ctx   = xn;   // alias: lifetimes disjoint
  float*  qk    = (float*)alloc((size_t)BHD * TSEQ * DHD * 4);
  float*  vbuf  = (float*)alloc((size_t)BHD * TSEQ * DHD * 4);
  float*  ffh   = (float*)alloc((size_t)NROWS * FFD * 4);
  float*  o4    = ffh;  // alias: lifetimes disjoint (same size)
  float*  lg    = (float*)alloc((size_t)BHD * NHASHK * TSEQ * 4);
  float*  sin_t = (float*)alloc((size_t)TSEQ * 32 * 4);
  float*  cos_t = (float*)alloc((size_t)TSEQ * 32 * 4);
  float2* stats = (float2*)alloc((size_t)NROWS * 8);
  float*  hm    = (float*)alloc(2 * DIMM * 4);
  float*  r1    = (float*)alloc(2 * 256 * 4);
  int*    bucket= (int*)alloc((size_t)BHD * NHASHK * TSEQ * 4);
  int*    st    = (int*)alloc((size_t)BHD * NHASHK * TSEQ * 4);

  k_embed<<<NROWS, 128, 0, stream>>>(x, token_emb, x1, x2);
  k_sincos<<<(TSEQ * 32) / 256, 256, 0, stream>>>(sin_t, cos_t);

  for (int L = 0; L < 4; ++L) {
    const float* wqk = Wqk + (size_t)L * DIMM * DIMM;
    const float* wv  = Wv  + (size_t)L * DIMM * DIMM;
    const float* wo  = Wo  + (size_t)L * DIMM * DIMM;
    const float* w1  = W1  + (size_t)L * DIMM * FFD;
    const float* w2  = W2  + (size_t)L * FFD * DIMM;
    const float* rot = rotations + (size_t)L * DHD * NHASHK * 16;

    k_layernorm<<<NROWS, 256, 0, stream>>>(x2, ln1_s + L * DIMM, ln1_b + L * DIMM, xn);
    dim3 gsq(NROWS / 64, DIMM / 64);
    k_gemm<2, 0><<<gsq, 256, 0, stream>>>(xn, wqk, nullptr, qk, DIMM, DIMM, sin_t, cos_t);
    k_gemm<3, 0><<<gsq, 256, 0, stream>>>(xn, wv, nullptr, vbuf, DIMM, DIMM, nullptr, nullptr);
    k_bucket<<<(BHD * NHASHK * TSEQ) / 256, 256, 0, stream>>>(qk, rot, bucket);
    k_sort<<<BHD * NHASHK, 64, 0, stream>>>(bucket, st);
    k_attn<<<BHD * CHUNKS, 256, 0, stream>>>(qk, vbuf, st, o4, lg);
    k_combine<<<(BHD * TSEQ) / 4, 256, 0, stream>>>(o4, lg, ctx);
    k_gemm<1, 0><<<gsq, 256, 0, stream>>>(ctx, wo, bo + L * DIMM, x1, DIMM, DIMM, nullptr, nullptr);
    k_layernorm<<<NROWS, 256, 0, stream>>>(x1, ln2_s + L * DIMM, ln2_b + L * DIMM, xn);
    dim3 gff1(NROWS / 64, FFD / 64);
    k_gemm<0, 1><<<gff1, 256, 0, stream>>>(xn, w1, b1 + L * FFD, ffh, DIMM, FFD, nullptr, nullptr);
    dim3 gff2(NROWS / 64, DIMM / 64);
    k_gemm<1, 0><<<gff2, 256, 0, stream>>>(ffh, w2, b2 + L * DIMM, x2, FFD, DIMM, nullptr, nullptr);
  }

  k_final_stats<<<NROWS, 256, 0, stream>>>(x1, x2, stats);
  k_colmean<<<4, 256, 0, stream>>>(x1, x2, stats, lnf_s, lnf_b, hm);
  k_head1<<<2, 256, 0, stream>>>(hm, Wf1, bf1, r1);
  k_head2<<<2, 256, 0, stream>>>(r1, Wout, bout, out);
}

// Round 2
// 2296.810 us; speedup vs baseline: 1.4774x; 1.4774x over previous
//
#include <hip/hip_runtime.h>
#include <math.h>

#define TSEQ   2048
#define DIMM   512
#define NHEAD  8
#define DHD    64
#define BHD    16      // BATCH*HEADS
#define NHASHK 4
#define CHUNKS 128     // NHASHK * (TSEQ/64)
#define FFD    2048
#define NROWS  4096    // BATCH*TSEQ

typedef unsigned short u16;
typedef __attribute__((ext_vector_type(8))) short bf16x8;
typedef __attribute__((ext_vector_type(4))) float f32x4;
typedef __attribute__((ext_vector_type(8))) unsigned short ushort8v;
typedef __attribute__((ext_vector_type(4))) unsigned short ushort4v;

__device__ inline u16 bf16_hi(float f) {
  unsigned u = __float_as_uint(f);
  unsigned r = u + 0x7fffu + ((u >> 16) & 1u);
  return (u16)(r >> 16);
}
__device__ inline void split_bf16(float f, u16& h, u16& l) {
  h = bf16_hi(f);
  float fh = __uint_as_float(((unsigned)h) << 16);
  l = bf16_hi(f - fh);
}

// ---------------- embed ----------------
__global__ __launch_bounds__(128) void k_embed(const int* __restrict__ x, const float* __restrict__ emb,
                                               float* __restrict__ x1, float* __restrict__ x2) {
  int row = blockIdx.x;
  int tok = x[row];
  float4 v = ((const float4*)(emb + (size_t)tok * DIMM))[threadIdx.x];
  ((float4*)(x1 + (size_t)row * DIMM))[threadIdx.x] = v;
  ((float4*)(x2 + (size_t)row * DIMM))[threadIdx.x] = v;
}

// ---------------- sin/cos tables ----------------
__global__ __launch_bounds__(256) void k_sincos(float* __restrict__ sin_t, float* __restrict__ cos_t) {
  int idx = blockIdx.x * 256 + threadIdx.x;   // TSEQ*32
  int t = idx >> 5, i = idx & 31;
  float inv = powf(10000.0f, -(float)(2 * i) / 64.0f);
  float ang = (float)t * inv;
  sin_t[idx] = sinf(ang);
  cos_t[idx] = cosf(ang);
}

// ---------------- layernorm (row = 512) -> bf16 hi/lo ----------------
__global__ __launch_bounds__(256) void k_layernorm(const float* __restrict__ x, const float* __restrict__ g,
                                                   const float* __restrict__ b,
                                                   u16* __restrict__ hi, u16* __restrict__ lo) {
  int row = blockIdx.x, tid = threadIdx.x;
  const float* xr = x + (size_t)row * DIMM;
  float v0 = xr[tid], v1 = xr[tid + 256];
  int lane = tid & 63, w = tid >> 6;
  __shared__ float red[8];
  float s = v0 + v1;
#pragma unroll
  for (int o = 32; o; o >>= 1) s += __shfl_xor(s, o);
  if (lane == 0) red[w] = s;
  __syncthreads();
  float mu = (red[0] + red[1] + red[2] + red[3]) * (1.0f / DIMM);
  float d0 = v0 - mu, d1 = v1 - mu;
  float q = d0 * d0 + d1 * d1;
#pragma unroll
  for (int o = 32; o; o >>= 1) q += __shfl_xor(q, o);
  if (lane == 0) red[4 + w] = q;
  __syncthreads();
  float var = (red[4] + red[5] + red[6] + red[7]) * (1.0f / DIMM);
  float rstd = 1.0f / sqrtf(var + 1e-5f);
  float y0 = d0 * rstd * g[tid] + b[tid];
  float y1 = d1 * rstd * g[tid + 256] + b[tid + 256];
  u16 h0, l0, h1, l1;
  split_bf16(y0, h0, l0);
  split_bf16(y1, h1, l1);
  size_t base = (size_t)row * DIMM;
  hi[base + tid] = h0; lo[base + tid] = l0;
  hi[base + tid + 256] = h1; lo[base + tid + 256] = l1;
}

// ---------------- weight transpose + bf16 split: W[K][N] -> T[N][K] hi/lo ----------------
__global__ __launch_bounds__(256) void k_tsplit(const float* __restrict__ W,
                                                u16* __restrict__ Thi, u16* __restrict__ Tlo,
                                                int K, int N) {
  __shared__ float tile[32][33];
  const int k0 = blockIdx.x << 5, n0 = blockIdx.y << 5;
  const int t = threadIdx.x;
  const int r = t >> 3, c4 = (t & 7) << 2;
  float4 v = *(const float4*)&W[(size_t)(k0 + r) * N + n0 + c4];
  tile[r][c4] = v.x; tile[r][c4 + 1] = v.y; tile[r][c4 + 2] = v.z; tile[r][c4 + 3] = v.w;
  __syncthreads();
  u16 hs[4], ls[4];
#pragma unroll
  for (int i = 0; i < 4; ++i) split_bf16(tile[c4 + i][r], hs[i], ls[i]);
  size_t o = (size_t)(n0 + r) * K + k0 + c4;
  *(ushort4v*)&Thi[o] = (ushort4v){hs[0], hs[1], hs[2], hs[3]};
  *(ushort4v*)&Tlo[o] = (ushort4v){ls[0], ls[1], ls[2], ls[3]};
}

// ---------------- split-bf16 MFMA GEMM: C = A[M][K] * B^T (Bt[N][K]) ----------------
// STORE: 1 = out[g] += val + bias; 2 = head-major + rotary (qk); 3 = head-major (v);
//        4 = gelu(val+bias) -> bf16 hi/lo split store
template <int BN, int STORE>
__global__ __launch_bounds__(256) void k_gemm_mfma(
    const u16* __restrict__ Ahi, const u16* __restrict__ Alo,
    const u16* __restrict__ Bhi, const u16* __restrict__ Blo,
    const float* __restrict__ bias, float* __restrict__ out,
    u16* __restrict__ out_hi, u16* __restrict__ out_lo,
    int K, int N,
    const float* __restrict__ sin_t, const float* __restrict__ cos_t) {
  constexpr int NF = BN / 32;             // n-frags per wave
  __shared__ __align__(16) u16 As_hi[128][40];
  __shared__ __align__(16) u16 As_lo[128][40];
  __shared__ __align__(16) u16 Bs_hi[BN][40];
  __shared__ __align__(16) u16 Bs_lo[BN][40];
  const int bm = blockIdx.x << 7;
  const int bn = blockIdx.y * BN;
  const int tid = threadIdx.x, lane = tid & 63, wid = tid >> 6;
  const int wm = (wid >> 1) << 6;         // 0 or 64
  const int wn = (wid & 1) * (BN >> 1);   // 0 or BN/2
  const int l16 = lane & 15, lg16 = lane >> 4;
  f32x4 acc[4][NF];
#pragma unroll
  for (int m = 0; m < 4; ++m)
#pragma unroll
    for (int n = 0; n < NF; ++n) acc[m][n] = (f32x4){0.f, 0.f, 0.f, 0.f};

  const int ar = tid >> 1, ac = (tid & 1) << 4;
  const size_t aoff = (size_t)(bm + ar) * K + ac;
  int br, bc;
  if constexpr (BN == 128) { br = tid >> 1; bc = (tid & 1) << 4; }
  else                     { br = tid >> 2; bc = (tid & 3) << 3; }
  const size_t boff = (size_t)(bn + br) * K + bc;

  for (int k0 = 0; k0 < K; k0 += 32) {
    ushort8v a_h0 = *(const ushort8v*)(Ahi + aoff + k0);
    ushort8v a_h1 = *(const ushort8v*)(Ahi + aoff + k0 + 8);
    ushort8v a_l0 = *(const ushort8v*)(Alo + aoff + k0);
    ushort8v a_l1 = *(const ushort8v*)(Alo + aoff + k0 + 8);
    ushort8v b_h0 = *(const ushort8v*)(Bhi + boff + k0);
    ushort8v b_l0 = *(const ushort8v*)(Blo + boff + k0);
    ushort8v b_h1{}, b_l1{};
    if constexpr (BN == 128) {
      b_h1 = *(const ushort8v*)(Bhi + boff + k0 + 8);
      b_l1 = *(const ushort8v*)(Blo + boff + k0 + 8);
    }
    __syncthreads();
    *(ushort8v*)&As_hi[ar][ac] = a_h0;
    *(ushort8v*)&As_hi[ar][ac + 8] = a_h1;
    *(ushort8v*)&As_lo[ar][ac] = a_l0;
    *(ushort8v*)&As_lo[ar][ac + 8] = a_l1;
    if constexpr (BN == 128) {
      *(ushort8v*)&Bs_hi[br][bc] = b_h0;
      *(ushort8v*)&Bs_hi[br][bc + 8] = b_h1;
      *(ushort8v*)&Bs_lo[br][bc] = b_l0;
      *(ushort8v*)&Bs_lo[br][bc + 8] = b_l1;
    } else {
      *(ushort8v*)&Bs_hi[br][bc] = b_h0;
      *(ushort8v*)&Bs_lo[br][bc] = b_l0;
    }
    __syncthreads();
    bf16x8 ah[4], al[4], bh[NF], bl[NF];
#pragma unroll
    for (int m = 0; m < 4; ++m) {
      ah[m] = *(const bf16x8*)&As_hi[wm + (m << 4) + l16][lg16 << 3];
      al[m] = *(const bf16x8*)&As_lo[wm + (m << 4) + l16][lg16 << 3];
    }
#pragma unroll
    for (int n = 0; n < NF; ++n) {
      bh[n] = *(const bf16x8*)&Bs_hi[wn + (n << 4) + l16][lg16 << 3];
      bl[n] = *(const bf16x8*)&Bs_lo[wn + (n << 4) + l16][lg16 << 3];
    }
#pragma unroll
    for (int m = 0; m < 4; ++m)
#pragma unroll
      for (int n = 0; n < NF; ++n) {
        acc[m][n] = __builtin_amdgcn_mfma_f32_16x16x32_bf16(ah[m], bh[n], acc[m][n], 0, 0, 0);
        acc[m][n] = __builtin_amdgcn_mfma_f32_16x16x32_bf16(ah[m], bl[n], acc[m][n], 0, 0, 0);
        acc[m][n] = __builtin_amdgcn_mfma_f32_16x16x32_bf16(al[m], bh[n], acc[m][n], 0, 0, 0);
      }
  }
  // epilogue (C/D layout: col = lane&15, row = (lane>>4)*4 + reg)
#pragma unroll
  for (int m = 0; m < 4; ++m) {
#pragma unroll
    for (int n = 0; n < NF; ++n) {
      const int gn = bn + wn + (n << 4) + l16;
      float bv = 0.f;
      if (STORE == 1 || STORE == 4) bv = bias[gn];
#pragma unroll
      for (int r = 0; r < 4; ++r) {
        const int gm = bm + wm + (m << 4) + (lg16 << 2) + r;
        float val = acc[m][n][r];
        if (STORE == 1) {
          out[(size_t)gm * N + gn] += val + bv;
        } else if (STORE == 4) {
          float gv = val + bv;
          gv = 0.5f * gv * (1.0f + erff(gv * 0.70710678118654752f));
          u16 h, l;
          split_bf16(gv, h, l);
          out_hi[(size_t)gm * N + gn] = h;
          out_lo[(size_t)gm * N + gn] = l;
        } else {
          const int bb = gm >> 11, tt = gm & (TSEQ - 1);
          const int hh = gn >> 6, dd = gn & 63;
          float o = val;
          if (STORE == 2) {
            float pv = __shfl_xor(val, 1);
            const int ip = dd >> 1;
            float cz = cos_t[tt * 32 + ip], sz = sin_t[tt * 32 + ip];
            o = (dd & 1) ? (val * cz + pv * sz) : (val * cz - pv * sz);
          }
          out[((size_t)((bb * NHEAD + hh) * TSEQ + tt)) * DHD + dd] = o;
        }
      }
    }
  }
}

// ---------------- LSH bucket ----------------
__global__ __launch_bounds__(256) void k_bucket(const float* __restrict__ qk, const float* __restrict__ rot,
                                                int* __restrict__ bucket) {
  int idx = blockIdx.x * 256 + threadIdx.x;   // bh*8192 + h*2048 + t
  int t = idx & (TSEQ - 1);
  int h = (idx >> 11) & 3;
  int bh = idx >> 13;
  const float* q = qk + ((size_t)bh * TSEQ + t) * DHD;
  float acc[16];
#pragma unroll
  for (int j = 0; j < 16; ++j) acc[j] = 0.0f;
  for (int d = 0; d < 64; ++d) {
    float qv = q[d];
    const float* rp = rot + d * 64 + h * 16;
#pragma unroll
    for (int j = 0; j < 16; ++j) acc[j] += qv * rp[j];
  }
  float best = acc[0]; int bi = 0;
#pragma unroll
  for (int j = 1; j < 16; ++j) if (acc[j] > best) { best = acc[j]; bi = j; }
#pragma unroll
  for (int j = 0; j < 16; ++j) { float nv = -acc[j]; if (nv > best) { best = nv; bi = 16 + j; } }
  bucket[idx] = bi;
}

// ---------------- stable counting sort per (bh,h): 32 buckets, 2048 items ----------------
__global__ __launch_bounds__(64) void k_sort(const int* __restrict__ bucket, int* __restrict__ st) {
  int seg = blockIdx.x;                 // bh*4 + h
  const int* bk = bucket + (size_t)seg * TSEQ;
  int lane = threadIdx.x;
  __shared__ int cnt[32];
  __shared__ int off[32];
  if (lane < 32) {
    int c = 0;
    for (int t = 0; t < TSEQ; ++t) c += (bk[t] == lane);
    cnt[lane] = c;
  }
  __syncthreads();
  if (lane == 0) {
    int s = 0;
    for (int j = 0; j < 32; ++j) { off[j] = s; s += cnt[j]; }
  }
  __syncthreads();
  if (lane < 32) {
    int pos = off[lane];
    int* dst = st + (size_t)seg * TSEQ;
    for (int t = 0; t < TSEQ; ++t)
      if (bk[t] == lane) dst[pos++] = t;
  }
}

// ---------------- chunked LSH attention ----------------
__global__ __launch_bounds__(256) void k_attn(const float* __restrict__ qk, const float* __restrict__ v,
                                              const int* __restrict__ st, float* __restrict__ o4,
                                              float* __restrict__ lg) {
  __shared__ float raw[128][68];
  __shared__ float vv[128][68];
  __shared__ float inv_norm[128];
  __shared__ int tids[128];
  __shared__ float prow4[4][4][128];
  int blk = blockIdx.x;
  int c = blk & (CHUNKS - 1), bh = blk >> 7;
  int h = c >> 5;
  int tid = threadIdx.x, lane = tid & 63, w = tid >> 6;
  if (tid < 128) {
    int cc = (tid < 64) ? c : ((c + CHUNKS - 1) & (CHUNKS - 1));
    tids[tid] = st[(size_t)bh * (NHASHK * TSEQ) + cc * 64 + (tid & 63)];
  }
  __syncthreads();
  const float* qbase = qk + (size_t)bh * TSEQ * DHD;
  const float* vbase = v + (size_t)bh * TSEQ * DHD;
  for (int e = tid; e < 128 * 16; e += 256) {
    int r = e >> 4, d4 = e & 15;
    int t = tids[r];
    float4 a = ((const float4*)(qbase + (size_t)t * DHD))[d4];
    float4 b = ((const float4*)(vbase + (size_t)t * DHD))[d4];
    *(float4*)&raw[r][d4 << 2] = a;
    *(float4*)&vv[r][d4 << 2] = b;
  }
  __syncthreads();
  for (int rr = 0; rr < 32; ++rr) {
    int r = (w << 5) + rr;
    float xv = raw[r][lane];
    float ss = xv * xv;
#pragma unroll
    for (int o = 32; o; o >>= 1) ss += __shfl_xor(ss, o);
    if (lane == 0) inv_norm[r] = 1.0f / fmaxf(sqrtf(ss), 1e-12f);
  }
  __syncthreads();
  int tk0 = tids[lane], tk1 = tids[64 + lane];
  float in0 = inv_norm[lane] * 0.125f, in1 = inv_norm[64 + lane] * 0.125f;
  size_t obase = (size_t)(bh * NHASHK + h) * TSEQ;
  for (int qg = 0; qg < 4; ++qg) {
    float acc[4][2] = {};
#pragma unroll 4
    for (int d4 = 0; d4 < 16; ++d4) {
      float4 k0 = *(const float4*)&raw[lane][d4 << 2];
      float4 k1 = *(const float4*)&raw[64 + lane][d4 << 2];
#pragma unroll
      for (int qi = 0; qi < 4; ++qi) {
        int i = (w << 4) + (qg << 2) + qi;
        float4 a = *(const float4*)&raw[i][d4 << 2];
        acc[qi][0] += a.x * k0.x + a.y * k0.y + a.z * k0.z + a.w * k0.w;
        acc[qi][1] += a.x * k1.x + a.y * k1.y + a.z * k1.z + a.w * k1.w;
      }
    }
#pragma unroll
    for (int qi = 0; qi < 4; ++qi) {
      int i = (w << 4) + (qg << 2) + qi;
      int tq = tids[i];
      float d0 = acc[qi][0] * in0;
      float d1 = acc[qi][1] * in1;
      if (tq == tk0) d0 = -5e4f;
      if (tq == tk1) d1 = -5e4f;
      float m = fmaxf(d0, d1);
#pragma unroll
      for (int o = 32; o; o >>= 1) m = fmaxf(m, __shfl_xor(m, o));
      float sum = expf(d0 - m) + expf(d1 - m);
#pragma unroll
      for (int o = 32; o; o >>= 1) sum += __shfl_xor(sum, o);
      float lse = logf(sum) + m;
      prow4[w][qi][lane] = expf(d0 - lse);
      prow4[w][qi][64 + lane] = expf(d1 - lse);
      if (lane == 0) lg[obase + tq] = lse;
    }
    float ov0 = 0, ov1 = 0, ov2 = 0, ov3 = 0;
    for (int j = 0; j < 128; ++j) {
      float vj = vv[j][lane];
      ov0 += prow4[w][0][j] * vj;
      ov1 += prow4[w][1][j] * vj;
      ov2 += prow4[w][2][j] * vj;
      ov3 += prow4[w][3][j] * vj;
    }
    float ovs[4] = {ov0, ov1, ov2, ov3};
#pragma unroll
    for (int qi = 0; qi < 4; ++qi) {
      int i = (w << 4) + (qg << 2) + qi;
      int tq = tids[i];
      o4[(obase + tq) * DHD + lane] = ovs[qi];
    }
  }
}

// ---------------- combine hash rounds -> ctx bf16 hi/lo [B,T,512] ----------------
__global__ __launch_bounds__(256) void k_combine(const float* __restrict__ o4, const float* __restrict__ lg,
                                                 u16* __restrict__ ctx_hi, u16* __restrict__ ctx_lo) {
  int tok = blockIdx.x * 4 + (threadIdx.x >> 6);   // over BHD*TSEQ
  int dd = threadIdx.x & 63;
  int bh = tok >> 11, t = tok & (TSEQ - 1);
  size_t base = (size_t)bh * NHASHK * TSEQ + t;
  float l0 = lg[base], l1 = lg[base + TSEQ], l2 = lg[base + 2 * TSEQ], l3 = lg[base + 3 * TSEQ];
  float m = fmaxf(fmaxf(l0, l1), fmaxf(l2, l3));
  float e0 = expf(l0 - m), e1 = expf(l1 - m), e2 = expf(l2 - m), e3 = expf(l3 - m);
  float inv = 1.0f / (e0 + e1 + e2 + e3);
  float o = (e0 * o4[base * 64 + dd] + e1 * o4[(base + TSEQ) * 64 + dd] +
             e2 * o4[(base + 2 * TSEQ) * 64 + dd] + e3 * o4[(base + 3 * TSEQ) * 64 + dd]) * inv;
  int b = bh >> 3, hh = bh & 7;
  size_t idx = ((size_t)(b * TSEQ + t)) * DIMM + hh * DHD + dd;
  u16 h2, l2q;
  split_bf16(o, h2, l2q);
  ctx_hi[idx] = h2;
  ctx_lo[idx] = l2q;
}

// ---------------- final LN stats on (x1+x2)/2 ----------------
__global__ __launch_bounds__(256) void k_final_stats(const float* __restrict__ x1, const float* __restrict__ x2,
                                                     float2* __restrict__ stats) {
  int row = blockIdx.x, tid = threadIdx.x;
  const float* p1 = x1 + (size_t)row * DIMM;
  const float* p2 = x2 + (size_t)row * DIMM;
  float v0 = 0.5f * (p1[tid] + p2[tid]);
  float v1 = 0.5f * (p1[tid + 256] + p2[tid + 256]);
  int lane = tid & 63, w = tid >> 6;
  __shared__ float red[8];
  float s = v0 + v1;
#pragma unroll
  for (int o = 32; o; o >>= 1) s += __shfl_xor(s, o);
  if (lane == 0) red[w] = s;
  __syncthreads();
  float mu = (red[0] + red[1] + red[2] + red[3]) * (1.0f / DIMM);
  float d0 = v0 - mu, d1 = v1 - mu;
  float q = d0 * d0 + d1 * d1;
#pragma unroll
  for (int o = 32; o; o >>= 1) q += __shfl_xor(q, o);
  if (lane == 0) red[4 + w] = q;
  __syncthreads();
  if (tid == 0) {
    float var = (red[4] + red[5] + red[6] + red[7]) * (1.0f / DIMM);
    stats[row] = make_float2(mu, 1.0f / sqrtf(var + 1e-5f));
  }
}

// ---------------- LN + mean over T, stage 1: 64 blocks of 64 rows ----------------
__global__ __launch_bounds__(256) void k_colmean1(const float* __restrict__ x1, const float* __restrict__ x2,
                                                  const float2* __restrict__ stats, float* __restrict__ part) {
  int blk = blockIdx.x;            // [0,64): bb*32 + ch
  int bb = blk >> 5, ch = blk & 31;
  int d = threadIdx.x;
  float a0 = 0.f, a1 = 0.f;
  for (int i = 0; i < 64; ++i) {
    int row = bb * TSEQ + (ch << 6) + i;
    float2 sr = stats[row];
    size_t base = (size_t)row * DIMM;
    a0 += (0.5f * (x1[base + d] + x2[base + d]) - sr.x) * sr.y;
    a1 += (0.5f * (x1[base + d + 256] + x2[base + d + 256]) - sr.x) * sr.y;
  }
  part[(size_t)blk * DIMM + d] = a0;
  part[(size_t)blk * DIMM + d + 256] = a1;
}

__global__ __launch_bounds__(256) void k_colmean2(const float* __restrict__ part,
                                                  const float* __restrict__ g, const float* __restrict__ b,
                                                  float* __restrict__ hm) {
  int idx = blockIdx.x * 256 + threadIdx.x;   // 1024
  int bb = idx >> 9, d = idx & 511;
  float s = 0.f;
  for (int c = 0; c < 32; ++c) s += part[(size_t)(bb * 32 + c) * DIMM + d];
  hm[idx] = s * (1.0f / TSEQ) * g[d] + b[d];
}

// ---------------- head ----------------
__global__ __launch_bounds__(256) void k_head1(const float* __restrict__ hm, const float* __restrict__ Wf1,
                                               const float* __restrict__ bf1, float* __restrict__ r1) {
  int b = blockIdx.x, j = threadIdx.x;   // 2 x 256
  float acc = 0;
  for (int k = 0; k < DIMM; ++k) acc += hm[b * DIMM + k] * Wf1[k * 256 + j];
  r1[b * 256 + j] = fmaxf(acc + bf1[j], 0.0f);
}

__global__ __launch_bounds__(256) void k_head2(const float* __restrict__ r1, const float* __restrict__ Wout,
                                               const float* __restrict__ bout, float* __restrict__ outp) {
  int b = blockIdx.x;
  int tid = threadIdx.x, lane = tid & 63, w = tid >> 6;
  float v = r1[b * 256 + tid] * Wout[tid];
#pragma unroll
  for (int o = 32; o; o >>= 1) v += __shfl_xor(v, o);
  __shared__ float red[4];
  if (lane == 0) red[w] = v;
  __syncthreads();
  if (tid == 0) outp[b] = red[0] + red[1] + red[2] + red[3] + bout[0];
}

extern "C" void kernel_launch(void* const* d_in, const int* in_sizes, int n_in,
                              void* d_out, int out_size, void* d_ws, size_t ws_size,
                              hipStream_t stream) {
  const int*   x         = (const int*)d_in[0];
  const float* token_emb = (const float*)d_in[1];
  const float* ln1_s     = (const float*)d_in[2];
  const float* ln1_b     = (const float*)d_in[3];
  const float* Wqk       = (const float*)d_in[4];
  const float* Wv        = (const float*)d_in[5];
  const float* Wo        = (const float*)d_in[6];
  const float* bo        = (const float*)d_in[7];
  const float* ln2_s     = (const float*)d_in[8];
  const float* ln2_b     = (const float*)d_in[9];
  const float* W1        = (const float*)d_in[10];
  const float* b1        = (const float*)d_in[11];
  const float* W2        = (const float*)d_in[12];
  const float* b2        = (const float*)d_in[13];
  const float* rotations = (const float*)d_in[14];
  const float* lnf_s     = (const float*)d_in[15];
  const float* lnf_b     = (const float*)d_in[16];
  const float* Wf1       = (const float*)d_in[17];
  const float* bf1       = (const float*)d_in[18];
  const float* Wout      = (const float*)d_in[19];
  const float* bout      = (const float*)d_in[20];
  float* out = (float*)d_out;

  char* ws = (char*)d_ws;
  size_t off = 0;
  auto alloc = [&](size_t nbytes) {
    char* p = ws + off;
    off += (nbytes + 255) & ~(size_t)255;
    return p;
  };
  float* x1     = (float*)alloc((size_t)NROWS * DIMM * 4);
  float* x2     = (float*)alloc((size_t)NROWS * DIMM * 4);
  u16*   xn_hi  = (u16*)alloc((size_t)NROWS * DIMM * 2);
  u16*   xn_lo  = (u16*)alloc((size_t)NROWS * DIMM * 2);
  float* qk     = (float*)alloc((size_t)BHD * TSEQ * DHD * 4);
  float* vbuf   = (float*)alloc((size_t)BHD * TSEQ * DHD * 4);
  u16*   ffh_hi = (u16*)alloc((size_t)NROWS * FFD * 2);   // o4 aliases ffh_hi..ffh_lo (32MB fp32)
  u16*   ffh_lo = (u16*)alloc((size_t)NROWS * FFD * 2);
  float* o4     = (float*)ffh_hi;
  float* lg     = (float*)alloc((size_t)BHD * NHASHK * TSEQ * 4);
  float* sin_t  = (float*)alloc((size_t)TSEQ * 32 * 4);
  float* cos_t  = (float*)alloc((size_t)TSEQ * 32 * 4);
  float2* stats = (float2*)alloc((size_t)NROWS * 8);
  float* part   = (float*)alloc((size_t)64 * DIMM * 4);
  float* hm     = (float*)alloc(2 * DIMM * 4);
  float* r1     = (float*)alloc(2 * 256 * 4);
  int*   bucket = (int*)alloc((size_t)BHD * NHASHK * TSEQ * 4);
  int*   st     = (int*)alloc((size_t)BHD * NHASHK * TSEQ * 4);
  const size_t OFF_WQK = 0;
  const size_t OFF_WV  = 512 * 512;
  const size_t OFF_WO  = 2 * 512 * 512;
  const size_t OFF_W1  = 3 * 512 * 512;
  const size_t OFF_W2  = 3 * 512 * 512 + 512 * 2048;
  const size_t WT_TOT  = 3 * 512 * 512 + 2 * 512 * 2048;
  u16*   wt_hi  = (u16*)alloc(WT_TOT * 2);
  u16*   wt_lo  = (u16*)alloc(WT_TOT * 2);
  u16*   ctx_hi = xn_hi;   // alias: lifetimes disjoint
  u16*   ctx_lo = xn_lo;

  k_embed<<<NROWS, 128, 0, stream>>>(x, token_emb, x1, x2);
  k_sincos<<<(TSEQ * 32) / 256, 256, 0, stream>>>(sin_t, cos_t);

  for (int L = 0; L < 4; ++L) {
    const float* wqk = Wqk + (size_t)L * DIMM * DIMM;
    const float* wv  = Wv  + (size_t)L * DIMM * DIMM;
    const float* wo  = Wo  + (size_t)L * DIMM * DIMM;
    const float* w1  = W1  + (size_t)L * DIMM * FFD;
    const float* w2  = W2  + (size_t)L * FFD * DIMM;
    const float* rot = rotations + (size_t)L * DHD * NHASHK * 16;

    // weight transpose+split for this layer
    k_tsplit<<<dim3(16, 16), 256, 0, stream>>>(wqk, wt_hi + OFF_WQK, wt_lo + OFF_WQK, 512, 512);
    k_tsplit<<<dim3(16, 16), 256, 0, stream>>>(wv,  wt_hi + OFF_WV,  wt_lo + OFF_WV,  512, 512);
    k_tsplit<<<dim3(16, 16), 256, 0, stream>>>(wo,  wt_hi + OFF_WO,  wt_lo + OFF_WO,  512, 512);
    k_tsplit<<<dim3(16, 64), 256, 0, stream>>>(w1,  wt_hi + OFF_W1,  wt_lo + OFF_W1,  512, 2048);
    k_tsplit<<<dim3(64, 16), 256, 0, stream>>>(w2,  wt_hi + OFF_W2,  wt_lo + OFF_W2,  2048, 512);

    k_layernorm<<<NROWS, 256, 0, stream>>>(x2, ln1_s + L * DIMM, ln1_b + L * DIMM, xn_hi, xn_lo);
    dim3 g512(32, 8);
    k_gemm_mfma<64, 2><<<g512, 256, 0, stream>>>(xn_hi, xn_lo, wt_hi + OFF_WQK, wt_lo + OFF_WQK,
                                                 nullptr, qk, nullptr, nullptr, 512, 512, sin_t, cos_t);
    k_gemm_mfma<64, 3><<<g512, 256, 0, stream>>>(xn_hi, xn_lo, wt_hi + OFF_WV, wt_lo + OFF_WV,
                                                 nullptr, vbuf, nullptr, nullptr, 512, 512, nullptr, nullptr);
    k_bucket<<<(BHD * NHASHK * TSEQ) / 256, 256, 0, stream>>>(qk, rot, bucket);
    k_sort<<<BHD * NHASHK, 64, 0, stream>>>(bucket, st);
    k_attn<<<BHD * CHUNKS, 256, 0, stream>>>(qk, vbuf, st, o4, lg);
    k_combine<<<(BHD * TSEQ) / 4, 256, 0, stream>>>(o4, lg, ctx_hi, ctx_lo);
    k_gemm_mfma<64, 1><<<g512, 256, 0, stream>>>(ctx_hi, ctx_lo, wt_hi + OFF_WO, wt_lo + OFF_WO,
                                                 bo + L * DIMM, x1, nullptr, nullptr, 512, 512, nullptr, nullptr);
    k_layernorm<<<NROWS, 256, 0, stream>>>(x1, ln2_s + L * DIMM, ln2_b + L * DIMM, xn_hi, xn_lo);
    dim3 gff1(32, 16);
    k_gemm_mfma<128, 4><<<gff1, 256, 0, stream>>>(xn_hi, xn_lo, wt_hi + OFF_W1, wt_lo + OFF_W1,
                                                  b1 + L * FFD, nullptr, ffh_hi, ffh_lo, 512, 2048, nullptr, nullptr);
    dim3 gff2(32, 8);
    k_gemm_mfma<64, 1><<<gff2, 256, 0, stream>>>(ffh_hi, ffh_lo, wt_hi + OFF_W2, wt_lo + OFF_W2,
                                                 b2 + L * DIMM, x2, nullptr, nullptr, 2048, 512, nullptr, nullptr);
  }

  k_final_stats<<<NROWS, 256, 0, stream>>>(x1, x2, stats);
  k_colmean1<<<64, 256, 0, stream>>>(x1, x2, stats, part);
  k_colmean2<<<4, 256, 0, stream>>>(part, lnf_s, lnf_b, hm);
  k_head1<<<2, 256, 0, stream>>>(hm, Wf1, bf1, r1);
  k_head2<<<2, 256, 0, stream>>>(r1, Wout, bout, out);
}

// Round 3
// 1038.589 us; speedup vs baseline: 3.2672x; 2.2115x over previous
//
#include <hip/hip_runtime.h>
#include <math.h>

#define TSEQ   2048
#define DIMM   512
#define NHEAD  8
#define DHD    64
#define BHD    16      // BATCH*HEADS
#define NHASHK 4
#define CHUNKS 128     // NHASHK * (TSEQ/64)
#define FFD    2048
#define NROWS  4096    // BATCH*TSEQ

typedef unsigned short u16;
typedef __attribute__((ext_vector_type(8))) short bf16x8;
typedef __attribute__((ext_vector_type(4))) float f32x4;
typedef __attribute__((ext_vector_type(8))) unsigned short ushort8v;
typedef __attribute__((ext_vector_type(4))) unsigned short ushort4v;

__device__ inline u16 bf16_hi(float f) {
  unsigned u = __float_as_uint(f);
  unsigned r = u + 0x7fffu + ((u >> 16) & 1u);
  return (u16)(r >> 16);
}
__device__ inline void split_bf16(float f, u16& h, u16& l) {
  h = bf16_hi(f);
  float fh = __uint_as_float(((unsigned)h) << 16);
  l = bf16_hi(f - fh);
}
__device__ inline bf16x8 mk8(unsigned a, unsigned b, unsigned c, unsigned d) {
  union { unsigned u[4]; bf16x8 v; } x;
  x.u[0] = a; x.u[1] = b; x.u[2] = c; x.u[3] = d;
  return x.v;
}
__device__ inline float unpack_hl(unsigned u) {
  return __uint_as_float(u & 0xffff0000u) + __uint_as_float(u << 16);
}

// ---------------- embed ----------------
__global__ __launch_bounds__(128) void k_embed(const int* __restrict__ x, const float* __restrict__ emb,
                                               float* __restrict__ x1, float* __restrict__ x2) {
  int row = blockIdx.x;
  int tok = x[row];
  float4 v = ((const float4*)(emb + (size_t)tok * DIMM))[threadIdx.x];
  ((float4*)(x1 + (size_t)row * DIMM))[threadIdx.x] = v;
  ((float4*)(x2 + (size_t)row * DIMM))[threadIdx.x] = v;
}

// ---------------- sin/cos tables ----------------
__global__ __launch_bounds__(256) void k_sincos(float* __restrict__ sin_t, float* __restrict__ cos_t) {
  int idx = blockIdx.x * 256 + threadIdx.x;   // TSEQ*32
  int t = idx >> 5, i = idx & 31;
  float inv = powf(10000.0f, -(float)(2 * i) / 64.0f);
  float ang = (float)t * inv;
  sin_t[idx] = sinf(ang);
  cos_t[idx] = cosf(ang);
}

// ---------------- layernorm (row = 512) -> bf16 hi/lo ----------------
__global__ __launch_bounds__(256) void k_layernorm(const float* __restrict__ x, const float* __restrict__ g,
                                                   const float* __restrict__ b,
                                                   u16* __restrict__ hi, u16* __restrict__ lo) {
  int row = blockIdx.x, tid = threadIdx.x;
  const float* xr = x + (size_t)row * DIMM;
  float v0 = xr[tid], v1 = xr[tid + 256];
  int lane = tid & 63, w = tid >> 6;
  __shared__ float red[8];
  float s = v0 + v1;
#pragma unroll
  for (int o = 32; o; o >>= 1) s += __shfl_xor(s, o);
  if (lane == 0) red[w] = s;
  __syncthreads();
  float mu = (red[0] + red[1] + red[2] + red[3]) * (1.0f / DIMM);
  float d0 = v0 - mu, d1 = v1 - mu;
  float q = d0 * d0 + d1 * d1;
#pragma unroll
  for (int o = 32; o; o >>= 1) q += __shfl_xor(q, o);
  if (lane == 0) red[4 + w] = q;
  __syncthreads();
  float var = (red[4] + red[5] + red[6] + red[7]) * (1.0f / DIMM);
  float rstd = 1.0f / sqrtf(var + 1e-5f);
  float y0 = d0 * rstd * g[tid] + b[tid];
  float y1 = d1 * rstd * g[tid + 256] + b[tid + 256];
  u16 h0, l0, h1, l1;
  split_bf16(y0, h0, l0);
  split_bf16(y1, h1, l1);
  size_t base = (size_t)row * DIMM;
  hi[base + tid] = h0; lo[base + tid] = l0;
  hi[base + tid + 256] = h1; lo[base + tid + 256] = l1;
}

__device__ inline float gelu_exact(float v) {
  return 0.5f * v * (1.0f + erff(v * 0.70710678118654752f));
}

// ---------------- weight transpose + bf16 split: W[K][N] -> T[N][K] hi/lo ----------------
__global__ __launch_bounds__(256) void k_tsplit(const float* __restrict__ W,
                                                u16* __restrict__ Thi, u16* __restrict__ Tlo,
                                                int K, int N) {
  __shared__ float tile[32][33];
  const int k0 = blockIdx.x << 5, n0 = blockIdx.y << 5;
  const int t = threadIdx.x;
  const int r = t >> 3, c4 = (t & 7) << 2;
  float4 v = *(const float4*)&W[(size_t)(k0 + r) * N + n0 + c4];
  tile[r][c4] = v.x; tile[r][c4 + 1] = v.y; tile[r][c4 + 2] = v.z; tile[r][c4 + 3] = v.w;
  __syncthreads();
  u16 hs[4], ls[4];
#pragma unroll
  for (int i = 0; i < 4; ++i) split_bf16(tile[c4 + i][r], hs[i], ls[i]);
  size_t o = (size_t)(n0 + r) * K + k0 + c4;
  *(ushort4v*)&Thi[o] = (ushort4v){hs[0], hs[1], hs[2], hs[3]};
  *(ushort4v*)&Tlo[o] = (ushort4v){ls[0], ls[1], ls[2], ls[3]};
}

// ---------------- split-bf16 MFMA GEMM: C = A[M][K] * B^T (Bt[N][K]) ----------------
// STORE: 1 = out[g] += val + bias; 2 = head-major rotary -> packed u32 hi|lo (qk)
//        3 = head-major -> packed u32 (v); 4 = gelu(val+bias) -> bf16 hi/lo split store
template <int BN, int STORE>
__global__ __launch_bounds__(256) void k_gemm_mfma(
    const u16* __restrict__ Ahi, const u16* __restrict__ Alo,
    const u16* __restrict__ Bhi, const u16* __restrict__ Blo,
    const float* __restrict__ bias, float* __restrict__ out,
    u16* __restrict__ out_hi, u16* __restrict__ out_lo,
    unsigned* __restrict__ out_u,
    int K, int N,
    const float* __restrict__ sin_t, const float* __restrict__ cos_t) {
  constexpr int NF = BN / 32;             // n-frags per wave
  __shared__ __align__(16) u16 As_hi[128][40];
  __shared__ __align__(16) u16 As_lo[128][40];
  __shared__ __align__(16) u16 Bs_hi[BN][40];
  __shared__ __align__(16) u16 Bs_lo[BN][40];
  const int bm = blockIdx.x << 7;
  const int bn = blockIdx.y * BN;
  const int tid = threadIdx.x, lane = tid & 63, wid = tid >> 6;
  const int wm = (wid >> 1) << 6;         // 0 or 64
  const int wn = (wid & 1) * (BN >> 1);   // 0 or BN/2
  const int l16 = lane & 15, lg16 = lane >> 4;
  f32x4 acc[4][NF];
#pragma unroll
  for (int m = 0; m < 4; ++m)
#pragma unroll
    for (int n = 0; n < NF; ++n) acc[m][n] = (f32x4){0.f, 0.f, 0.f, 0.f};

  const int ar = tid >> 1, ac = (tid & 1) << 4;
  const size_t aoff = (size_t)(bm + ar) * K + ac;
  int br, bc;
  if constexpr (BN == 128) { br = tid >> 1; bc = (tid & 1) << 4; }
  else                     { br = tid >> 2; bc = (tid & 3) << 3; }
  const size_t boff = (size_t)(bn + br) * K + bc;

  for (int k0 = 0; k0 < K; k0 += 32) {
    ushort8v a_h0 = *(const ushort8v*)(Ahi + aoff + k0);
    ushort8v a_h1 = *(const ushort8v*)(Ahi + aoff + k0 + 8);
    ushort8v a_l0 = *(const ushort8v*)(Alo + aoff + k0);
    ushort8v a_l1 = *(const ushort8v*)(Alo + aoff + k0 + 8);
    ushort8v b_h0 = *(const ushort8v*)(Bhi + boff + k0);
    ushort8v b_l0 = *(const ushort8v*)(Blo + boff + k0);
    ushort8v b_h1{}, b_l1{};
    if constexpr (BN == 128) {
      b_h1 = *(const ushort8v*)(Bhi + boff + k0 + 8);
      b_l1 = *(const ushort8v*)(Blo + boff + k0 + 8);
    }
    __syncthreads();
    *(ushort8v*)&As_hi[ar][ac] = a_h0;
    *(ushort8v*)&As_hi[ar][ac + 8] = a_h1;
    *(ushort8v*)&As_lo[ar][ac] = a_l0;
    *(ushort8v*)&As_lo[ar][ac + 8] = a_l1;
    if constexpr (BN == 128) {
      *(ushort8v*)&Bs_hi[br][bc] = b_h0;
      *(ushort8v*)&Bs_hi[br][bc + 8] = b_h1;
      *(ushort8v*)&Bs_lo[br][bc] = b_l0;
      *(ushort8v*)&Bs_lo[br][bc + 8] = b_l1;
    } else {
      *(ushort8v*)&Bs_hi[br][bc] = b_h0;
      *(ushort8v*)&Bs_lo[br][bc] = b_l0;
    }
    __syncthreads();
    bf16x8 ah[4], al[4], bh[NF], bl[NF];
#pragma unroll
    for (int m = 0; m < 4; ++m) {
      ah[m] = *(const bf16x8*)&As_hi[wm + (m << 4) + l16][lg16 << 3];
      al[m] = *(const bf16x8*)&As_lo[wm + (m << 4) + l16][lg16 << 3];
    }
#pragma unroll
    for (int n = 0; n < NF; ++n) {
      bh[n] = *(const bf16x8*)&Bs_hi[wn + (n << 4) + l16][lg16 << 3];
      bl[n] = *(const bf16x8*)&Bs_lo[wn + (n << 4) + l16][lg16 << 3];
    }
#pragma unroll
    for (int m = 0; m < 4; ++m)
#pragma unroll
      for (int n = 0; n < NF; ++n) {
        acc[m][n] = __builtin_amdgcn_mfma_f32_16x16x32_bf16(ah[m], bh[n], acc[m][n], 0, 0, 0);
        acc[m][n] = __builtin_amdgcn_mfma_f32_16x16x32_bf16(ah[m], bl[n], acc[m][n], 0, 0, 0);
        acc[m][n] = __builtin_amdgcn_mfma_f32_16x16x32_bf16(al[m], bh[n], acc[m][n], 0, 0, 0);
      }
  }
  // epilogue (C/D layout: col = lane&15, row = (lane>>4)*4 + reg)
#pragma unroll
  for (int m = 0; m < 4; ++m) {
#pragma unroll
    for (int n = 0; n < NF; ++n) {
      const int gn = bn + wn + (n << 4) + l16;
      float bv = 0.f;
      if (STORE == 1 || STORE == 4) bv = bias[gn];
#pragma unroll
      for (int r = 0; r < 4; ++r) {
        const int gm = bm + wm + (m << 4) + (lg16 << 2) + r;
        float val = acc[m][n][r];
        if (STORE == 1) {
          out[(size_t)gm * N + gn] += val + bv;
        } else if (STORE == 4) {
          float gv = gelu_exact(val + bv);
          u16 hx, lx;
          split_bf16(gv, hx, lx);
          out_hi[(size_t)gm * N + gn] = hx;
          out_lo[(size_t)gm * N + gn] = lx;
        } else {
          const int bb = gm >> 11, tt = gm & (TSEQ - 1);
          const int hh = gn >> 6, dd = gn & 63;
          float o = val;
          if (STORE == 2) {
            float pv = __shfl_xor(val, 1);
            const int ip = dd >> 1;
            float cz = cos_t[tt * 32 + ip], sz = sin_t[tt * 32 + ip];
            o = (dd & 1) ? (val * cz + pv * sz) : (val * cz - pv * sz);
          }
          u16 hx, lx;
          split_bf16(o, hx, lx);
          out_u[((size_t)((bb * NHEAD + hh) * TSEQ + tt)) * DHD + dd] = ((unsigned)hx << 16) | lx;
        }
      }
    }
  }
}

// ---------------- LSH bucket via MFMA: rv = qk @ rot^T, fused argmax ----------------
__global__ __launch_bounds__(256) void k_bucket_gemm(const unsigned* __restrict__ qk_hl,
                                                     const u16* __restrict__ Rhi, const u16* __restrict__ Rlo,
                                                     int* __restrict__ bucket) {
  __shared__ __align__(16) u16 Ahi[128][72];
  __shared__ __align__(16) u16 Alo[128][72];
  __shared__ __align__(16) u16 Bh[64][72];
  __shared__ __align__(16) u16 Bl[64][72];
  const int bm = blockIdx.x << 7;
  const int tid = threadIdx.x, lane = tid & 63, wid = tid >> 6;
  const int l16 = lane & 15, g = lane >> 4;
  // stage A (packed u32 rows -> hi/lo)
  {
    const int r = tid >> 1, hf = tid & 1;
    const unsigned* src = qk_hl + (size_t)(bm + r) * 64 + hf * 32;
#pragma unroll
    for (int i = 0; i < 8; ++i) {
      uint4 u = ((const uint4*)src)[i];
      unsigned hw0 = (u.x >> 16) | (u.y & 0xffff0000u);
      unsigned lw0 = (u.x & 0xffffu) | (u.y << 16);
      unsigned hw1 = (u.z >> 16) | (u.w & 0xffff0000u);
      unsigned lw1 = (u.z & 0xffffu) | (u.w << 16);
      int colb = hf * 32 + i * 4;
      *(uint2*)&Ahi[r][colb] = make_uint2(hw0, hw1);
      *(uint2*)&Alo[r][colb] = make_uint2(lw0, lw1);
    }
  }
  if (tid < 128) {
    const int r = tid >> 1, hf = tid & 1;
#pragma unroll
    for (int i = 0; i < 4; ++i) {
      *(ushort8v*)&Bh[r][hf * 32 + i * 8] = *(const ushort8v*)&Rhi[r * 64 + hf * 32 + i * 8];
      *(ushort8v*)&Bl[r][hf * 32 + i * 8] = *(const ushort8v*)&Rlo[r * 64 + hf * 32 + i * 8];
    }
  }
  __syncthreads();
  const int wm = (wid >> 1) << 6, wn = (wid & 1) << 5;
  f32x4 acc[4][2];
#pragma unroll
  for (int m = 0; m < 4; ++m) { acc[m][0] = (f32x4){0,0,0,0}; acc[m][1] = (f32x4){0,0,0,0}; }
#pragma unroll
  for (int s = 0; s < 2; ++s) {
    bf16x8 bhf[2], blf[2];
#pragma unroll
    for (int n = 0; n < 2; ++n) {
      bhf[n] = *(const bf16x8*)&Bh[wn + (n << 4) + l16][s * 32 + g * 8];
      blf[n] = *(const bf16x8*)&Bl[wn + (n << 4) + l16][s * 32 + g * 8];
    }
#pragma unroll
    for (int m = 0; m < 4; ++m) {
      bf16x8 ah = *(const bf16x8*)&Ahi[wm + (m << 4) + l16][s * 32 + g * 8];
      bf16x8 al = *(const bf16x8*)&Alo[wm + (m << 4) + l16][s * 32 + g * 8];
#pragma unroll
      for (int n = 0; n < 2; ++n) {
        acc[m][n] = __builtin_amdgcn_mfma_f32_16x16x32_bf16(ah, bhf[n], acc[m][n], 0, 0, 0);
        acc[m][n] = __builtin_amdgcn_mfma_f32_16x16x32_bf16(ah, blf[n], acc[m][n], 0, 0, 0);
        acc[m][n] = __builtin_amdgcn_mfma_f32_16x16x32_bf16(al, bhf[n], acc[m][n], 0, 0, 0);
      }
    }
  }
  // argmax over [rv, -rv] per h (16 cols each, within l16 group)
#pragma unroll
  for (int m = 0; m < 4; ++m)
#pragma unroll
    for (int n = 0; n < 2; ++n) {
      const int hcol = (wn >> 4) + n;
#pragma unroll
      for (int r = 0; r < 4; ++r) {
        float v = acc[m][n][r];
        float best = v; int bi = l16;
        if (-v > best) { best = -v; bi = 16 + l16; }
#pragma unroll
        for (int o = 1; o < 16; o <<= 1) {
          float ob = __shfl_xor(best, o);
          int obi = __shfl_xor(bi, o);
          if (ob > best || (ob == best && obi < bi)) { best = ob; bi = obi; }
        }
        if (l16 == 0) {
          int gm = bm + wm + (m << 4) + (g << 2) + r;
          int bh_ = gm >> 11, t = gm & (TSEQ - 1);
          bucket[((size_t)(bh_ * NHASHK) + hcol) * TSEQ + t] = bi;
        }
      }
    }
}

// ---------------- stable counting sort per (bh,h): 32 buckets, 2048 items ----------------
__global__ __launch_bounds__(256) void k_sort(const int* __restrict__ bucket, int* __restrict__ st) {
  __shared__ int hist[256][33];
  __shared__ int bbase[32];
  const int seg = blockIdx.x;
  const int tid = threadIdx.x;
  const int* bk = bucket + (size_t)seg * TSEQ;
  int4 u0 = *(const int4*)(bk + tid * 8);
  int4 u1 = *(const int4*)(bk + tid * 8 + 4);
  int myb[8] = {u0.x, u0.y, u0.z, u0.w, u1.x, u1.y, u1.z, u1.w};
#pragma unroll
  for (int j = 0; j < 33; ++j) hist[tid][j] = 0;
  __syncthreads();
#pragma unroll
  for (int i = 0; i < 8; ++i) hist[tid][myb[i]]++;
  __syncthreads();
  if (tid < 32) {
    int run = 0;
    for (int gq = 0; gq < 256; ++gq) { int c = hist[gq][tid]; hist[gq][tid] = run; run += c; }
    bbase[tid] = run;
  }
  __syncthreads();
  if (tid == 0) {
    int s = 0;
    for (int j = 0; j < 32; ++j) { int c = bbase[j]; bbase[j] = s; s += c; }
  }
  __syncthreads();
  int* dst = st + (size_t)seg * TSEQ;
#pragma unroll
  for (int i = 0; i < 8; ++i) {
    int b = myb[i];
    int p = bbase[b] + hist[tid][b];
    hist[tid][b]++;
    dst[p] = tid * 8 + i;
  }
}

// ---------------- chunked LSH attention (MFMA) ----------------
__global__ __launch_bounds__(256) void k_attn(const unsigned* __restrict__ qk_hl,
                                              const unsigned* __restrict__ v_hl,
                                              const int* __restrict__ st,
                                              float* __restrict__ o4, float* __restrict__ lg) {
  __shared__ __align__(16) u16 Khi[128][72];
  __shared__ __align__(16) u16 Klo[128][72];
  __shared__ float inv_norm[128];
  __shared__ int tids[128];
  __shared__ float pn[256];
  const int blk = blockIdx.x;
  const int c = blk & (CHUNKS - 1), bh = blk >> 7;
  const int h = c >> 5;
  const int tid = threadIdx.x, lane = tid & 63, wid = tid >> 6;
  const int l16 = lane & 15, g = lane >> 4;

  if (tid < 128) {
    int cc = (tid < 64) ? c : ((c + CHUNKS - 1) & (CHUNKS - 1));
    tids[tid] = st[bh * (NHASHK * TSEQ) + cc * 64 + (tid & 63)];
  }
  __syncthreads();
  // stage K (= rotated qk rows) hi/lo + norm partials
  {
    const int r = tid >> 1, hf = tid & 1;
    const unsigned* src = qk_hl + ((size_t)bh * TSEQ + tids[r]) * 64 + hf * 32;
    float ss = 0.f;
#pragma unroll
    for (int i = 0; i < 8; ++i) {
      uint4 u = ((const uint4*)src)[i];
      unsigned hw0 = (u.x >> 16) | (u.y & 0xffff0000u);
      unsigned lw0 = (u.x & 0xffffu) | (u.y << 16);
      unsigned hw1 = (u.z >> 16) | (u.w & 0xffff0000u);
      unsigned lw1 = (u.z & 0xffffu) | (u.w << 16);
      int colb = hf * 32 + i * 4;
      *(uint2*)&Khi[r][colb] = make_uint2(hw0, hw1);
      *(uint2*)&Klo[r][colb] = make_uint2(lw0, lw1);
      float f0 = unpack_hl(u.x), f1 = unpack_hl(u.y), f2 = unpack_hl(u.z), f3 = unpack_hl(u.w);
      ss += f0 * f0 + f1 * f1 + f2 * f2 + f3 * f3;
    }
    pn[tid] = ss;
  }
  __syncthreads();
  if (tid < 128) {
    float s2 = pn[2 * tid] + pn[2 * tid + 1];
    inv_norm[tid] = 1.0f / fmaxf(sqrtf(s2), 1e-12f);
  }
  __syncthreads();

  const int q0 = wid << 4;
  const int qrow = q0 + l16;
  const int tq = tids[qrow];
  const size_t obase = (size_t)(bh * NHASHK + h) * TSEQ + tq;

  // S^T = K_raw · Q^T : C[k][q], 3-term split
  f32x4 accs[8];
#pragma unroll
  for (int i = 0; i < 8; ++i) accs[i] = (f32x4){0, 0, 0, 0};
#pragma unroll
  for (int s = 0; s < 2; ++s) {
    bf16x8 qh = *(const bf16x8*)&Khi[qrow][s * 32 + g * 8];
    bf16x8 ql = *(const bf16x8*)&Klo[qrow][s * 32 + g * 8];
#pragma unroll
    for (int mf = 0; mf < 8; ++mf) {
      bf16x8 ah = *(const bf16x8*)&Khi[mf * 16 + l16][s * 32 + g * 8];
      bf16x8 al = *(const bf16x8*)&Klo[mf * 16 + l16][s * 32 + g * 8];
      accs[mf] = __builtin_amdgcn_mfma_f32_16x16x32_bf16(ah, qh, accs[mf], 0, 0, 0);
      accs[mf] = __builtin_amdgcn_mfma_f32_16x16x32_bf16(ah, ql, accs[mf], 0, 0, 0);
      accs[mf] = __builtin_amdgcn_mfma_f32_16x16x32_bf16(al, qh, accs[mf], 0, 0, 0);
    }
  }
  // scale + self-mask; lane holds k = mf*16 + g*4 + r for q = q0+l16
  float pv[8][4];
  float mx = -3e38f;
#pragma unroll
  for (int mf = 0; mf < 8; ++mf) {
    float4 invn = *(const float4*)&inv_norm[mf * 16 + g * 4];
    int4 tk = *(const int4*)&tids[mf * 16 + g * 4];
    float inva[4] = {invn.x, invn.y, invn.z, invn.w};
    int tka[4] = {tk.x, tk.y, tk.z, tk.w};
#pragma unroll
    for (int r = 0; r < 4; ++r) {
      float d = accs[mf][r] * inva[r] * 0.125f;
      if (tka[r] == tq) d = -5e4f;
      pv[mf][r] = d;
      mx = fmaxf(mx, d);
    }
  }
  mx = fmaxf(mx, __shfl_xor(mx, 16));
  mx = fmaxf(mx, __shfl_xor(mx, 32));
  float sum = 0.f;
#pragma unroll
  for (int mf = 0; mf < 8; ++mf)
#pragma unroll
    for (int r = 0; r < 4; ++r) {
      float e = __expf(pv[mf][r] - mx);
      pv[mf][r] = e;
      sum += e;
    }
  sum += __shfl_xor(sum, 16);
  sum += __shfl_xor(sum, 32);
  float lse = __logf(sum) + mx;
  float rs = 1.0f / sum;
  if (g == 0) lg[obase] = lse;
  // pack P pairs: P2[mf][m] = (p_{2m}, p_{2m+1}) for k = 16mf + 4g + {2m,2m+1}
  unsigned P2h[8][2], P2l[8][2];
#pragma unroll
  for (int mf = 0; mf < 8; ++mf)
#pragma unroll
    for (int m = 0; m < 2; ++m) {
      float p0 = pv[mf][2 * m] * rs, p1 = pv[mf][2 * m + 1] * rs;
      u16 h0, l0, h1, l1;
      split_bf16(p0, h0, l0);
      split_bf16(p1, h1, l1);
      P2h[mf][m] = (unsigned)h0 | ((unsigned)h1 << 16);
      P2l[mf][m] = (unsigned)l0 | ((unsigned)l1 << 16);
    }
  // PV: O^T = V^T · P^T  (A = V^T via global gather, B = P via shfl redistribution)
  f32x4 acco[4];
#pragma unroll
  for (int i = 0; i < 4; ++i) acco[i] = (f32x4){0, 0, 0, 0};
  const unsigned* vbase = v_hl + (size_t)bh * TSEQ * 64;
#pragma unroll
  for (int s = 0; s < 4; ++s) {
    unsigned bhw[4], blw[4];
#pragma unroll
    for (int w = 0; w < 4; ++w) {
      int srl = l16 + (((2 * g + (w >> 1)) & 3) << 4);
      unsigned a0 = __shfl(P2h[2 * s][w & 1], srl);
      unsigned a1 = __shfl(P2h[2 * s + 1][w & 1], srl);
      bhw[w] = (g >> 1) ? a1 : a0;
      unsigned b0 = __shfl(P2l[2 * s][w & 1], srl);
      unsigned b1 = __shfl(P2l[2 * s + 1][w & 1], srl);
      blw[w] = (g >> 1) ? b1 : b0;
    }
    bf16x8 pb_h = mk8(bhw[0], bhw[1], bhw[2], bhw[3]);
    bf16x8 pb_l = mk8(blw[0], blw[1], blw[2], blw[3]);
    int4 t0 = *(const int4*)&tids[s * 32 + g * 8];
    int4 t1 = *(const int4*)&tids[s * 32 + g * 8 + 4];
    int ro[8] = {t0.x, t0.y, t0.z, t0.w, t1.x, t1.y, t1.z, t1.w};
#pragma unroll
    for (int mf = 0; mf < 4; ++mf) {
      const int dcol = mf * 16 + l16;
      unsigned vw[8];
#pragma unroll
      for (int j = 0; j < 8; ++j) vw[j] = vbase[(size_t)ro[j] * 64 + dcol];
      unsigned vhh[4], vll[4];
#pragma unroll
      for (int w = 0; w < 4; ++w) {
        vhh[w] = (vw[2 * w] >> 16) | (vw[2 * w + 1] & 0xffff0000u);
        vll[w] = (vw[2 * w] & 0xffffu) | (vw[2 * w + 1] << 16);
      }
      bf16x8 vh8 = mk8(vhh[0], vhh[1], vhh[2], vhh[3]);
      bf16x8 vl8 = mk8(vll[0], vll[1], vll[2], vll[3]);
      acco[mf] = __builtin_amdgcn_mfma_f32_16x16x32_bf16(vh8, pb_h, acco[mf], 0, 0, 0);
      acco[mf] = __builtin_amdgcn_mfma_f32_16x16x32_bf16(vh8, pb_l, acco[mf], 0, 0, 0);
      acco[mf] = __builtin_amdgcn_mfma_f32_16x16x32_bf16(vl8, pb_h, acco[mf], 0, 0, 0);
    }
  }
  // store O^T: lane holds O[d = 16mf + 4g + r] for q=tq
#pragma unroll
  for (int mf = 0; mf < 4; ++mf)
    *(float4*)&o4[obase * 64 + mf * 16 + g * 4] =
        make_float4(acco[mf][0], acco[mf][1], acco[mf][2], acco[mf][3]);
}

// ---------------- combine hash rounds -> ctx bf16 hi/lo [B,T,512] ----------------
__global__ __launch_bounds__(256) void k_combine(const float* __restrict__ o4, const float* __restrict__ lg,
                                                 u16* __restrict__ ctx_hi, u16* __restrict__ ctx_lo) {
  int tok = blockIdx.x * 4 + (threadIdx.x >> 6);   // over BHD*TSEQ
  int dd = threadIdx.x & 63;
  int bh = tok >> 11, t = tok & (TSEQ - 1);
  size_t base = (size_t)bh * NHASHK * TSEQ + t;
  float l0 = lg[base], l1 = lg[base + TSEQ], l2 = lg[base + 2 * TSEQ], l3 = lg[base + 3 * TSEQ];
  float m = fmaxf(fmaxf(l0, l1), fmaxf(l2, l3));
  float e0 = expf(l0 - m), e1 = expf(l1 - m), e2 = expf(l2 - m), e3 = expf(l3 - m);
  float inv = 1.0f / (e0 + e1 + e2 + e3);
  float o = (e0 * o4[base * 64 + dd] + e1 * o4[(base + TSEQ) * 64 + dd] +
             e2 * o4[(base + 2 * TSEQ) * 64 + dd] + e3 * o4[(base + 3 * TSEQ) * 64 + dd]) * inv;
  int b = bh >> 3, hh = bh & 7;
  size_t idx = ((size_t)(b * TSEQ + t)) * DIMM + hh * DHD + dd;
  u16 h2, l2q;
  split_bf16(o, h2, l2q);
  ctx_hi[idx] = h2;
  ctx_lo[idx] = l2q;
}

// ---------------- final LN stats on (x1+x2)/2 ----------------
__global__ __launch_bounds__(256) void k_final_stats(const float* __restrict__ x1, const float* __restrict__ x2,
                                                     float2* __restrict__ stats) {
  int row = blockIdx.x, tid = threadIdx.x;
  const float* p1 = x1 + (size_t)row * DIMM;
  const float* p2 = x2 + (size_t)row * DIMM;
  float v0 = 0.5f * (p1[tid] + p2[tid]);
  float v1 = 0.5f * (p1[tid + 256] + p2[tid + 256]);
  int lane = tid & 63, w = tid >> 6;
  __shared__ float red[8];
  float s = v0 + v1;
#pragma unroll
  for (int o = 32; o; o >>= 1) s += __shfl_xor(s, o);
  if (lane == 0) red[w] = s;
  __syncthreads();
  float mu = (red[0] + red[1] + red[2] + red[3]) * (1.0f / DIMM);
  float d0 = v0 - mu, d1 = v1 - mu;
  float q = d0 * d0 + d1 * d1;
#pragma unroll
  for (int o = 32; o; o >>= 1) q += __shfl_xor(q, o);
  if (lane == 0) red[4 + w] = q;
  __syncthreads();
  if (tid == 0) {
    float var = (red[4] + red[5] + red[6] + red[7]) * (1.0f / DIMM);
    stats[row] = make_float2(mu, 1.0f / sqrtf(var + 1e-5f));
  }
}

// ---------------- LN + mean over T, stage 1: 64 blocks of 64 rows ----------------
__global__ __launch_bounds__(256) void k_colmean1(const float* __restrict__ x1, const float* __restrict__ x2,
                                                  const float2* __restrict__ stats, float* __restrict__ part) {
  int blk = blockIdx.x;            // [0,64): bb*32 + ch
  int bb = blk >> 5, ch = blk & 31;
  int d = threadIdx.x;
  float a0 = 0.f, a1 = 0.f;
  for (int i = 0; i < 64; ++i) {
    int row = bb * TSEQ + (ch << 6) + i;
    float2 sr = stats[row];
    size_t base = (size_t)row * DIMM;
    a0 += (0.5f * (x1[base + d] + x2[base + d]) - sr.x) * sr.y;
    a1 += (0.5f * (x1[base + d + 256] + x2[base + d + 256]) - sr.x) * sr.y;
  }
  part[(size_t)blk * DIMM + d] = a0;
  part[(size_t)blk * DIMM + d + 256] = a1;
}

__global__ __launch_bounds__(256) void k_colmean2(const float* __restrict__ part,
                                                  const float* __restrict__ g, const float* __restrict__ b,
                                                  float* __restrict__ hm) {
  int idx = blockIdx.x * 256 + threadIdx.x;   // 1024
  int bb = idx >> 9, d = idx & 511;
  float s = 0.f;
  for (int c = 0; c < 32; ++c) s += part[(size_t)(bb * 32 + c) * DIMM + d];
  hm[idx] = s * (1.0f / TSEQ) * g[d] + b[d];
}

// ---------------- head ----------------
__global__ __launch_bounds__(256) void k_head1(const float* __restrict__ hm, const float* __restrict__ Wf1,
                                               const float* __restrict__ bf1, float* __restrict__ r1) {
  int b = blockIdx.x, j = threadIdx.x;   // 2 x 256
  float acc = 0;
  for (int k = 0; k < DIMM; ++k) acc += hm[b * DIMM + k] * Wf1[k * 256 + j];
  r1[b * 256 + j] = fmaxf(acc + bf1[j], 0.0f);
}

__global__ __launch_bounds__(256) void k_head2(const float* __restrict__ r1, const float* __restrict__ Wout,
                                               const float* __restrict__ bout, float* __restrict__ outp) {
  int b = blockIdx.x;
  int tid = threadIdx.x, lane = tid & 63, w = tid >> 6;
  float v = r1[b * 256 + tid] * Wout[tid];
#pragma unroll
  for (int o = 32; o; o >>= 1) v += __shfl_xor(v, o);
  __shared__ float red[4];
  if (lane == 0) red[w] = v;
  __syncthreads();
  if (tid == 0) outp[b] = red[0] + red[1] + red[2] + red[3] + bout[0];
}

extern "C" void kernel_launch(void* const* d_in, const int* in_sizes, int n_in,
                              void* d_out, int out_size, void* d_ws, size_t ws_size,
                              hipStream_t stream) {
  const int*   x         = (const int*)d_in[0];
  const float* token_emb = (const float*)d_in[1];
  const float* ln1_s     = (const float*)d_in[2];
  const float* ln1_b     = (const float*)d_in[3];
  const float* Wqk       = (const float*)d_in[4];
  const float* Wv        = (const float*)d_in[5];
  const float* Wo        = (const float*)d_in[6];
  const float* bo        = (const float*)d_in[7];
  const float* ln2_s     = (const float*)d_in[8];
  const float* ln2_b     = (const float*)d_in[9];
  const float* W1        = (const float*)d_in[10];
  const float* b1        = (const float*)d_in[11];
  const float* W2        = (const float*)d_in[12];
  const float* b2        = (const float*)d_in[13];
  const float* rotations = (const float*)d_in[14];
  const float* lnf_s     = (const float*)d_in[15];
  const float* lnf_b     = (const float*)d_in[16];
  const float* Wf1       = (const float*)d_in[17];
  const float* bf1       = (const float*)d_in[18];
  const float* Wout      = (const float*)d_in[19];
  const float* bout      = (const float*)d_in[20];
  float* out = (float*)d_out;

  char* ws = (char*)d_ws;
  size_t off = 0;
  auto alloc = [&](size_t nbytes) {
    char* p = ws + off;
    off += (nbytes + 255) & ~(size_t)255;
    return p;
  };
  float*    x1     = (float*)alloc((size_t)NROWS * DIMM * 4);
  float*    x2     = (float*)alloc((size_t)NROWS * DIMM * 4);
  u16*      xn_hi  = (u16*)alloc((size_t)NROWS * DIMM * 2);
  u16*      xn_lo  = (u16*)alloc((size_t)NROWS * DIMM * 2);
  unsigned* qk_hl  = (unsigned*)alloc((size_t)BHD * TSEQ * DHD * 4);
  unsigned* v_hl   = (unsigned*)alloc((size_t)BHD * TSEQ * DHD * 4);
  u16*      ffh_hi = (u16*)alloc((size_t)NROWS * FFD * 2);   // o4 aliases ffh_hi..ffh_lo (32MB fp32)
  u16*      ffh_lo = (u16*)alloc((size_t)NROWS * FFD * 2);
  float*    o4     = (float*)ffh_hi;
  float*    lg     = (float*)alloc((size_t)BHD * NHASHK * TSEQ * 4);
  float*    sin_t  = (float*)alloc((size_t)TSEQ * 32 * 4);
  float*    cos_t  = (float*)alloc((size_t)TSEQ * 32 * 4);
  float2*   stats  = (float2*)alloc((size_t)NROWS * 8);
  float*    part   = (float*)alloc((size_t)64 * DIMM * 4);
  float*    hm     = (float*)alloc(2 * DIMM * 4);
  float*    r1     = (float*)alloc(2 * 256 * 4);
  int*      bucket = (int*)alloc((size_t)BHD * NHASHK * TSEQ * 4);
  int*      st     = (int*)alloc((size_t)BHD * NHASHK * TSEQ * 4);
  const size_t OFF_WQK = 0;
  const size_t OFF_WV  = 512 * 512;
  const size_t OFF_WO  = 2 * 512 * 512;
  const size_t OFF_W1  = 3 * 512 * 512;
  const size_t OFF_W2  = 3 * 512 * 512 + 512 * 2048;
  const size_t WT_TOT  = 3 * 512 * 512 + 2 * 512 * 2048;
  u16*      wt_hi  = (u16*)alloc(WT_TOT * 2);
  u16*      wt_lo  = (u16*)alloc(WT_TOT * 2);
  u16*      rott_hi = (u16*)alloc(64 * 64 * 2);
  u16*      rott_lo = (u16*)alloc(64 * 64 * 2);
  u16*      ctx_hi = xn_hi;   // alias: lifetimes disjoint
  u16*      ctx_lo = xn_lo;

  k_embed<<<NROWS, 128, 0, stream>>>(x, token_emb, x1, x2);
  k_sincos<<<(TSEQ * 32) / 256, 256, 0, stream>>>(sin_t, cos_t);

  for (int L = 0; L < 4; ++L) {
    const float* wqk = Wqk + (size_t)L * DIMM * DIMM;
    const float* wv  = Wv  + (size_t)L * DIMM * DIMM;
    const float* wo  = Wo  + (size_t)L * DIMM * DIMM;
    const float* w1  = W1  + (size_t)L * DIMM * FFD;
    const float* w2  = W2  + (size_t)L * FFD * DIMM;
    const float* rot = rotations + (size_t)L * DHD * NHASHK * 16;

    k_tsplit<<<dim3(16, 16), 256, 0, stream>>>(wqk, wt_hi + OFF_WQK, wt_lo + OFF_WQK, 512, 512);
    k_tsplit<<<dim3(16, 16), 256, 0, stream>>>(wv,  wt_hi + OFF_WV,  wt_lo + OFF_WV,  512, 512);
    k_tsplit<<<dim3(16, 16), 256, 0, stream>>>(wo,  wt_hi + OFF_WO,  wt_lo + OFF_WO,  512, 512);
    k_tsplit<<<dim3(16, 64), 256, 0, stream>>>(w1,  wt_hi + OFF_W1,  wt_lo + OFF_W1,  512, 2048);
    k_tsplit<<<dim3(64, 16), 256, 0, stream>>>(w2,  wt_hi + OFF_W2,  wt_lo + OFF_W2,  2048, 512);
    k_tsplit<<<dim3(2, 2), 256, 0, stream>>>(rot, rott_hi, rott_lo, 64, 64);

    k_layernorm<<<NROWS, 256, 0, stream>>>(x2, ln1_s + L * DIMM, ln1_b + L * DIMM, xn_hi, xn_lo);
    dim3 g512(32, 8);
    k_gemm_mfma<64, 2><<<g512, 256, 0, stream>>>(xn_hi, xn_lo, wt_hi + OFF_WQK, wt_lo + OFF_WQK,
                                                 nullptr, nullptr, nullptr, nullptr, qk_hl, 512, 512, sin_t, cos_t);
    k_gemm_mfma<64, 3><<<g512, 256, 0, stream>>>(xn_hi, xn_lo, wt_hi + OFF_WV, wt_lo + OFF_WV,
                                                 nullptr, nullptr, nullptr, nullptr, v_hl, 512, 512, nullptr, nullptr);
    k_bucket_gemm<<<BHD * TSEQ / 128, 256, 0, stream>>>(qk_hl, rott_hi, rott_lo, bucket);
    k_sort<<<BHD * NHASHK, 256, 0, stream>>>(bucket, st);
    k_attn<<<BHD * CHUNKS, 256, 0, stream>>>(qk_hl, v_hl, st, o4, lg);
    k_combine<<<(BHD * TSEQ) / 4, 256, 0, stream>>>(o4, lg, ctx_hi, ctx_lo);
    k_gemm_mfma<64, 1><<<g512, 256, 0, stream>>>(ctx_hi, ctx_lo, wt_hi + OFF_WO, wt_lo + OFF_WO,
                                                 bo + L * DIMM, x1, nullptr, nullptr, nullptr, 512, 512, nullptr, nullptr);
    k_layernorm<<<NROWS, 256, 0, stream>>>(x1, ln2_s + L * DIMM, ln2_b + L * DIMM, xn_hi, xn_lo);
    dim3 gff1(32, 16);
    k_gemm_mfma<128, 4><<<gff1, 256, 0, stream>>>(xn_hi, xn_lo, wt_hi + OFF_W1, wt_lo + OFF_W1,
                                                  b1 + L * FFD, nullptr, ffh_hi, ffh_lo, nullptr, 512, 2048, nullptr, nullptr);
    dim3 gff2(32, 8);
    k_gemm_mfma<64, 1><<<gff2, 256, 0, stream>>>(ffh_hi, ffh_lo, wt_hi + OFF_W2, wt_lo + OFF_W2,
                                                 b2 + L * DIMM, x2, nullptr, nullptr, nullptr, 2048, 512, nullptr, nullptr);
  }

  k_final_stats<<<NROWS, 256, 0, stream>>>(x1, x2, stats);
  k_colmean1<<<64, 256, 0, stream>>>(x1, x2, stats, part);
  k_colmean2<<<4, 256, 0, stream>>>(part, lnf_s, lnf_b, hm);
  k_head1<<<2, 256, 0, stream>>>(hm, Wf1, bf1, r1);
  k_head2<<<2, 256, 0, stream>>>(r1, Wout, bout, out);
}

// Round 4
// 900.529 us; speedup vs baseline: 3.7681x; 1.1533x over previous
//
#include <hip/hip_runtime.h>
#include <math.h>

#define TSEQ   2048
#define DIMM   512
#define NHEAD  8
#define DHD    64
#define BHD    16      // BATCH*HEADS
#define NHASHK 4
#define CHUNKS 128     // NHASHK * (TSEQ/64)
#define FFD    2048
#define NROWS  4096    // BATCH*TSEQ

#define OFF_WQK 0
#define OFF_WV  262144
#define OFF_WO  524288
#define OFF_W1  786432
#define OFF_W2  1835008
#define WT_TOT  2883584

typedef unsigned short u16;
typedef __attribute__((ext_vector_type(8))) short bf16x8;
typedef __attribute__((ext_vector_type(4))) float f32x4;
typedef __attribute__((ext_vector_type(8))) unsigned short ushort8v;
typedef __attribute__((ext_vector_type(4))) unsigned short ushort4v;

__device__ inline u16 bf16_hi(float f) {
  unsigned u = __float_as_uint(f);
  unsigned r = u + 0x7fffu + ((u >> 16) & 1u);
  return (u16)(r >> 16);
}
__device__ inline void split_bf16(float f, u16& h, u16& l) {
  h = bf16_hi(f);
  float fh = __uint_as_float(((unsigned)h) << 16);
  l = bf16_hi(f - fh);
}
__device__ inline bf16x8 mk8(unsigned a, unsigned b, unsigned c, unsigned d) {
  union { unsigned u[4]; bf16x8 v; } x;
  x.u[0] = a; x.u[1] = b; x.u[2] = c; x.u[3] = d;
  return x.v;
}
__device__ inline float unpack_hl(unsigned u) {
  return __uint_as_float(u & 0xffff0000u) + __uint_as_float(u << 16);
}
__device__ inline float gelu_exact(float v) {
  return 0.5f * v * (1.0f + erff(v * 0.70710678118654752f));
}

// ---------------- embed ----------------
__global__ __launch_bounds__(128) void k_embed(const int* __restrict__ x, const float* __restrict__ emb,
                                               float* __restrict__ x1, float* __restrict__ x2) {
  int row = blockIdx.x;
  int tok = x[row];
  float4 v = ((const float4*)(emb + (size_t)tok * DIMM))[threadIdx.x];
  ((float4*)(x1 + (size_t)row * DIMM))[threadIdx.x] = v;
  ((float4*)(x2 + (size_t)row * DIMM))[threadIdx.x] = v;
}

// ---------------- sin/cos tables ----------------
__global__ __launch_bounds__(256) void k_sincos(float* __restrict__ sin_t, float* __restrict__ cos_t) {
  int idx = blockIdx.x * 256 + threadIdx.x;   // TSEQ*32
  int t = idx >> 5, i = idx & 31;
  float inv = powf(10000.0f, -(float)(2 * i) / 64.0f);
  float ang = (float)t * inv;
  sin_t[idx] = sinf(ang);
  cos_t[idx] = cosf(ang);
}

// ---------------- layernorm (row = 512) -> bf16 hi/lo ----------------
__global__ __launch_bounds__(256) void k_layernorm(const float* __restrict__ x, const float* __restrict__ g,
                                                   const float* __restrict__ b,
                                                   u16* __restrict__ hi, u16* __restrict__ lo) {
  int row = blockIdx.x, tid = threadIdx.x;
  const float* xr = x + (size_t)row * DIMM;
  float v0 = xr[tid], v1 = xr[tid + 256];
  int lane = tid & 63, w = tid >> 6;
  __shared__ float red[8];
  float s = v0 + v1;
#pragma unroll
  for (int o = 32; o; o >>= 1) s += __shfl_xor(s, o);
  if (lane == 0) red[w] = s;
  __syncthreads();
  float mu = (red[0] + red[1] + red[2] + red[3]) * (1.0f / DIMM);
  float d0 = v0 - mu, d1 = v1 - mu;
  float q = d0 * d0 + d1 * d1;
#pragma unroll
  for (int o = 32; o; o >>= 1) q += __shfl_xor(q, o);
  if (lane == 0) red[4 + w] = q;
  __syncthreads();
  float var = (red[4] + red[5] + red[6] + red[7]) * (1.0f / DIMM);
  float rstd = 1.0f / sqrtf(var + 1e-5f);
  float y0 = d0 * rstd * g[tid] + b[tid];
  float y1 = d1 * rstd * g[tid + 256] + b[tid + 256];
  u16 h0, l0, h1, l1;
  split_bf16(y0, h0, l0);
  split_bf16(y1, h1, l1);
  size_t base = (size_t)row * DIMM;
  hi[base + tid] = h0; lo[base + tid] = l0;
  hi[base + tid + 256] = h1; lo[base + tid + 256] = l1;
}

// ---------------- fused per-layer weight prep: transpose + bf16 split ----------------
// tiles: qk/v/wo (3 x 256) | w1 (1024) | w2 (1024) | rot (4)  => 2820 blocks
__global__ __launch_bounds__(256) void k_prep(const float* __restrict__ Wqk, const float* __restrict__ Wv,
                                              const float* __restrict__ Wo, const float* __restrict__ W1,
                                              const float* __restrict__ W2, const float* __restrict__ rot,
                                              u16* __restrict__ wt_hi, u16* __restrict__ wt_lo,
                                              u16* __restrict__ rt_hi, u16* __restrict__ rt_lo) {
  __shared__ float tile[32][33];
  const int idx = blockIdx.x;
  const float* src;
  u16 *dh, *dl;
  int K, N, k0, n0;
  if (idx < 768) {
    int w = idx >> 8, r = idx & 255;
    K = 512; N = 512; k0 = (r >> 4) << 5; n0 = (r & 15) << 5;
    src = (w == 0) ? Wqk : (w == 1) ? Wv : Wo;
    size_t off = (size_t)w * 262144;
    dh = wt_hi + off; dl = wt_lo + off;
  } else if (idx < 1792) {
    int r = idx - 768;
    K = 512; N = 2048; k0 = (r >> 6) << 5; n0 = (r & 63) << 5;
    src = W1; dh = wt_hi + OFF_W1; dl = wt_lo + OFF_W1;
  } else if (idx < 2816) {
    int r = idx - 1792;
    K = 2048; N = 512; k0 = (r >> 4) << 5; n0 = (r & 15) << 5;
    src = W2; dh = wt_hi + OFF_W2; dl = wt_lo + OFF_W2;
  } else {
    int r = idx - 2816;
    K = 64; N = 64; k0 = (r >> 1) << 5; n0 = (r & 1) << 5;
    src = rot; dh = rt_hi; dl = rt_lo;
  }
  const int t = threadIdx.x;
  const int r = t >> 3, c4 = (t & 7) << 2;
  float4 v = *(const float4*)&src[(size_t)(k0 + r) * N + n0 + c4];
  tile[r][c4] = v.x; tile[r][c4 + 1] = v.y; tile[r][c4 + 2] = v.z; tile[r][c4 + 3] = v.w;
  __syncthreads();
  u16 hs[4], ls[4];
#pragma unroll
  for (int i = 0; i < 4; ++i) split_bf16(tile[c4 + i][r], hs[i], ls[i]);
  size_t o = (size_t)(n0 + r) * K + k0 + c4;
  *(ushort4v*)&dh[o] = (ushort4v){hs[0], hs[1], hs[2], hs[3]};
  *(ushort4v*)&dl[o] = (ushort4v){ls[0], ls[1], ls[2], ls[3]};
}

// ---------------- split-bf16 MFMA GEMM: C = A[M][K] * B^T (Bt[N][K]) ----------------
// BM = 64 or 128 (BN fixed 64), 4 waves. Register-prefetched K loop, LDS stride 36.
// STORE: 1 = out += val + bias (residual);  4 = gelu(val+bias) -> bf16 hi/lo
//        5 = fused QKV: gn<512 -> rotary -> qk_hl packed; gn>=512 -> v_hl packed
template <int BM, int STORE>
__global__ __launch_bounds__(256) void k_gemm64(
    const u16* __restrict__ Ahi, const u16* __restrict__ Alo,
    const u16* __restrict__ Bhi, const u16* __restrict__ Blo,
    const float* __restrict__ bias, float* __restrict__ out,
    u16* __restrict__ out_hi, u16* __restrict__ out_lo,
    unsigned* __restrict__ qk_u, unsigned* __restrict__ v_u,
    int K, int N,
    const float* __restrict__ sin_t, const float* __restrict__ cos_t) {
  constexpr int MF = BM / 32;   // m-frags per wave
  constexpr int NA = BM / 64;   // A-chunks per thread per tile
  __shared__ __align__(16) u16 As_hi[BM][36];
  __shared__ __align__(16) u16 As_lo[BM][36];
  __shared__ __align__(16) u16 Bs_hi[64][36];
  __shared__ __align__(16) u16 Bs_lo[64][36];
  const int bm = blockIdx.x * BM, bn = blockIdx.y << 6;
  const int tid = threadIdx.x, lane = tid & 63, wid = tid >> 6;
  const int wm = (wid >> 1) * (BM / 2), wn = (wid & 1) << 5;
  const int l16 = lane & 15, g = lane >> 4;
  f32x4 acc[MF][2];
#pragma unroll
  for (int m = 0; m < MF; ++m) { acc[m][0] = (f32x4){0,0,0,0}; acc[m][1] = (f32x4){0,0,0,0}; }

  const int sr = tid >> 2, sc = (tid & 3) << 3;
  const u16* aph = Ahi + (size_t)(bm + sr) * K + sc;
  const u16* apl = Alo + (size_t)(bm + sr) * K + sc;
  const u16* bph = Bhi + (size_t)(bn + sr) * K + sc;
  const u16* bpl = Blo + (size_t)(bn + sr) * K + sc;

  ushort8v pa_h[NA], pa_l[NA], pb_h, pb_l;
#pragma unroll
  for (int i = 0; i < NA; ++i) {
    pa_h[i] = *(const ushort8v*)(aph + (size_t)(i << 6) * K);
    pa_l[i] = *(const ushort8v*)(apl + (size_t)(i << 6) * K);
  }
  pb_h = *(const ushort8v*)bph;
  pb_l = *(const ushort8v*)bpl;

  for (int k0 = 0;;) {
#pragma unroll
    for (int i = 0; i < NA; ++i) {
      *(ushort8v*)&As_hi[sr + (i << 6)][sc] = pa_h[i];
      *(ushort8v*)&As_lo[sr + (i << 6)][sc] = pa_l[i];
    }
    *(ushort8v*)&Bs_hi[sr][sc] = pb_h;
    *(ushort8v*)&Bs_lo[sr][sc] = pb_l;
    __syncthreads();
    const int kn = k0 + 32;
    if (kn < K) {   // prefetch next tile while computing this one
#pragma unroll
      for (int i = 0; i < NA; ++i) {
        pa_h[i] = *(const ushort8v*)(aph + (size_t)(i << 6) * K + kn);
        pa_l[i] = *(const ushort8v*)(apl + (size_t)(i << 6) * K + kn);
      }
      pb_h = *(const ushort8v*)(bph + kn);
      pb_l = *(const ushort8v*)(bpl + kn);
    }
    bf16x8 a_h[MF], a_l[MF], b_h[2], b_l[2];
#pragma unroll
    for (int m = 0; m < MF; ++m) {
      a_h[m] = *(const bf16x8*)&As_hi[wm + (m << 4) + l16][g << 3];
      a_l[m] = *(const bf16x8*)&As_lo[wm + (m << 4) + l16][g << 3];
    }
#pragma unroll
    for (int n = 0; n < 2; ++n) {
      b_h[n] = *(const bf16x8*)&Bs_hi[wn + (n << 4) + l16][g << 3];
      b_l[n] = *(const bf16x8*)&Bs_lo[wn + (n << 4) + l16][g << 3];
    }
#pragma unroll
    for (int m = 0; m < MF; ++m)
#pragma unroll
      for (int n = 0; n < 2; ++n) {
        acc[m][n] = __builtin_amdgcn_mfma_f32_16x16x32_bf16(a_h[m], b_h[n], acc[m][n], 0, 0, 0);
        acc[m][n] = __builtin_amdgcn_mfma_f32_16x16x32_bf16(a_h[m], b_l[n], acc[m][n], 0, 0, 0);
        acc[m][n] = __builtin_amdgcn_mfma_f32_16x16x32_bf16(a_l[m], b_h[n], acc[m][n], 0, 0, 0);
      }
    if (kn >= K) break;
    __syncthreads();
    k0 = kn;
  }
  // epilogue (C/D: col = lane&15 -> B rows, row = (lane>>4)*4 + reg -> A rows)
#pragma unroll
  for (int m = 0; m < MF; ++m) {
#pragma unroll
    for (int n = 0; n < 2; ++n) {
      const int gn = bn + wn + (n << 4) + l16;
      float bv = 0.f;
      if (STORE == 1 || STORE == 4) bv = bias[gn];
#pragma unroll
      for (int r = 0; r < 4; ++r) {
        const int gm = bm + wm + (m << 4) + (g << 2) + r;
        float val = acc[m][n][r];
        if (STORE == 1) {
          out[(size_t)gm * N + gn] += val + bv;
        } else if (STORE == 4) {
          float gv = gelu_exact(val + bv);
          u16 hx, lx;
          split_bf16(gv, hx, lx);
          out_hi[(size_t)gm * N + gn] = hx;
          out_lo[(size_t)gm * N + gn] = lx;
        } else {  // STORE == 5
          const float pv = __shfl_xor(val, 1);
          const int bb = gm >> 11, tt = gm & (TSEQ - 1);
          if (gn < 512) {
            const int hh = gn >> 6, dd = gn & 63;
            const int ip = dd >> 1;
            float cz = cos_t[tt * 32 + ip], sz = sin_t[tt * 32 + ip];
            float o = (dd & 1) ? (val * cz + pv * sz) : (val * cz - pv * sz);
            u16 hx, lx;
            split_bf16(o, hx, lx);
            qk_u[((size_t)((bb * NHEAD + hh) * TSEQ + tt)) * DHD + dd] = ((unsigned)hx << 16) | lx;
          } else {
            const int gnn = gn - 512;
            const int hh = gnn >> 6, dd = gnn & 63;
            u16 hx, lx;
            split_bf16(val, hx, lx);
            v_u[((size_t)((bb * NHEAD + hh) * TSEQ + tt)) * DHD + dd] = ((unsigned)hx << 16) | lx;
          }
        }
      }
    }
  }
}

// ---------------- LSH bucket via MFMA: rv = qk @ rot^T, fused argmax ----------------
__global__ __launch_bounds__(256) void k_bucket_gemm(const unsigned* __restrict__ qk_hl,
                                                     const u16* __restrict__ Rhi, const u16* __restrict__ Rlo,
                                                     int* __restrict__ bucket) {
  __shared__ __align__(16) u16 Ahi[128][72];
  __shared__ __align__(16) u16 Alo[128][72];
  __shared__ __align__(16) u16 Bh[64][72];
  __shared__ __align__(16) u16 Bl[64][72];
  const int bm = blockIdx.x << 7;
  const int tid = threadIdx.x, lane = tid & 63, wid = tid >> 6;
  const int l16 = lane & 15, g = lane >> 4;
  {
    const int r = tid >> 1, hf = tid & 1;
    const unsigned* src = qk_hl + (size_t)(bm + r) * 64 + hf * 32;
#pragma unroll
    for (int i = 0; i < 8; ++i) {
      uint4 u = ((const uint4*)src)[i];
      unsigned hw0 = (u.x >> 16) | (u.y & 0xffff0000u);
      unsigned lw0 = (u.x & 0xffffu) | (u.y << 16);
      unsigned hw1 = (u.z >> 16) | (u.w & 0xffff0000u);
      unsigned lw1 = (u.z & 0xffffu) | (u.w << 16);
      int colb = hf * 32 + i * 4;
      *(uint2*)&Ahi[r][colb] = make_uint2(hw0, hw1);
      *(uint2*)&Alo[r][colb] = make_uint2(lw0, lw1);
    }
  }
  if (tid < 128) {
    const int r = tid >> 1, hf = tid & 1;
#pragma unroll
    for (int i = 0; i < 4; ++i) {
      *(ushort8v*)&Bh[r][hf * 32 + i * 8] = *(const ushort8v*)&Rhi[r * 64 + hf * 32 + i * 8];
      *(ushort8v*)&Bl[r][hf * 32 + i * 8] = *(const ushort8v*)&Rlo[r * 64 + hf * 32 + i * 8];
    }
  }
  __syncthreads();
  const int wm = (wid >> 1) << 6, wn = (wid & 1) << 5;
  f32x4 acc[4][2];
#pragma unroll
  for (int m = 0; m < 4; ++m) { acc[m][0] = (f32x4){0,0,0,0}; acc[m][1] = (f32x4){0,0,0,0}; }
#pragma unroll
  for (int s = 0; s < 2; ++s) {
    bf16x8 bhf[2], blf[2];
#pragma unroll
    for (int n = 0; n < 2; ++n) {
      bhf[n] = *(const bf16x8*)&Bh[wn + (n << 4) + l16][s * 32 + g * 8];
      blf[n] = *(const bf16x8*)&Bl[wn + (n << 4) + l16][s * 32 + g * 8];
    }
#pragma unroll
    for (int m = 0; m < 4; ++m) {
      bf16x8 ah = *(const bf16x8*)&Ahi[wm + (m << 4) + l16][s * 32 + g * 8];
      bf16x8 al = *(const bf16x8*)&Alo[wm + (m << 4) + l16][s * 32 + g * 8];
#pragma unroll
      for (int n = 0; n < 2; ++n) {
        acc[m][n] = __builtin_amdgcn_mfma_f32_16x16x32_bf16(ah, bhf[n], acc[m][n], 0, 0, 0);
        acc[m][n] = __builtin_amdgcn_mfma_f32_16x16x32_bf16(ah, blf[n], acc[m][n], 0, 0, 0);
        acc[m][n] = __builtin_amdgcn_mfma_f32_16x16x32_bf16(al, bhf[n], acc[m][n], 0, 0, 0);
      }
    }
  }
#pragma unroll
  for (int m = 0; m < 4; ++m)
#pragma unroll
    for (int n = 0; n < 2; ++n) {
      const int hcol = (wn >> 4) + n;
#pragma unroll
      for (int r = 0; r < 4; ++r) {
        float v = acc[m][n][r];
        float best = v; int bi = l16;
        if (-v > best) { best = -v; bi = 16 + l16; }
#pragma unroll
        for (int o = 1; o < 16; o <<= 1) {
          float ob = __shfl_xor(best, o);
          int obi = __shfl_xor(bi, o);
          if (ob > best || (ob == best && obi < bi)) { best = ob; bi = obi; }
        }
        if (l16 == 0) {
          int gm = bm + wm + (m << 4) + (g << 2) + r;
          int bh_ = gm >> 11, t = gm & (TSEQ - 1);
          bucket[((size_t)(bh_ * NHASHK) + hcol) * TSEQ + t] = bi;
        }
      }
    }
}

// ---------------- stable counting sort per (bh,h): 32 buckets, 2048 items ----------------
__global__ __launch_bounds__(256) void k_sort(const int* __restrict__ bucket, int* __restrict__ st) {
  __shared__ int hist[256][33];
  __shared__ int bbase[32];
  const int seg = blockIdx.x;
  const int tid = threadIdx.x;
  const int* bk = bucket + (size_t)seg * TSEQ;
  int4 u0 = *(const int4*)(bk + tid * 8);
  int4 u1 = *(const int4*)(bk + tid * 8 + 4);
  int myb[8] = {u0.x, u0.y, u0.z, u0.w, u1.x, u1.y, u1.z, u1.w};
#pragma unroll
  for (int j = 0; j < 33; ++j) hist[tid][j] = 0;
  __syncthreads();
#pragma unroll
  for (int i = 0; i < 8; ++i) hist[tid][myb[i]]++;
  __syncthreads();
  if (tid < 32) {
    int run = 0;
    for (int gq = 0; gq < 256; ++gq) { int c = hist[gq][tid]; hist[gq][tid] = run; run += c; }
    bbase[tid] = run;
  }
  __syncthreads();
  if (tid == 0) {
    int s = 0;
    for (int j = 0; j < 32; ++j) { int c = bbase[j]; bbase[j] = s; s += c; }
  }
  __syncthreads();
  int* dst = st + (size_t)seg * TSEQ;
#pragma unroll
  for (int i = 0; i < 8; ++i) {
    int b = myb[i];
    int p = bbase[b] + hist[tid][b];
    hist[tid][b]++;
    dst[p] = tid * 8 + i;
  }
}

// ---------------- chunked LSH attention (MFMA) ----------------
__global__ __launch_bounds__(256) void k_attn(const unsigned* __restrict__ qk_hl,
                                              const unsigned* __restrict__ v_hl,
                                              const int* __restrict__ st,
                                              float* __restrict__ o4, float* __restrict__ lg) {
  __shared__ __align__(16) u16 Khi[128][72];
  __shared__ __align__(16) u16 Klo[128][72];
  __shared__ float inv_norm[128];
  __shared__ int tids[128];
  __shared__ float pn[256];
  const int blk = blockIdx.x;
  const int c = blk & (CHUNKS - 1), bh = blk >> 7;
  const int h = c >> 5;
  const int tid = threadIdx.x, lane = tid & 63, wid = tid >> 6;
  const int l16 = lane & 15, g = lane >> 4;

  if (tid < 128) {
    int cc = (tid < 64) ? c : ((c + CHUNKS - 1) & (CHUNKS - 1));
    tids[tid] = st[bh * (NHASHK * TSEQ) + cc * 64 + (tid & 63)];
  }
  __syncthreads();
  {
    const int r = tid >> 1, hf = tid & 1;
    const unsigned* src = qk_hl + ((size_t)bh * TSEQ + tids[r]) * 64 + hf * 32;
    float ss = 0.f;
#pragma unroll
    for (int i = 0; i < 8; ++i) {
      uint4 u = ((const uint4*)src)[i];
      unsigned hw0 = (u.x >> 16) | (u.y & 0xffff0000u);
      unsigned lw0 = (u.x & 0xffffu) | (u.y << 16);
      unsigned hw1 = (u.z >> 16) | (u.w & 0xffff0000u);
      unsigned lw1 = (u.z & 0xffffu) | (u.w << 16);
      int colb = hf * 32 + i * 4;
      *(uint2*)&Khi[r][colb] = make_uint2(hw0, hw1);
      *(uint2*)&Klo[r][colb] = make_uint2(lw0, lw1);
      float f0 = unpack_hl(u.x), f1 = unpack_hl(u.y), f2 = unpack_hl(u.z), f3 = unpack_hl(u.w);
      ss += f0 * f0 + f1 * f1 + f2 * f2 + f3 * f3;
    }
    pn[tid] = ss;
  }
  __syncthreads();
  if (tid < 128) {
    float s2 = pn[2 * tid] + pn[2 * tid + 1];
    inv_norm[tid] = 1.0f / fmaxf(sqrtf(s2), 1e-12f);
  }
  __syncthreads();

  const int q0 = wid << 4;
  const int qrow = q0 + l16;
  const int tq = tids[qrow];
  const size_t obase = (size_t)(bh * NHASHK + h) * TSEQ + tq;

  f32x4 accs[8];
#pragma unroll
  for (int i = 0; i < 8; ++i) accs[i] = (f32x4){0, 0, 0, 0};
#pragma unroll
  for (int s = 0; s < 2; ++s) {
    bf16x8 qh = *(const bf16x8*)&Khi[qrow][s * 32 + g * 8];
    bf16x8 ql = *(const bf16x8*)&Klo[qrow][s * 32 + g * 8];
#pragma unroll
    for (int mf = 0; mf < 8; ++mf) {
      bf16x8 ah = *(const bf16x8*)&Khi[mf * 16 + l16][s * 32 + g * 8];
      bf16x8 al = *(const bf16x8*)&Klo[mf * 16 + l16][s * 32 + g * 8];
      accs[mf] = __builtin_amdgcn_mfma_f32_16x16x32_bf16(ah, qh, accs[mf], 0, 0, 0);
      accs[mf] = __builtin_amdgcn_mfma_f32_16x16x32_bf16(ah, ql, accs[mf], 0, 0, 0);
      accs[mf] = __builtin_amdgcn_mfma_f32_16x16x32_bf16(al, qh, accs[mf], 0, 0, 0);
    }
  }
  float pv[8][4];
  float mx = -3e38f;
#pragma unroll
  for (int mf = 0; mf < 8; ++mf) {
    float4 invn = *(const float4*)&inv_norm[mf * 16 + g * 4];
    int4 tk = *(const int4*)&tids[mf * 16 + g * 4];
    float inva[4] = {invn.x, invn.y, invn.z, invn.w};
    int tka[4] = {tk.x, tk.y, tk.z, tk.w};
#pragma unroll
    for (int r = 0; r < 4; ++r) {
      float d = accs[mf][r] * inva[r] * 0.125f;
      if (tka[r] == tq) d = -5e4f;
      pv[mf][r] = d;
      mx = fmaxf(mx, d);
    }
  }
  mx = fmaxf(mx, __shfl_xor(mx, 16));
  mx = fmaxf(mx, __shfl_xor(mx, 32));
  float sum = 0.f;
#pragma unroll
  for (int mf = 0; mf < 8; ++mf)
#pragma unroll
    for (int r = 0; r < 4; ++r) {
      float e = __expf(pv[mf][r] - mx);
      pv[mf][r] = e;
      sum += e;
    }
  sum += __shfl_xor(sum, 16);
  sum += __shfl_xor(sum, 32);
  float lse = __logf(sum) + mx;
  float rs = 1.0f / sum;
  if (g == 0) lg[obase] = lse;
  unsigned P2h[8][2], P2l[8][2];
#pragma unroll
  for (int mf = 0; mf < 8; ++mf)
#pragma unroll
    for (int m = 0; m < 2; ++m) {
      float p0 = pv[mf][2 * m] * rs, p1 = pv[mf][2 * m + 1] * rs;
      u16 h0, l0, h1, l1;
      split_bf16(p0, h0, l0);
      split_bf16(p1, h1, l1);
      P2h[mf][m] = (unsigned)h0 | ((unsigned)h1 << 16);
      P2l[mf][m] = (unsigned)l0 | ((unsigned)l1 << 16);
    }
  f32x4 acco[4];
#pragma unroll
  for (int i = 0; i < 4; ++i) acco[i] = (f32x4){0, 0, 0, 0};
  const unsigned* vbase = v_hl + (size_t)bh * TSEQ * 64;
#pragma unroll
  for (int s = 0; s < 4; ++s) {
    unsigned bhw[4], blw[4];
#pragma unroll
    for (int w = 0; w < 4; ++w) {
      int srl = l16 + (((2 * g + (w >> 1)) & 3) << 4);
      unsigned a0 = __shfl(P2h[2 * s][w & 1], srl);
      unsigned a1 = __shfl(P2h[2 * s + 1][w & 1], srl);
      bhw[w] = (g >> 1) ? a1 : a0;
      unsigned b0 = __shfl(P2l[2 * s][w & 1], srl);
      unsigned b1 = __shfl(P2l[2 * s + 1][w & 1], srl);
      blw[w] = (g >> 1) ? b1 : b0;
    }
    bf16x8 pb_h = mk8(bhw[0], bhw[1], bhw[2], bhw[3]);
    bf16x8 pb_l = mk8(blw[0], blw[1], blw[2], blw[3]);
    int4 t0 = *(const int4*)&tids[s * 32 + g * 8];
    int4 t1 = *(const int4*)&tids[s * 32 + g * 8 + 4];
    int ro[8] = {t0.x, t0.y, t0.z, t0.w, t1.x, t1.y, t1.z, t1.w};
#pragma unroll
    for (int mf = 0; mf < 4; ++mf) {
      const int dcol = mf * 16 + l16;
      unsigned vw[8];
#pragma unroll
      for (int j = 0; j < 8; ++j) vw[j] = vbase[(size_t)ro[j] * 64 + dcol];
      unsigned vhh[4], vll[4];
#pragma unroll
      for (int w = 0; w < 4; ++w) {
        vhh[w] = (vw[2 * w] >> 16) | (vw[2 * w + 1] & 0xffff0000u);
        vll[w] = (vw[2 * w] & 0xffffu) | (vw[2 * w + 1] << 16);
      }
      bf16x8 vh8 = mk8(vhh[0], vhh[1], vhh[2], vhh[3]);
      bf16x8 vl8 = mk8(vll[0], vll[1], vll[2], vll[3]);
      acco[mf] = __builtin_amdgcn_mfma_f32_16x16x32_bf16(vh8, pb_h, acco[mf], 0, 0, 0);
      acco[mf] = __builtin_amdgcn_mfma_f32_16x16x32_bf16(vh8, pb_l, acco[mf], 0, 0, 0);
      acco[mf] = __builtin_amdgcn_mfma_f32_16x16x32_bf16(vl8, pb_h, acco[mf], 0, 0, 0);
    }
  }
#pragma unroll
  for (int mf = 0; mf < 4; ++mf)
    *(float4*)&o4[obase * 64 + mf * 16 + g * 4] =
        make_float4(acco[mf][0], acco[mf][1], acco[mf][2], acco[mf][3]);
}

// ---------------- combine hash rounds -> ctx bf16 hi/lo [B,T,512] ----------------
__global__ __launch_bounds__(256) void k_combine(const float* __restrict__ o4, const float* __restrict__ lg,
                                                 u16* __restrict__ ctx_hi, u16* __restrict__ ctx_lo) {
  int tok = blockIdx.x * 4 + (threadIdx.x >> 6);   // over BHD*TSEQ
  int dd = threadIdx.x & 63;
  int bh = tok >> 11, t = tok & (TSEQ - 1);
  size_t base = (size_t)bh * NHASHK * TSEQ + t;
  float l0 = lg[base], l1 = lg[base + TSEQ], l2 = lg[base + 2 * TSEQ], l3 = lg[base + 3 * TSEQ];
  float m = fmaxf(fmaxf(l0, l1), fmaxf(l2, l3));
  float e0 = expf(l0 - m), e1 = expf(l1 - m), e2 = expf(l2 - m), e3 = expf(l3 - m);
  float inv = 1.0f / (e0 + e1 + e2 + e3);
  float o = (e0 * o4[base * 64 + dd] + e1 * o4[(base + TSEQ) * 64 + dd] +
             e2 * o4[(base + 2 * TSEQ) * 64 + dd] + e3 * o4[(base + 3 * TSEQ) * 64 + dd]) * inv;
  int b = bh >> 3, hh = bh & 7;
  size_t idx = ((size_t)(b * TSEQ + t)) * DIMM + hh * DHD + dd;
  u16 h2, l2q;
  split_bf16(o, h2, l2q);
  ctx_hi[idx] = h2;
  ctx_lo[idx] = l2q;
}

// ---------------- final LN stats on (x1+x2)/2 ----------------
__global__ __launch_bounds__(256) void k_final_stats(const float* __restrict__ x1, const float* __restrict__ x2,
                                                     float2* __restrict__ stats) {
  int row = blockIdx.x, tid = threadIdx.x;
  const float* p1 = x1 + (size_t)row * DIMM;
  const float* p2 = x2 + (size_t)row * DIMM;
  float v0 = 0.5f * (p1[tid] + p2[tid]);
  float v1 = 0.5f * (p1[tid + 256] + p2[tid + 256]);
  int lane = tid & 63, w = tid >> 6;
  __shared__ float red[8];
  float s = v0 + v1;
#pragma unroll
  for (int o = 32; o; o >>= 1) s += __shfl_xor(s, o);
  if (lane == 0) red[w] = s;
  __syncthreads();
  float mu = (red[0] + red[1] + red[2] + red[3]) * (1.0f / DIMM);
  float d0 = v0 - mu, d1 = v1 - mu;
  float q = d0 * d0 + d1 * d1;
#pragma unroll
  for (int o = 32; o; o >>= 1) q += __shfl_xor(q, o);
  if (lane == 0) red[4 + w] = q;
  __syncthreads();
  if (tid == 0) {
    float var = (red[4] + red[5] + red[6] + red[7]) * (1.0f / DIMM);
    stats[row] = make_float2(mu, 1.0f / sqrtf(var + 1e-5f));
  }
}

// ---------------- LN + mean over T, stage 1: 64 blocks of 64 rows ----------------
__global__ __launch_bounds__(256) void k_colmean1(const float* __restrict__ x1, const float* __restrict__ x2,
                                                  const float2* __restrict__ stats, float* __restrict__ part) {
  int blk = blockIdx.x;            // [0,64): bb*32 + ch
  int bb = blk >> 5, ch = blk & 31;
  int d = threadIdx.x;
  float a0 = 0.f, a1 = 0.f;
  for (int i = 0; i < 64; ++i) {
    int row = bb * TSEQ + (ch << 6) + i;
    float2 sr = stats[row];
    size_t base = (size_t)row * DIMM;
    a0 += (0.5f * (x1[base + d] + x2[base + d]) - sr.x) * sr.y;
    a1 += (0.5f * (x1[base + d + 256] + x2[base + d + 256]) - sr.x) * sr.y;
  }
  part[(size_t)blk * DIMM + d] = a0;
  part[(size_t)blk * DIMM + d + 256] = a1;
}

__global__ __launch_bounds__(256) void k_colmean2(const float* __restrict__ part,
                                                  const float* __restrict__ g, const float* __restrict__ b,
                                                  float* __restrict__ hm) {
  int idx = blockIdx.x * 256 + threadIdx.x;   // 1024
  int bb = idx >> 9, d = idx & 511;
  float s = 0.f;
  for (int c = 0; c < 32; ++c) s += part[(size_t)(bb * 32 + c) * DIMM + d];
  hm[idx] = s * (1.0f / TSEQ) * g[d] + b[d];
}

// ---------------- head ----------------
__global__ __launch_bounds__(256) void k_head1(const float* __restrict__ hm, const float* __restrict__ Wf1,
                                               const float* __restrict__ bf1, float* __restrict__ r1) {
  int b = blockIdx.x, j = threadIdx.x;   // 2 x 256
  float acc = 0;
  for (int k = 0; k < DIMM; ++k) acc += hm[b * DIMM + k] * Wf1[k * 256 + j];
  r1[b * 256 + j] = fmaxf(acc + bf1[j], 0.0f);
}

__global__ __launch_bounds__(256) void k_head2(const float* __restrict__ r1, const float* __restrict__ Wout,
                                               const float* __restrict__ bout, float* __restrict__ outp) {
  int b = blockIdx.x;
  int tid = threadIdx.x, lane = tid & 63, w = tid >> 6;
  float v = r1[b * 256 + tid] * Wout[tid];
#pragma unroll
  for (int o = 32; o; o >>= 1) v += __shfl_xor(v, o);
  __shared__ float red[4];
  if (lane == 0) red[w] = v;
  __syncthreads();
  if (tid == 0) outp[b] = red[0] + red[1] + red[2] + red[3] + bout[0];
}

extern "C" void kernel_launch(void* const* d_in, const int* in_sizes, int n_in,
                              void* d_out, int out_size, void* d_ws, size_t ws_size,
                              hipStream_t stream) {
  const int*   x         = (const int*)d_in[0];
  const float* token_emb = (const float*)d_in[1];
  const float* ln1_s     = (const float*)d_in[2];
  const float* ln1_b     = (const float*)d_in[3];
  const float* Wqk       = (const float*)d_in[4];
  const float* Wv        = (const float*)d_in[5];
  const float* Wo        = (const float*)d_in[6];
  const float* bo        = (const float*)d_in[7];
  const float* ln2_s     = (const float*)d_in[8];
  const float* ln2_b     = (const float*)d_in[9];
  const float* W1        = (const float*)d_in[10];
  const float* b1        = (const float*)d_in[11];
  const float* W2        = (const float*)d_in[12];
  const float* b2        = (const float*)d_in[13];
  const float* rotations = (const float*)d_in[14];
  const float* lnf_s     = (const float*)d_in[15];
  const float* lnf_b     = (const float*)d_in[16];
  const float* Wf1       = (const float*)d_in[17];
  const float* bf1       = (const float*)d_in[18];
  const float* Wout      = (const float*)d_in[19];
  const float* bout      = (const float*)d_in[20];
  float* out = (float*)d_out;

  char* ws = (char*)d_ws;
  size_t off = 0;
  auto alloc = [&](size_t nbytes) {
    char* p = ws + off;
    off += (nbytes + 255) & ~(size_t)255;
    return p;
  };
  float*    x1     = (float*)alloc((size_t)NROWS * DIMM * 4);
  float*    x2     = (float*)alloc((size_t)NROWS * DIMM * 4);
  u16*      xn_hi  = (u16*)alloc((size_t)NROWS * DIMM * 2);
  u16*      xn_lo  = (u16*)alloc((size_t)NROWS * DIMM * 2);
  unsigned* qk_hl  = (unsigned*)alloc((size_t)BHD * TSEQ * DHD * 4);
  unsigned* v_hl   = (unsigned*)alloc((size_t)BHD * TSEQ * DHD * 4);
  u16*      ffh_hi = (u16*)alloc((size_t)NROWS * FFD * 2);   // o4 aliases ffh_hi..ffh_lo (32MB fp32)
  u16*      ffh_lo = (u16*)alloc((size_t)NROWS * FFD * 2);
  float*    o4     = (float*)ffh_hi;
  float*    lg     = (float*)alloc((size_t)BHD * NHASHK * TSEQ * 4);
  float*    sin_t  = (float*)alloc((size_t)TSEQ * 32 * 4);
  float*    cos_t  = (float*)alloc((size_t)TSEQ * 32 * 4);
  float2*   stats  = (float2*)alloc((size_t)NROWS * 8);
  float*    part   = (float*)alloc((size_t)64 * DIMM * 4);
  float*    hm     = (float*)alloc(2 * DIMM * 4);
  float*    r1     = (float*)alloc(2 * 256 * 4);
  int*      bucket = (int*)alloc((size_t)BHD * NHASHK * TSEQ * 4);
  int*      st     = (int*)alloc((size_t)BHD * NHASHK * TSEQ * 4);
  u16*      wt_hi  = (u16*)alloc((size_t)WT_TOT * 2);
  u16*      wt_lo  = (u16*)alloc((size_t)WT_TOT * 2);
  u16*      rott_hi = (u16*)alloc(64 * 64 * 2);
  u16*      rott_lo = (u16*)alloc(64 * 64 * 2);
  u16*      ctx_hi = xn_hi;   // alias: lifetimes disjoint
  u16*      ctx_lo = xn_lo;

  k_embed<<<NROWS, 128, 0, stream>>>(x, token_emb, x1, x2);
  k_sincos<<<(TSEQ * 32) / 256, 256, 0, stream>>>(sin_t, cos_t);

  for (int L = 0; L < 4; ++L) {
    const float* wqk = Wqk + (size_t)L * DIMM * DIMM;
    const float* wv  = Wv  + (size_t)L * DIMM * DIMM;
    const float* wo  = Wo  + (size_t)L * DIMM * DIMM;
    const float* w1  = W1  + (size_t)L * DIMM * FFD;
    const float* w2  = W2  + (size_t)L * FFD * DIMM;
    const float* rot = rotations + (size_t)L * DHD * NHASHK * 16;

    k_prep<<<2820, 256, 0, stream>>>(wqk, wv, wo, w1, w2, rot, wt_hi, wt_lo, rott_hi, rott_lo);
    k_layernorm<<<NROWS, 256, 0, stream>>>(x2, ln1_s + L * DIMM, ln1_b + L * DIMM, xn_hi, xn_lo);
    // fused QK+V GEMM: B = [Wqk^T ; Wv^T] rows 0..1023, contiguous in wt
    k_gemm64<128, 5><<<dim3(32, 16), 256, 0, stream>>>(
        xn_hi, xn_lo, wt_hi + OFF_WQK, wt_lo + OFF_WQK,
        nullptr, nullptr, nullptr, nullptr, qk_hl, v_hl, 512, 1024, sin_t, cos_t);
    k_bucket_gemm<<<BHD * TSEQ / 128, 256, 0, stream>>>(qk_hl, rott_hi, rott_lo, bucket);
    k_sort<<<BHD * NHASHK, 256, 0, stream>>>(bucket, st);
    k_attn<<<BHD * CHUNKS, 256, 0, stream>>>(qk_hl, v_hl, st, o4, lg);
    k_combine<<<(BHD * TSEQ) / 4, 256, 0, stream>>>(o4, lg, ctx_hi, ctx_lo);
    k_gemm64<64, 1><<<dim3(64, 8), 256, 0, stream>>>(
        ctx_hi, ctx_lo, wt_hi + OFF_WO, wt_lo + OFF_WO,
        bo + L * DIMM, x1, nullptr, nullptr, nullptr, nullptr, 512, 512, nullptr, nullptr);
    k_layernorm<<<NROWS, 256, 0, stream>>>(x1, ln2_s + L * DIMM, ln2_b + L * DIMM, xn_hi, xn_lo);
    k_gemm64<128, 4><<<dim3(32, 32), 256, 0, stream>>>(
        xn_hi, xn_lo, wt_hi + OFF_W1, wt_lo + OFF_W1,
        b1 + L * FFD, nullptr, ffh_hi, ffh_lo, nullptr, nullptr, 512, 2048, nullptr, nullptr);
    k_gemm64<64, 1><<<dim3(64, 8), 256, 0, stream>>>(
        ffh_hi, ffh_lo, wt_hi + OFF_W2, wt_lo + OFF_W2,
        b2 + L * DIMM, x2, nullptr, nullptr, nullptr, nullptr, 2048, 512, nullptr, nullptr);
  }

  k_final_stats<<<NROWS, 256, 0, stream>>>(x1, x2, stats);
  k_colmean1<<<64, 256, 0, stream>>>(x1, x2, stats, part);
  k_colmean2<<<4, 256, 0, stream>>>(part, lnf_s, lnf_b, hm);
  k_head1<<<2, 256, 0, stream>>>(hm, Wf1, bf1, r1);
  k_head2<<<2, 256, 0, stream>>>(r1, Wout, bout, out);
}

// Round 5
// 611.499 us; speedup vs baseline: 5.5491x; 1.4727x over previous
//
#include <hip/hip_runtime.h>
#include <math.h>

#define TSEQ   2048
#define DIMM   512
#define NHEAD  8
#define DHD    64
#define BHD    16      // BATCH*HEADS
#define NHASHK 4
#define CHUNKS 128     // NHASHK * (TSEQ/64)
#define FFD    2048
#define NROWS  4096    // BATCH*TSEQ

#define OFF_WQK 0
#define OFF_WV  262144
#define OFF_WO  524288
#define OFF_W1  786432
#define OFF_W2  1835008
#define WT_TOT  2883584

typedef unsigned short u16;
typedef _Float16 f16;
typedef __attribute__((ext_vector_type(8))) _Float16 f16x8;
typedef __attribute__((ext_vector_type(4))) float f32x4;
typedef __attribute__((ext_vector_type(8))) unsigned short ushort8v;
typedef __attribute__((ext_vector_type(4))) unsigned short ushort4v;

__device__ inline u16 h16(float f) {
  union { f16 h; u16 u; } x;
  x.h = (f16)f;
  return x.u;
}
__device__ inline float f16f(u16 u) {
  union { u16 u; f16 h; } x;
  x.u = u;
  return (float)x.h;
}
__device__ inline f16x8 mk8f(unsigned a, unsigned b, unsigned c, unsigned d) {
  union { unsigned u[4]; f16x8 v; } x;
  x.u[0] = a; x.u[1] = b; x.u[2] = c; x.u[3] = d;
  return x.v;
}
__device__ inline float gelu_exact(float v) {
  return 0.5f * v * (1.0f + erff(v * 0.70710678118654752f));
}
// XOR swizzle for 128-byte LDS rows: 16B slot index ^= (row&7) -> 2-way max (free)
__device__ inline int swz128(int row, int colbyte) {
  return row * 128 + (colbyte ^ ((row & 7) << 4));
}

// ---------------- embed ----------------
__global__ __launch_bounds__(128) void k_embed(const int* __restrict__ x, const float* __restrict__ emb,
                                               float* __restrict__ x1, float* __restrict__ x2) {
  int row = blockIdx.x;
  int tok = x[row];
  float4 v = ((const float4*)(emb + (size_t)tok * DIMM))[threadIdx.x];
  ((float4*)(x1 + (size_t)row * DIMM))[threadIdx.x] = v;
  ((float4*)(x2 + (size_t)row * DIMM))[threadIdx.x] = v;
}

// ---------------- sin/cos tables ----------------
__global__ __launch_bounds__(256) void k_sincos(float* __restrict__ sin_t, float* __restrict__ cos_t) {
  int idx = blockIdx.x * 256 + threadIdx.x;   // TSEQ*32
  int t = idx >> 5, i = idx & 31;
  float inv = powf(10000.0f, -(float)(2 * i) / 64.0f);
  float ang = (float)t * inv;
  sin_t[idx] = sinf(ang);
  cos_t[idx] = cosf(ang);
}

// ---------------- layernorm (row = 512) -> fp16 ----------------
__global__ __launch_bounds__(256) void k_layernorm(const float* __restrict__ x, const float* __restrict__ g,
                                                   const float* __restrict__ b, u16* __restrict__ dst) {
  int row = blockIdx.x, tid = threadIdx.x;
  const float* xr = x + (size_t)row * DIMM;
  float v0 = xr[tid], v1 = xr[tid + 256];
  int lane = tid & 63, w = tid >> 6;
  __shared__ float red[8];
  float s = v0 + v1;
#pragma unroll
  for (int o = 32; o; o >>= 1) s += __shfl_xor(s, o);
  if (lane == 0) red[w] = s;
  __syncthreads();
  float mu = (red[0] + red[1] + red[2] + red[3]) * (1.0f / DIMM);
  float d0 = v0 - mu, d1 = v1 - mu;
  float q = d0 * d0 + d1 * d1;
#pragma unroll
  for (int o = 32; o; o >>= 1) q += __shfl_xor(q, o);
  if (lane == 0) red[4 + w] = q;
  __syncthreads();
  float var = (red[4] + red[5] + red[6] + red[7]) * (1.0f / DIMM);
  float rstd = 1.0f / sqrtf(var + 1e-5f);
  size_t base = (size_t)row * DIMM;
  dst[base + tid] = h16(d0 * rstd * g[tid] + b[tid]);
  dst[base + tid + 256] = h16(d1 * rstd * g[tid + 256] + b[tid + 256]);
}

// ---------------- fused per-layer weight prep: transpose + fp16 ----------------
__global__ __launch_bounds__(256) void k_prep(const float* __restrict__ Wqk, const float* __restrict__ Wv,
                                              const float* __restrict__ Wo, const float* __restrict__ W1,
                                              const float* __restrict__ W2, const float* __restrict__ rot,
                                              u16* __restrict__ wt16, u16* __restrict__ rt16) {
  __shared__ float tile[32][33];
  const int idx = blockIdx.x;
  const float* src;
  u16* dh;
  int K, N, k0, n0;
  if (idx < 768) {
    int w = idx >> 8, r = idx & 255;
    K = 512; N = 512; k0 = (r >> 4) << 5; n0 = (r & 15) << 5;
    src = (w == 0) ? Wqk : (w == 1) ? Wv : Wo;
    dh = wt16 + (size_t)w * 262144;
  } else if (idx < 1792) {
    int r = idx - 768;
    K = 512; N = 2048; k0 = (r >> 6) << 5; n0 = (r & 63) << 5;
    src = W1; dh = wt16 + OFF_W1;
  } else if (idx < 2816) {
    int r = idx - 1792;
    K = 2048; N = 512; k0 = (r >> 4) << 5; n0 = (r & 15) << 5;
    src = W2; dh = wt16 + OFF_W2;
  } else {
    int r = idx - 2816;
    K = 64; N = 64; k0 = (r >> 1) << 5; n0 = (r & 1) << 5;
    src = rot; dh = rt16;
  }
  const int t = threadIdx.x;
  const int r = t >> 3, c4 = (t & 7) << 2;
  float4 v = *(const float4*)&src[(size_t)(k0 + r) * N + n0 + c4];
  tile[r][c4] = v.x; tile[r][c4 + 1] = v.y; tile[r][c4 + 2] = v.z; tile[r][c4 + 3] = v.w;
  __syncthreads();
  u16 hs[4];
#pragma unroll
  for (int i = 0; i < 4; ++i) hs[i] = h16(tile[c4 + i][r]);
  size_t o = (size_t)(n0 + r) * K + k0 + c4;
  *(ushort4v*)&dh[o] = (ushort4v){hs[0], hs[1], hs[2], hs[3]};
}

// ---------------- fp16 MFMA GEMM: C = A[M][K] * B^T (Bt[N][K]), BK=64 ----------------
// STORE: 1 = out += val + bias (residual fp32); 4 = gelu(val+bias) -> fp16
//        5 = fused QKV: gn<512 -> rotary -> qk16; gn>=512 -> v16
template <int BM, int STORE>
__global__ __launch_bounds__(256) void k_gemm16(
    const u16* __restrict__ A, const u16* __restrict__ Bt,
    const float* __restrict__ bias, float* __restrict__ out,
    u16* __restrict__ out16, u16* __restrict__ qk16, u16* __restrict__ v16,
    int K, int N,
    const float* __restrict__ sin_t, const float* __restrict__ cos_t) {
  constexpr int MF = BM / 32;    // m-frags per wave
  constexpr int ACH = BM / 32;   // A 16B-chunks per thread per K-step
  __shared__ __align__(16) char AsB[BM * 128];
  __shared__ __align__(16) char BsB[64 * 128];
  const int bm = blockIdx.x * BM, bn = blockIdx.y << 6;
  const int tid = threadIdx.x, lane = tid & 63, wid = tid >> 6;
  const int wm = (wid >> 1) * (BM / 2), wn = (wid & 1) << 5;
  const int l16 = lane & 15, g = lane >> 4;
  f32x4 acc[MF][2];
#pragma unroll
  for (int m = 0; m < MF; ++m) { acc[m][0] = (f32x4){0,0,0,0}; acc[m][1] = (f32x4){0,0,0,0}; }

  const int srow = tid >> 3;            // 0..31
  const int scolb = (tid & 7) << 4;     // 16B chunk col within 128B row
  const u16* ap = A + (size_t)(bm + srow) * K + ((tid & 7) << 3);
  const u16* bp = Bt + (size_t)(bn + srow) * K + ((tid & 7) << 3);

  ushort8v pa[ACH], pb[2];
#pragma unroll
  for (int i = 0; i < ACH; ++i) pa[i] = *(const ushort8v*)(ap + (size_t)(i << 5) * K);
#pragma unroll
  for (int i = 0; i < 2; ++i) pb[i] = *(const ushort8v*)(bp + (size_t)(i << 5) * K);

  for (int k0 = 0;;) {
#pragma unroll
    for (int i = 0; i < ACH; ++i)
      *(ushort8v*)(AsB + swz128(srow + (i << 5), scolb)) = pa[i];
#pragma unroll
    for (int i = 0; i < 2; ++i)
      *(ushort8v*)(BsB + swz128(srow + (i << 5), scolb)) = pb[i];
    __syncthreads();
    const int kn = k0 + 64;
    if (kn < K) {   // prefetch next K-step while computing this one
#pragma unroll
      for (int i = 0; i < ACH; ++i) pa[i] = *(const ushort8v*)(ap + (size_t)(i << 5) * K + kn);
#pragma unroll
      for (int i = 0; i < 2; ++i) pb[i] = *(const ushort8v*)(bp + (size_t)(i << 5) * K + kn);
    }
    f16x8 af[MF][2], bf[2][2];
#pragma unroll
    for (int m = 0; m < MF; ++m)
#pragma unroll
      for (int ks = 0; ks < 2; ++ks)
        af[m][ks] = *(const f16x8*)(AsB + swz128(wm + (m << 4) + l16, ((ks << 2) + g) << 4));
#pragma unroll
    for (int n = 0; n < 2; ++n)
#pragma unroll
      for (int ks = 0; ks < 2; ++ks)
        bf[n][ks] = *(const f16x8*)(BsB + swz128(wn + (n << 4) + l16, ((ks << 2) + g) << 4));
#pragma unroll
    for (int m = 0; m < MF; ++m)
#pragma unroll
      for (int n = 0; n < 2; ++n)
#pragma unroll
        for (int ks = 0; ks < 2; ++ks)
          acc[m][n] = __builtin_amdgcn_mfma_f32_16x16x32_f16(af[m][ks], bf[n][ks], acc[m][n], 0, 0, 0);
    if (kn >= K) break;
    __syncthreads();
    k0 = kn;
  }
  // epilogue (C/D: col = lane&15 -> B rows, row = (lane>>4)*4 + reg -> A rows)
#pragma unroll
  for (int m = 0; m < MF; ++m) {
#pragma unroll
    for (int n = 0; n < 2; ++n) {
      const int gn = bn + wn + (n << 4) + l16;
      float bv = 0.f;
      if (STORE == 1 || STORE == 4) bv = bias[gn];
#pragma unroll
      for (int r = 0; r < 4; ++r) {
        const int gm = bm + wm + (m << 4) + (g << 2) + r;
        float val = acc[m][n][r];
        if (STORE == 1) {
          out[(size_t)gm * N + gn] += val + bv;
        } else if (STORE == 4) {
          out16[(size_t)gm * N + gn] = h16(gelu_exact(val + bv));
        } else {  // STORE == 5
          const float pv = __shfl_xor(val, 1);
          const int bb = gm >> 11, tt = gm & (TSEQ - 1);
          if (gn < 512) {
            const int hh = gn >> 6, dd = gn & 63;
            const int ip = dd >> 1;
            float cz = cos_t[tt * 32 + ip], sz = sin_t[tt * 32 + ip];
            float o = (dd & 1) ? (val * cz + pv * sz) : (val * cz - pv * sz);
            qk16[((size_t)((bb * NHEAD + hh) * TSEQ + tt)) * DHD + dd] = h16(o);
          } else {
            const int gnn = gn - 512;
            const int hh = gnn >> 6, dd = gnn & 63;
            v16[((size_t)((bb * NHEAD + hh) * TSEQ + tt)) * DHD + dd] = h16(val);
          }
        }
      }
    }
  }
}

// ---------------- LSH bucket via MFMA: rv = qk @ rot^T, fused argmax ----------------
__global__ __launch_bounds__(256) void k_bucket_gemm(const u16* __restrict__ qk16,
                                                     const u16* __restrict__ rt16,
                                                     int* __restrict__ bucket) {
  __shared__ __align__(16) u16 Ah[128][72];
  __shared__ __align__(16) u16 Bh[64][72];
  const int bm = blockIdx.x << 7;
  const int tid = threadIdx.x, lane = tid & 63, wid = tid >> 6;
  const int l16 = lane & 15, g = lane >> 4;
  {
    const int r = tid >> 1, hf = tid & 1;
    const u16* src = qk16 + (size_t)(bm + r) * 64 + hf * 32;
#pragma unroll
    for (int i = 0; i < 4; ++i)
      *(ushort8v*)&Ah[r][hf * 32 + i * 8] = *(const ushort8v*)(src + i * 8);
  }
  if (tid < 128) {
    const int r = tid >> 1, hf = tid & 1;
    const u16* src = rt16 + (size_t)r * 64 + hf * 32;
#pragma unroll
    for (int i = 0; i < 4; ++i)
      *(ushort8v*)&Bh[r][hf * 32 + i * 8] = *(const ushort8v*)(src + i * 8);
  }
  __syncthreads();
  const int wm = (wid >> 1) << 6, wn = (wid & 1) << 5;
  f32x4 acc[4][2];
#pragma unroll
  for (int m = 0; m < 4; ++m) { acc[m][0] = (f32x4){0,0,0,0}; acc[m][1] = (f32x4){0,0,0,0}; }
#pragma unroll
  for (int s = 0; s < 2; ++s) {
    f16x8 bfr[2];
#pragma unroll
    for (int n = 0; n < 2; ++n)
      bfr[n] = *(const f16x8*)&Bh[wn + (n << 4) + l16][s * 32 + g * 8];
#pragma unroll
    for (int m = 0; m < 4; ++m) {
      f16x8 afr = *(const f16x8*)&Ah[wm + (m << 4) + l16][s * 32 + g * 8];
#pragma unroll
      for (int n = 0; n < 2; ++n)
        acc[m][n] = __builtin_amdgcn_mfma_f32_16x16x32_f16(afr, bfr[n], acc[m][n], 0, 0, 0);
    }
  }
#pragma unroll
  for (int m = 0; m < 4; ++m)
#pragma unroll
    for (int n = 0; n < 2; ++n) {
      const int hcol = (wn >> 4) + n;
#pragma unroll
      for (int r = 0; r < 4; ++r) {
        float v = acc[m][n][r];
        float best = v; int bi = l16;
        if (-v > best) { best = -v; bi = 16 + l16; }
#pragma unroll
        for (int o = 1; o < 16; o <<= 1) {
          float ob = __shfl_xor(best, o);
          int obi = __shfl_xor(bi, o);
          if (ob > best || (ob == best && obi < bi)) { best = ob; bi = obi; }
        }
        if (l16 == 0) {
          int gm = bm + wm + (m << 4) + (g << 2) + r;
          int bh_ = gm >> 11, t = gm & (TSEQ - 1);
          bucket[((size_t)(bh_ * NHASHK) + hcol) * TSEQ + t] = bi;
        }
      }
    }
}

// ---------------- stable counting sort per (bh,h): 32 buckets, 2048 items ----------------
__global__ __launch_bounds__(256) void k_sort(const int* __restrict__ bucket, int* __restrict__ st) {
  __shared__ int hist[256][33];
  __shared__ int bbase[32];
  const int seg = blockIdx.x;
  const int tid = threadIdx.x;
  const int* bk = bucket + (size_t)seg * TSEQ;
  int4 u0 = *(const int4*)(bk + tid * 8);
  int4 u1 = *(const int4*)(bk + tid * 8 + 4);
  int myb[8] = {u0.x, u0.y, u0.z, u0.w, u1.x, u1.y, u1.z, u1.w};
#pragma unroll
  for (int j = 0; j < 33; ++j) hist[tid][j] = 0;
  __syncthreads();
#pragma unroll
  for (int i = 0; i < 8; ++i) hist[tid][myb[i]]++;
  __syncthreads();
  if (tid < 32) {
    int run = 0;
    for (int gq = 0; gq < 256; ++gq) { int c = hist[gq][tid]; hist[gq][tid] = run; run += c; }
    bbase[tid] = run;
  }
  __syncthreads();
  if (tid == 0) {
    int s = 0;
    for (int j = 0; j < 32; ++j) { int c = bbase[j]; bbase[j] = s; s += c; }
  }
  __syncthreads();
  int* dst = st + (size_t)seg * TSEQ;
#pragma unroll
  for (int i = 0; i < 8; ++i) {
    int b = myb[i];
    int p = bbase[b] + hist[tid][b];
    hist[tid][b]++;
    dst[p] = tid * 8 + i;
  }
}

// ---------------- chunked LSH attention (fp16 MFMA) ----------------
__global__ __launch_bounds__(256) void k_attn(const u16* __restrict__ qk16,
                                              const u16* __restrict__ v16,
                                              const int* __restrict__ st,
                                              float* __restrict__ o4, float* __restrict__ lg) {
  __shared__ __align__(16) char Kb[128 * 128];   // swizzled fp16 K rows
  __shared__ float inv_norm[128];
  __shared__ int tids[128];
  __shared__ float pn[256];
  const int blk = blockIdx.x;
  const int c = blk & (CHUNKS - 1), bh = blk >> 7;
  const int h = c >> 5;
  const int tid = threadIdx.x, lane = tid & 63, wid = tid >> 6;
  const int l16 = lane & 15, g = lane >> 4;

  if (tid < 128) {
    int cc = (tid < 64) ? c : ((c + CHUNKS - 1) & (CHUNKS - 1));
    tids[tid] = st[bh * (NHASHK * TSEQ) + cc * 64 + (tid & 63)];
  }
  __syncthreads();
  {
    const int r = tid >> 1, hf = tid & 1;
    const u16* src = qk16 + ((size_t)bh * TSEQ + tids[r]) * 64 + hf * 32;
    float ss = 0.f;
#pragma unroll
    for (int i = 0; i < 4; ++i) {
      ushort8v u = *(const ushort8v*)(src + i * 8);
      *(ushort8v*)(Kb + swz128(r, hf * 64 + i * 16)) = u;
#pragma unroll
      for (int j = 0; j < 8; ++j) { float f = f16f(u[j]); ss += f * f; }
    }
    pn[tid] = ss;
  }
  __syncthreads();
  if (tid < 128) {
    float s2 = pn[2 * tid] + pn[2 * tid + 1];
    inv_norm[tid] = 1.0f / fmaxf(sqrtf(s2), 1e-12f);
  }
  __syncthreads();

  const int qrow = (wid << 4) + l16;
  const int tq = tids[qrow];
  const size_t obase = (size_t)(bh * NHASHK + h) * TSEQ + tq;

  // S^T = K_raw · Q^T : lane holds S[k][q] for its q-column
  f32x4 accs[8];
#pragma unroll
  for (int i = 0; i < 8; ++i) accs[i] = (f32x4){0, 0, 0, 0};
#pragma unroll
  for (int s = 0; s < 2; ++s) {
    f16x8 qf = *(const f16x8*)(Kb + swz128(qrow, ((s << 2) + g) << 4));
#pragma unroll
    for (int mf = 0; mf < 8; ++mf) {
      f16x8 afr = *(const f16x8*)(Kb + swz128(mf * 16 + l16, ((s << 2) + g) << 4));
      accs[mf] = __builtin_amdgcn_mfma_f32_16x16x32_f16(afr, qf, accs[mf], 0, 0, 0);
    }
  }
  float pv[8][4];
  float mx = -3e38f;
#pragma unroll
  for (int mf = 0; mf < 8; ++mf) {
    float4 invn = *(const float4*)&inv_norm[mf * 16 + g * 4];
    int4 tk = *(const int4*)&tids[mf * 16 + g * 4];
    float inva[4] = {invn.x, invn.y, invn.z, invn.w};
    int tka[4] = {tk.x, tk.y, tk.z, tk.w};
#pragma unroll
    for (int r = 0; r < 4; ++r) {
      float d = accs[mf][r] * inva[r] * 0.125f;
      if (tka[r] == tq) d = -5e4f;
      pv[mf][r] = d;
      mx = fmaxf(mx, d);
    }
  }
  mx = fmaxf(mx, __shfl_xor(mx, 16));
  mx = fmaxf(mx, __shfl_xor(mx, 32));
  float sum = 0.f;
#pragma unroll
  for (int mf = 0; mf < 8; ++mf)
#pragma unroll
    for (int r = 0; r < 4; ++r) {
      float e = __expf(pv[mf][r] - mx);
      pv[mf][r] = e;
      sum += e;
    }
  sum += __shfl_xor(sum, 16);
  sum += __shfl_xor(sum, 32);
  float lse = __logf(sum) + mx;
  float rs = 1.0f / sum;
  if (g == 0) lg[obase] = lse;
  // pack P pairs fp16: P2[mf][m] = (p_{2m}, p_{2m+1}) for k = 16mf + 4g + {2m,2m+1}
  unsigned P2[8][2];
#pragma unroll
  for (int mf = 0; mf < 8; ++mf)
#pragma unroll
    for (int m = 0; m < 2; ++m) {
      float p0 = pv[mf][2 * m] * rs, p1 = pv[mf][2 * m + 1] * rs;
      P2[mf][m] = (unsigned)h16(p0) | ((unsigned)h16(p1) << 16);
    }
  // PV: O^T = V^T · P^T  (A = V^T via global gather, B = P via shfl redistribution)
  f32x4 acco[4];
#pragma unroll
  for (int i = 0; i < 4; ++i) acco[i] = (f32x4){0, 0, 0, 0};
  const u16* vbase = v16 + (size_t)bh * TSEQ * 64;
#pragma unroll
  for (int s = 0; s < 4; ++s) {
    unsigned bw[4];
#pragma unroll
    for (int w = 0; w < 4; ++w) {
      int srl = l16 + (((2 * g + (w >> 1)) & 3) << 4);
      unsigned a0 = __shfl(P2[2 * s][w & 1], srl);
      unsigned a1 = __shfl(P2[2 * s + 1][w & 1], srl);
      bw[w] = (g >> 1) ? a1 : a0;
    }
    f16x8 pb = mk8f(bw[0], bw[1], bw[2], bw[3]);
    int4 t0 = *(const int4*)&tids[s * 32 + g * 8];
    int4 t1 = *(const int4*)&tids[s * 32 + g * 8 + 4];
    int ro[8] = {t0.x, t0.y, t0.z, t0.w, t1.x, t1.y, t1.z, t1.w};
#pragma unroll
    for (int mf = 0; mf < 4; ++mf) {
      const int dcol = mf * 16 + l16;
      u16 vw[8];
#pragma unroll
      for (int j = 0; j < 8; ++j) vw[j] = vbase[(size_t)ro[j] * 64 + dcol];
      f16x8 vf = mk8f((unsigned)vw[0] | ((unsigned)vw[1] << 16),
                      (unsigned)vw[2] | ((unsigned)vw[3] << 16),
                      (unsigned)vw[4] | ((unsigned)vw[5] << 16),
                      (unsigned)vw[6] | ((unsigned)vw[7] << 16));
      acco[mf] = __builtin_amdgcn_mfma_f32_16x16x32_f16(vf, pb, acco[mf], 0, 0, 0);
    }
  }
#pragma unroll
  for (int mf = 0; mf < 4; ++mf)
    *(float4*)&o4[obase * 64 + mf * 16 + g * 4] =
        make_float4(acco[mf][0], acco[mf][1], acco[mf][2], acco[mf][3]);
}

// ---------------- combine hash rounds -> ctx fp16 [B,T,512] ----------------
__global__ __launch_bounds__(256) void k_combine(const float* __restrict__ o4, const float* __restrict__ lg,
                                                 u16* __restrict__ ctx16) {
  int tok = blockIdx.x * 4 + (threadIdx.x >> 6);   // over BHD*TSEQ
  int dd = threadIdx.x & 63;
  int bh = tok >> 11, t = tok & (TSEQ - 1);
  size_t base = (size_t)bh * NHASHK * TSEQ + t;
  float l0 = lg[base], l1 = lg[base + TSEQ], l2 = lg[base + 2 * TSEQ], l3 = lg[base + 3 * TSEQ];
  float m = fmaxf(fmaxf(l0, l1), fmaxf(l2, l3));
  float e0 = expf(l0 - m), e1 = expf(l1 - m), e2 = expf(l2 - m), e3 = expf(l3 - m);
  float inv = 1.0f / (e0 + e1 + e2 + e3);
  float o = (e0 * o4[base * 64 + dd] + e1 * o4[(base + TSEQ) * 64 + dd] +
             e2 * o4[(base + 2 * TSEQ) * 64 + dd] + e3 * o4[(base + 3 * TSEQ) * 64 + dd]) * inv;
  int b = bh >> 3, hh = bh & 7;
  ctx16[((size_t)(b * TSEQ + t)) * DIMM + hh * DHD + dd] = h16(o);
}

// ---------------- final LN stats on (x1+x2)/2 ----------------
__global__ __launch_bounds__(256) void k_final_stats(const float* __restrict__ x1, const float* __restrict__ x2,
                                                     float2* __restrict__ stats) {
  int row = blockIdx.x, tid = threadIdx.x;
  const float* p1 = x1 + (size_t)row * DIMM;
  const float* p2 = x2 + (size_t)row * DIMM;
  float v0 = 0.5f * (p1[tid] + p2[tid]);
  float v1 = 0.5f * (p1[tid + 256] + p2[tid + 256]);
  int lane = tid & 63, w = tid >> 6;
  __shared__ float red[8];
  float s = v0 + v1;
#pragma unroll
  for (int o = 32; o; o >>= 1) s += __shfl_xor(s, o);
  if (lane == 0) red[w] = s;
  __syncthreads();
  float mu = (red[0] + red[1] + red[2] + red[3]) * (1.0f / DIMM);
  float d0 = v0 - mu, d1 = v1 - mu;
  float q = d0 * d0 + d1 * d1;
#pragma unroll
  for (int o = 32; o; o >>= 1) q += __shfl_xor(q, o);
  if (lane == 0) red[4 + w] = q;
  __syncthreads();
  if (tid == 0) {
    float var = (red[4] + red[5] + red[6] + red[7]) * (1.0f / DIMM);
    stats[row] = make_float2(mu, 1.0f / sqrtf(var + 1e-5f));
  }
}

// ---------------- LN + mean over T, stage 1: 64 blocks of 64 rows ----------------
__global__ __launch_bounds__(256) void k_colmean1(const float* __restrict__ x1, const float* __restrict__ x2,
                                                  const float2* __restrict__ stats, float* __restrict__ part) {
  int blk = blockIdx.x;            // [0,64): bb*32 + ch
  int bb = blk >> 5, ch = blk & 31;
  int d = threadIdx.x;
  float a0 = 0.f, a1 = 0.f;
  for (int i = 0; i < 64; ++i) {
    int row = bb * TSEQ + (ch << 6) + i;
    float2 sr = stats[row];
    size_t base = (size_t)row * DIMM;
    a0 += (0.5f * (x1[base + d] + x2[base + d]) - sr.x) * sr.y;
    a1 += (0.5f * (x1[base + d + 256] + x2[base + d + 256]) - sr.x) * sr.y;
  }
  part[(size_t)blk * DIMM + d] = a0;
  part[(size_t)blk * DIMM + d + 256] = a1;
}

__global__ __launch_bounds__(256) void k_colmean2(const float* __restrict__ part,
                                                  const float* __restrict__ g, const float* __restrict__ b,
                                                  float* __restrict__ hm) {
  int idx = blockIdx.x * 256 + threadIdx.x;   // 1024
  int bb = idx >> 9, d = idx & 511;
  float s = 0.f;
  for (int c = 0; c < 32; ++c) s += part[(size_t)(bb * 32 + c) * DIMM + d];
  hm[idx] = s * (1.0f / TSEQ) * g[d] + b[d];
}

// ---------------- head ----------------
__global__ __launch_bounds__(256) void k_head1(const float* __restrict__ hm, const float* __restrict__ Wf1,
                                               const float* __restrict__ bf1, float* __restrict__ r1) {
  int b = blockIdx.x, j = threadIdx.x;   // 2 x 256
  float acc = 0;
  for (int k = 0; k < DIMM; ++k) acc += hm[b * DIMM + k] * Wf1[k * 256 + j];
  r1[b * 256 + j] = fmaxf(acc + bf1[j], 0.0f);
}

__global__ __launch_bounds__(256) void k_head2(const float* __restrict__ r1, const float* __restrict__ Wout,
                                               const float* __restrict__ bout, float* __restrict__ outp) {
  int b = blockIdx.x;
  int tid = threadIdx.x, lane = tid & 63, w = tid >> 6;
  float v = r1[b * 256 + tid] * Wout[tid];
#pragma unroll
  for (int o = 32; o; o >>= 1) v += __shfl_xor(v, o);
  __shared__ float red[4];
  if (lane == 0) red[w] = v;
  __syncthreads();
  if (tid == 0) outp[b] = red[0] + red[1] + red[2] + red[3] + bout[0];
}

extern "C" void kernel_launch(void* const* d_in, const int* in_sizes, int n_in,
                              void* d_out, int out_size, void* d_ws, size_t ws_size,
                              hipStream_t stream) {
  const int*   x         = (const int*)d_in[0];
  const float* token_emb = (const float*)d_in[1];
  const float* ln1_s     = (const float*)d_in[2];
  const float* ln1_b     = (const float*)d_in[3];
  const float* Wqk       = (const float*)d_in[4];
  const float* Wv        = (const float*)d_in[5];
  const float* Wo        = (const float*)d_in[6];
  const float* bo        = (const float*)d_in[7];
  const float* ln2_s     = (const float*)d_in[8];
  const float* ln2_b     = (const float*)d_in[9];
  const float* W1        = (const float*)d_in[10];
  const float* b1        = (const float*)d_in[11];
  const float* W2        = (const float*)d_in[12];
  const float* b2        = (const float*)d_in[13];
  const float* rotations = (const float*)d_in[14];
  const float* lnf_s     = (const float*)d_in[15];
  const float* lnf_b     = (const float*)d_in[16];
  const float* Wf1       = (const float*)d_in[17];
  const float* bf1       = (const float*)d_in[18];
  const float* Wout      = (const float*)d_in[19];
  const float* bout      = (const float*)d_in[20];
  float* out = (float*)d_out;

  char* ws = (char*)d_ws;
  size_t off = 0;
  auto alloc = [&](size_t nbytes) {
    char* p = ws + off;
    off += (nbytes + 255) & ~(size_t)255;
    return p;
  };
  float*  x1     = (float*)alloc((size_t)NROWS * DIMM * 4);
  float*  x2     = (float*)alloc((size_t)NROWS * DIMM * 4);
  u16*    xn16   = (u16*)alloc((size_t)NROWS * DIMM * 2);
  u16*    qk16   = (u16*)alloc((size_t)BHD * TSEQ * DHD * 2);
  u16*    v16    = (u16*)alloc((size_t)BHD * TSEQ * DHD * 2);
  u16*    ffh16  = (u16*)alloc((size_t)NROWS * FFD * 2);
  float*  o4     = (float*)alloc((size_t)BHD * NHASHK * TSEQ * DHD * 4);
  float*  lg     = (float*)alloc((size_t)BHD * NHASHK * TSEQ * 4);
  float*  sin_t  = (float*)alloc((size_t)TSEQ * 32 * 4);
  float*  cos_t  = (float*)alloc((size_t)TSEQ * 32 * 4);
  float2* stats  = (float2*)alloc((size_t)NROWS * 8);
  float*  part   = (float*)alloc((size_t)64 * DIMM * 4);
  float*  hm     = (float*)alloc(2 * DIMM * 4);
  float*  r1     = (float*)alloc(2 * 256 * 4);
  int*    bucket = (int*)alloc((size_t)BHD * NHASHK * TSEQ * 4);
  int*    st     = (int*)alloc((size_t)BHD * NHASHK * TSEQ * 4);
  u16*    wt16   = (u16*)alloc((size_t)WT_TOT * 2);
  u16*    rott16 = (u16*)alloc(64 * 64 * 2);
  u16*    ctx16  = xn16;   // alias: lifetimes disjoint

  k_embed<<<NROWS, 128, 0, stream>>>(x, token_emb, x1, x2);
  k_sincos<<<(TSEQ * 32) / 256, 256, 0, stream>>>(sin_t, cos_t);

  for (int L = 0; L < 4; ++L) {
    const float* wqk = Wqk + (size_t)L * DIMM * DIMM;
    const float* wv  = Wv  + (size_t)L * DIMM * DIMM;
    const float* wo  = Wo  + (size_t)L * DIMM * DIMM;
    const float* w1  = W1  + (size_t)L * DIMM * FFD;
    const float* w2  = W2  + (size_t)L * FFD * DIMM;
    const float* rot = rotations + (size_t)L * DHD * NHASHK * 16;

    k_prep<<<2820, 256, 0, stream>>>(wqk, wv, wo, w1, w2, rot, wt16, rott16);
    k_layernorm<<<NROWS, 256, 0, stream>>>(x2, ln1_s + L * DIMM, ln1_b + L * DIMM, xn16);
    // fused QK+V GEMM: B = [Wqk^T ; Wv^T] rows 0..1023
    k_gemm16<128, 5><<<dim3(32, 16), 256, 0, stream>>>(
        xn16, wt16 + OFF_WQK, nullptr, nullptr, nullptr, qk16, v16, 512, 1024, sin_t, cos_t);
    k_bucket_gemm<<<BHD * TSEQ / 128, 256, 0, stream>>>(qk16, rott16, bucket);
    k_sort<<<BHD * NHASHK, 256, 0, stream>>>(bucket, st);
    k_attn<<<BHD * CHUNKS, 256, 0, stream>>>(qk16, v16, st, o4, lg);
    k_combine<<<(BHD * TSEQ) / 4, 256, 0, stream>>>(o4, lg, ctx16);
    k_gemm16<64, 1><<<dim3(64, 8), 256, 0, stream>>>(
        ctx16, wt16 + OFF_WO, bo + L * DIMM, x1, nullptr, nullptr, nullptr, 512, 512, nullptr, nullptr);
    k_layernorm<<<NROWS, 256, 0, stream>>>(x1, ln2_s + L * DIMM, ln2_b + L * DIMM, xn16);
    k_gemm16<128, 4><<<dim3(32, 32), 256, 0, stream>>>(
        xn16, wt16 + OFF_W1, b1 + L * FFD, nullptr, ffh16, nullptr, nullptr, 512, 2048, nullptr, nullptr);
    k_gemm16<64, 1><<<dim3(64, 8), 256, 0, stream>>>(
        ffh16, wt16 + OFF_W2, b2 + L * DIMM, x2, nullptr, nullptr, nullptr, 2048, 512, nullptr, nullptr);
  }

  k_final_stats<<<NROWS, 256, 0, stream>>>(x1, x2, stats);
  k_colmean1<<<64, 256, 0, stream>>>(x1, x2, stats, part);
  k_colmean2<<<4, 256, 0, stream>>>(part, lnf_s, lnf_b, hm);
  k_head1<<<2, 256, 0, stream>>>(hm, Wf1, bf1, r1);
  k_head2<<<2, 256, 0, stream>>>(r1, Wout, bout, out);
}

// Round 6
// 570.463 us; speedup vs baseline: 5.9482x; 1.0719x over previous
//
#include <hip/hip_runtime.h>
#include <math.h>

#define TSEQ   2048
#define DIMM   512
#define NHEAD  8
#define DHD    64
#define BHD    16      // BATCH*HEADS
#define NHASHK 4
#define CHUNKS 128     // NHASHK * (TSEQ/64)
#define FFD    2048
#define NROWS  4096    // BATCH*TSEQ

#define OFF_WQK 0
#define OFF_WV  262144
#define OFF_WO  524288
#define OFF_W1  786432
#define OFF_W2  1835008
#define WT_TOT  2883584

typedef unsigned short u16;
typedef _Float16 f16;
typedef __attribute__((ext_vector_type(8))) _Float16 f16x8;
typedef __attribute__((ext_vector_type(4))) float f32x4;
typedef __attribute__((ext_vector_type(8))) unsigned short ushort8v;
typedef __attribute__((ext_vector_type(4))) unsigned short ushort4v;

__device__ inline u16 h16(float f) {
  union { f16 h; u16 u; } x;
  x.h = (f16)f;
  return x.u;
}
__device__ inline float f16f(u16 u) {
  union { u16 u; f16 h; } x;
  x.u = u;
  return (float)x.h;
}
__device__ inline f16x8 mk8f(unsigned a, unsigned b, unsigned c, unsigned d) {
  union { unsigned u[4]; f16x8 v; } x;
  x.u[0] = a; x.u[1] = b; x.u[2] = c; x.u[3] = d;
  return x.v;
}
__device__ inline float gelu_exact(float v) {
  return 0.5f * v * (1.0f + erff(v * 0.70710678118654752f));
}
// XOR swizzle for 128-byte LDS rows: 16B slot index ^= (row&7) -> 2-way max (free)
__device__ inline int swz128(int row, int colbyte) {
  return row * 128 + (colbyte ^ ((row & 7) << 4));
}
// transposed V LDS: byte address of Vt[d][k] (u16), stride 264B + half offset
#define VT(d, k) ((d) * 264 + (((d) & 32) ? 8 : 0) + ((k) << 1))

// ---------------- embed ----------------
__global__ __launch_bounds__(128) void k_embed(const int* __restrict__ x, const float* __restrict__ emb,
                                               float* __restrict__ x1, float* __restrict__ x2) {
  int row = blockIdx.x;
  int tok = x[row];
  float4 v = ((const float4*)(emb + (size_t)tok * DIMM))[threadIdx.x];
  ((float4*)(x1 + (size_t)row * DIMM))[threadIdx.x] = v;
  ((float4*)(x2 + (size_t)row * DIMM))[threadIdx.x] = v;
}

// ---------------- sin/cos tables ----------------
__global__ __launch_bounds__(256) void k_sincos(float* __restrict__ sin_t, float* __restrict__ cos_t) {
  int idx = blockIdx.x * 256 + threadIdx.x;   // TSEQ*32
  int t = idx >> 5, i = idx & 31;
  float inv = powf(10000.0f, -(float)(2 * i) / 64.0f);
  float ang = (float)t * inv;
  sin_t[idx] = sinf(ang);
  cos_t[idx] = cosf(ang);
}

// ---------------- layernorm (row = 512) -> fp16 ----------------
__global__ __launch_bounds__(256) void k_layernorm(const float* __restrict__ x, const float* __restrict__ g,
                                                   const float* __restrict__ b, u16* __restrict__ dst) {
  int row = blockIdx.x, tid = threadIdx.x;
  const float* xr = x + (size_t)row * DIMM;
  float v0 = xr[tid], v1 = xr[tid + 256];
  int lane = tid & 63, w = tid >> 6;
  __shared__ float red[8];
  float s = v0 + v1;
#pragma unroll
  for (int o = 32; o; o >>= 1) s += __shfl_xor(s, o);
  if (lane == 0) red[w] = s;
  __syncthreads();
  float mu = (red[0] + red[1] + red[2] + red[3]) * (1.0f / DIMM);
  float d0 = v0 - mu, d1 = v1 - mu;
  float q = d0 * d0 + d1 * d1;
#pragma unroll
  for (int o = 32; o; o >>= 1) q += __shfl_xor(q, o);
  if (lane == 0) red[4 + w] = q;
  __syncthreads();
  float var = (red[4] + red[5] + red[6] + red[7]) * (1.0f / DIMM);
  float rstd = 1.0f / sqrtf(var + 1e-5f);
  size_t base = (size_t)row * DIMM;
  dst[base + tid] = h16(d0 * rstd * g[tid] + b[tid]);
  dst[base + tid + 256] = h16(d1 * rstd * g[tid + 256] + b[tid + 256]);
}

// ---------------- ALL-layer weight prep: transpose + fp16 (4 x 2820 blocks) ----------------
__global__ __launch_bounds__(256) void k_prep(const float* __restrict__ Wqk, const float* __restrict__ Wv,
                                              const float* __restrict__ Wo, const float* __restrict__ W1,
                                              const float* __restrict__ W2, const float* __restrict__ rot,
                                              u16* __restrict__ wt16, u16* __restrict__ rt16) {
  __shared__ float tile[32][33];
  const int L = blockIdx.x / 2820;
  const int idx = blockIdx.x - L * 2820;
  Wqk += (size_t)L * 262144;
  Wv  += (size_t)L * 262144;
  Wo  += (size_t)L * 262144;
  W1  += (size_t)L * 1048576;
  W2  += (size_t)L * 1048576;
  rot += (size_t)L * 4096;
  u16* wt = wt16 + (size_t)L * WT_TOT;
  u16* rt = rt16 + (size_t)L * 4096;
  const float* src;
  u16* dh;
  int K, N, k0, n0;
  if (idx < 768) {
    int w = idx >> 8, r = idx & 255;
    K = 512; N = 512; k0 = (r >> 4) << 5; n0 = (r & 15) << 5;
    src = (w == 0) ? Wqk : (w == 1) ? Wv : Wo;
    dh = wt + (size_t)w * 262144;
  } else if (idx < 1792) {
    int r = idx - 768;
    K = 512; N = 2048; k0 = (r >> 6) << 5; n0 = (r & 63) << 5;
    src = W1; dh = wt + OFF_W1;
  } else if (idx < 2816) {
    int r = idx - 1792;
    K = 2048; N = 512; k0 = (r >> 4) << 5; n0 = (r & 15) << 5;
    src = W2; dh = wt + OFF_W2;
  } else {
    int r = idx - 2816;
    K = 64; N = 64; k0 = (r >> 1) << 5; n0 = (r & 1) << 5;
    src = rot; dh = rt;
  }
  const int t = threadIdx.x;
  const int r = t >> 3, c4 = (t & 7) << 2;
  float4 v = *(const float4*)&src[(size_t)(k0 + r) * N + n0 + c4];
  tile[r][c4] = v.x; tile[r][c4 + 1] = v.y; tile[r][c4 + 2] = v.z; tile[r][c4 + 3] = v.w;
  __syncthreads();
  u16 hs[4];
#pragma unroll
  for (int i = 0; i < 4; ++i) hs[i] = h16(tile[c4 + i][r]);
  size_t o = (size_t)(n0 + r) * K + k0 + c4;
  *(ushort4v*)&dh[o] = (ushort4v){hs[0], hs[1], hs[2], hs[3]};
}

// ---------------- fp16 MFMA GEMM: C = A[M][K] * B^T (Bt[N][K]), BK=64, depth-2 prefetch ----------------
// STORE: 1 = out += val + bias (residual fp32); 4 = gelu(val+bias) -> fp16
//        5 = fused QKV: gn<512 -> rotary -> qk16; gn>=512 -> v16
template <int BM, int STORE>
__global__ __launch_bounds__(256) void k_gemm16(
    const u16* __restrict__ A, const u16* __restrict__ Bt,
    const float* __restrict__ bias, float* __restrict__ out,
    u16* __restrict__ out16, u16* __restrict__ qk16, u16* __restrict__ v16,
    int K, int N,
    const float* __restrict__ sin_t, const float* __restrict__ cos_t) {
  constexpr int MF = BM / 32;    // m-frags per wave
  constexpr int ACH = BM / 32;   // A 16B-chunks per thread per K-step
  __shared__ __align__(16) char AsB[BM * 128];
  __shared__ __align__(16) char BsB[64 * 128];
  const int bm = blockIdx.x * BM, bn = blockIdx.y << 6;
  const int tid = threadIdx.x, lane = tid & 63, wid = tid >> 6;
  const int wm = (wid >> 1) * (BM / 2), wn = (wid & 1) << 5;
  const int l16 = lane & 15, g = lane >> 4;
  f32x4 acc[MF][2];
#pragma unroll
  for (int m = 0; m < MF; ++m) { acc[m][0] = (f32x4){0,0,0,0}; acc[m][1] = (f32x4){0,0,0,0}; }

  const int srow = tid >> 3;            // 0..31
  const int scolb = (tid & 7) << 4;     // 16B chunk col within 128B row
  const u16* ap = A + (size_t)(bm + srow) * K + ((tid & 7) << 3);
  const u16* bp = Bt + (size_t)(bn + srow) * K + ((tid & 7) << 3);

  // two named in-flight register sets (depth-2 pipeline; no runtime indexing)
  ushort8v paA[ACH], pbA[2], paB[ACH], pbB[2];
#pragma unroll
  for (int i = 0; i < ACH; ++i) paA[i] = *(const ushort8v*)(ap + (size_t)(i << 5) * K);
#pragma unroll
  for (int i = 0; i < 2; ++i) pbA[i] = *(const ushort8v*)(bp + (size_t)(i << 5) * K);
#pragma unroll
  for (int i = 0; i < ACH; ++i) paB[i] = *(const ushort8v*)(ap + (size_t)(i << 5) * K + 64);
#pragma unroll
  for (int i = 0; i < 2; ++i) pbB[i] = *(const ushort8v*)(bp + (size_t)(i << 5) * K + 64);

  auto gstep = [&](ushort8v (&PA)[ACH], ushort8v (&PB)[2], int S) {
#pragma unroll
    for (int i = 0; i < ACH; ++i)
      *(ushort8v*)(AsB + swz128(srow + (i << 5), scolb)) = PA[i];
#pragma unroll
    for (int i = 0; i < 2; ++i)
      *(ushort8v*)(BsB + swz128(srow + (i << 5), scolb)) = PB[i];
    __syncthreads();
    const int kf = (S + 2) << 6;
    if (kf < K) {   // issue loads for step S+2 (in flight across ~2 K-steps)
#pragma unroll
      for (int i = 0; i < ACH; ++i) PA[i] = *(const ushort8v*)(ap + (size_t)(i << 5) * K + kf);
#pragma unroll
      for (int i = 0; i < 2; ++i) PB[i] = *(const ushort8v*)(bp + (size_t)(i << 5) * K + kf);
    }
    f16x8 af[MF][2], bfr[2][2];
#pragma unroll
    for (int m = 0; m < MF; ++m)
#pragma unroll
      for (int ks = 0; ks < 2; ++ks)
        af[m][ks] = *(const f16x8*)(AsB + swz128(wm + (m << 4) + l16, ((ks << 2) + g) << 4));
#pragma unroll
    for (int n = 0; n < 2; ++n)
#pragma unroll
      for (int ks = 0; ks < 2; ++ks)
        bfr[n][ks] = *(const f16x8*)(BsB + swz128(wn + (n << 4) + l16, ((ks << 2) + g) << 4));
#pragma unroll
    for (int m = 0; m < MF; ++m)
#pragma unroll
      for (int n = 0; n < 2; ++n)
#pragma unroll
        for (int ks = 0; ks < 2; ++ks)
          acc[m][n] = __builtin_amdgcn_mfma_f32_16x16x32_f16(af[m][ks], bfr[n][ks], acc[m][n], 0, 0, 0);
    __syncthreads();
  };

  const int nsteps = K >> 6;            // always even (K = 512 or 2048)
  for (int s = 0; s < nsteps; s += 2) {
    gstep(paA, pbA, s);
    gstep(paB, pbB, s + 1);
  }

  // epilogue (C/D: col = lane&15 -> B rows, row = (lane>>4)*4 + reg -> A rows)
#pragma unroll
  for (int m = 0; m < MF; ++m) {
#pragma unroll
    for (int n = 0; n < 2; ++n) {
      const int gn = bn + wn + (n << 4) + l16;
      float bv = 0.f;
      if (STORE == 1 || STORE == 4) bv = bias[gn];
#pragma unroll
      for (int r = 0; r < 4; ++r) {
        const int gm = bm + wm + (m << 4) + (g << 2) + r;
        float val = acc[m][n][r];
        if (STORE == 1) {
          out[(size_t)gm * N + gn] += val + bv;
        } else if (STORE == 4) {
          out16[(size_t)gm * N + gn] = h16(gelu_exact(val + bv));
        } else {  // STORE == 5
          const float pv = __shfl_xor(val, 1);
          const int bb = gm >> 11, tt = gm & (TSEQ - 1);
          if (gn < 512) {
            const int hh = gn >> 6, dd = gn & 63;
            const int ip = dd >> 1;
            float cz = cos_t[tt * 32 + ip], sz = sin_t[tt * 32 + ip];
            float o = (dd & 1) ? (val * cz + pv * sz) : (val * cz - pv * sz);
            qk16[((size_t)((bb * NHEAD + hh) * TSEQ + tt)) * DHD + dd] = h16(o);
          } else {
            const int gnn = gn - 512;
            const int hh = gnn >> 6, dd = gnn & 63;
            v16[((size_t)((bb * NHEAD + hh) * TSEQ + tt)) * DHD + dd] = h16(val);
          }
        }
      }
    }
  }
}

// ---------------- LSH bucket via MFMA: rv = qk @ rot^T, fused argmax ----------------
__global__ __launch_bounds__(256) void k_bucket_gemm(const u16* __restrict__ qk16,
                                                     const u16* __restrict__ rt16,
                                                     int* __restrict__ bucket) {
  __shared__ __align__(16) u16 Ah[128][72];
  __shared__ __align__(16) u16 Bh[64][72];
  const int bm = blockIdx.x << 7;
  const int tid = threadIdx.x, lane = tid & 63, wid = tid >> 6;
  const int l16 = lane & 15, g = lane >> 4;
  {
    const int r = tid >> 1, hf = tid & 1;
    const u16* src = qk16 + (size_t)(bm + r) * 64 + hf * 32;
#pragma unroll
    for (int i = 0; i < 4; ++i)
      *(ushort8v*)&Ah[r][hf * 32 + i * 8] = *(const ushort8v*)(src + i * 8);
  }
  if (tid < 128) {
    const int r = tid >> 1, hf = tid & 1;
    const u16* src = rt16 + (size_t)r * 64 + hf * 32;
#pragma unroll
    for (int i = 0; i < 4; ++i)
      *(ushort8v*)&Bh[r][hf * 32 + i * 8] = *(const ushort8v*)(src + i * 8);
  }
  __syncthreads();
  const int wm = (wid >> 1) << 6, wn = (wid & 1) << 5;
  f32x4 acc[4][2];
#pragma unroll
  for (int m = 0; m < 4; ++m) { acc[m][0] = (f32x4){0,0,0,0}; acc[m][1] = (f32x4){0,0,0,0}; }
#pragma unroll
  for (int s = 0; s < 2; ++s) {
    f16x8 bfr[2];
#pragma unroll
    for (int n = 0; n < 2; ++n)
      bfr[n] = *(const f16x8*)&Bh[wn + (n << 4) + l16][s * 32 + g * 8];
#pragma unroll
    for (int m = 0; m < 4; ++m) {
      f16x8 afr = *(const f16x8*)&Ah[wm + (m << 4) + l16][s * 32 + g * 8];
#pragma unroll
      for (int n = 0; n < 2; ++n)
        acc[m][n] = __builtin_amdgcn_mfma_f32_16x16x32_f16(afr, bfr[n], acc[m][n], 0, 0, 0);
    }
  }
#pragma unroll
  for (int m = 0; m < 4; ++m)
#pragma unroll
    for (int n = 0; n < 2; ++n) {
      const int hcol = (wn >> 4) + n;
#pragma unroll
      for (int r = 0; r < 4; ++r) {
        float v = acc[m][n][r];
        float best = v; int bi = l16;
        if (-v > best) { best = -v; bi = 16 + l16; }
#pragma unroll
        for (int o = 1; o < 16; o <<= 1) {
          float ob = __shfl_xor(best, o);
          int obi = __shfl_xor(bi, o);
          if (ob > best || (ob == best && obi < bi)) { best = ob; bi = obi; }
        }
        if (l16 == 0) {
          int gm = bm + wm + (m << 4) + (g << 2) + r;
          int bh_ = gm >> 11, t = gm & (TSEQ - 1);
          bucket[((size_t)(bh_ * NHASHK) + hcol) * TSEQ + t] = bi;
        }
      }
    }
}

// ---------------- stable counting sort per (bh,h): 32 buckets, 2048 items ----------------
__global__ __launch_bounds__(256) void k_sort(const int* __restrict__ bucket, int* __restrict__ st) {
  __shared__ int hist[256][33];
  __shared__ int bbase[32];
  const int seg = blockIdx.x;
  const int tid = threadIdx.x;
  const int* bk = bucket + (size_t)seg * TSEQ;
  int4 u0 = *(const int4*)(bk + tid * 8);
  int4 u1 = *(const int4*)(bk + tid * 8 + 4);
  int myb[8] = {u0.x, u0.y, u0.z, u0.w, u1.x, u1.y, u1.z, u1.w};
#pragma unroll
  for (int j = 0; j < 33; ++j) hist[tid][j] = 0;
  __syncthreads();
#pragma unroll
  for (int i = 0; i < 8; ++i) hist[tid][myb[i]]++;
  __syncthreads();
  if (tid < 32) {
    int run = 0;
    for (int gq = 0; gq < 256; ++gq) { int c = hist[gq][tid]; hist[gq][tid] = run; run += c; }
    bbase[tid] = run;
  }
  __syncthreads();
  if (tid == 0) {
    int s = 0;
    for (int j = 0; j < 32; ++j) { int c = bbase[j]; bbase[j] = s; s += c; }
  }
  __syncthreads();
  int* dst = st + (size_t)seg * TSEQ;
#pragma unroll
  for (int i = 0; i < 8; ++i) {
    int b = myb[i];
    int p = bbase[b] + hist[tid][b];
    hist[tid][b]++;
    dst[p] = tid * 8 + i;
  }
}

// ---------------- chunked LSH attention (fp16 MFMA, K + transposed-V in LDS) ----------------
__global__ __launch_bounds__(256) void k_attn(const u16* __restrict__ qk16,
                                              const u16* __restrict__ v16,
                                              const int* __restrict__ st,
                                              float* __restrict__ o4, float* __restrict__ lg) {
  __shared__ __align__(16) char Kb[128 * 128];        // swizzled fp16 K rows
  __shared__ __align__(16) char Vb[64 * 264 + 16];    // transposed V: Vt[d][k]
  __shared__ float inv_norm[128];
  __shared__ int tids[128];
  __shared__ float pn[256];
  const int blk = blockIdx.x;
  const int c = blk & (CHUNKS - 1), bh = blk >> 7;
  const int h = c >> 5;
  const int tid = threadIdx.x, lane = tid & 63, wid = tid >> 6;
  const int l16 = lane & 15, g = lane >> 4;

  if (tid < 128) {
    int cc = (tid < 64) ? c : ((c + CHUNKS - 1) & (CHUNKS - 1));
    tids[tid] = st[bh * (NHASHK * TSEQ) + cc * 64 + (tid & 63)];
  }
  __syncthreads();
  {
    const int r = tid >> 1, hf = tid & 1;
    const u16* qsrc = qk16 + ((size_t)bh * TSEQ + tids[r]) * 64 + hf * 32;
    const u16* vsrc = v16 + ((size_t)bh * TSEQ + tids[r]) * 64 + hf * 32;
    float ss = 0.f;
#pragma unroll
    for (int i = 0; i < 4; ++i) {
      ushort8v u = *(const ushort8v*)(qsrc + i * 8);
      *(ushort8v*)(Kb + swz128(r, hf * 64 + i * 16)) = u;
#pragma unroll
      for (int j = 0; j < 8; ++j) { float f = f16f(u[j]); ss += f * f; }
      ushort8v vv8 = *(const ushort8v*)(vsrc + i * 8);
#pragma unroll
      for (int j = 0; j < 8; ++j)
        *(u16*)(Vb + VT(hf * 32 + i * 8 + j, r)) = vv8[j];
    }
    pn[tid] = ss;
  }
  __syncthreads();
  if (tid < 128) {
    float s2 = pn[2 * tid] + pn[2 * tid + 1];
    inv_norm[tid] = 1.0f / fmaxf(sqrtf(s2), 1e-12f);
  }
  __syncthreads();

  const int qrow = (wid << 4) + l16;
  const int tq = tids[qrow];
  const size_t obase = (size_t)(bh * NHASHK + h) * TSEQ + tq;

  // S^T = K_raw · Q^T : lane holds S[k][q] for its q-column
  f32x4 accs[8];
#pragma unroll
  for (int i = 0; i < 8; ++i) accs[i] = (f32x4){0, 0, 0, 0};
#pragma unroll
  for (int s = 0; s < 2; ++s) {
    f16x8 qf = *(const f16x8*)(Kb + swz128(qrow, ((s << 2) + g) << 4));
#pragma unroll
    for (int mf = 0; mf < 8; ++mf) {
      f16x8 afr = *(const f16x8*)(Kb + swz128(mf * 16 + l16, ((s << 2) + g) << 4));
      accs[mf] = __builtin_amdgcn_mfma_f32_16x16x32_f16(afr, qf, accs[mf], 0, 0, 0);
    }
  }
  float pv[8][4];
  float mx = -3e38f;
#pragma unroll
  for (int mf = 0; mf < 8; ++mf) {
    float4 invn = *(const float4*)&inv_norm[mf * 16 + g * 4];
    int4 tk = *(const int4*)&tids[mf * 16 + g * 4];
    float inva[4] = {invn.x, invn.y, invn.z, invn.w};
    int tka[4] = {tk.x, tk.y, tk.z, tk.w};
#pragma unroll
    for (int r = 0; r < 4; ++r) {
      float d = accs[mf][r] * inva[r] * 0.125f;
      if (tka[r] == tq) d = -5e4f;
      pv[mf][r] = d;
      mx = fmaxf(mx, d);
    }
  }
  mx = fmaxf(mx, __shfl_xor(mx, 16));
  mx = fmaxf(mx, __shfl_xor(mx, 32));
  float sum = 0.f;
#pragma unroll
  for (int mf = 0; mf < 8; ++mf)
#pragma unroll
    for (int r = 0; r < 4; ++r) {
      float e = __expf(pv[mf][r] - mx);
      pv[mf][r] = e;
      sum += e;
    }
  sum += __shfl_xor(sum, 16);
  sum += __shfl_xor(sum, 32);
  float lse = __logf(sum) + mx;
  float rs = 1.0f / sum;
  if (g == 0) lg[obase] = lse;
  // pack P pairs fp16: P2[mf][m] = (p_{2m}, p_{2m+1}) for k = 16mf + 4g + {2m,2m+1}
  unsigned P2[8][2];
#pragma unroll
  for (int mf = 0; mf < 8; ++mf)
#pragma unroll
    for (int m = 0; m < 2; ++m) {
      float p0 = pv[mf][2 * m] * rs, p1 = pv[mf][2 * m + 1] * rs;
      P2[mf][m] = (unsigned)h16(p0) | ((unsigned)h16(p1) << 16);
    }
  // PV: O^T = V^T · P^T  (A = V^T from transposed LDS, B = P via shfl redistribution)
  f32x4 acco[4];
#pragma unroll
  for (int i = 0; i < 4; ++i) acco[i] = (f32x4){0, 0, 0, 0};
#pragma unroll
  for (int s = 0; s < 4; ++s) {
    unsigned bw[4];
#pragma unroll
    for (int w = 0; w < 4; ++w) {
      int srl = l16 + (((2 * g + (w >> 1)) & 3) << 4);
      unsigned a0 = __shfl(P2[2 * s][w & 1], srl);
      unsigned a1 = __shfl(P2[2 * s + 1][w & 1], srl);
      bw[w] = (g >> 1) ? a1 : a0;
    }
    f16x8 pb = mk8f(bw[0], bw[1], bw[2], bw[3]);
    const int k0 = s * 32 + g * 8;
#pragma unroll
    for (int mf = 0; mf < 4; ++mf) {
      const int dcol = mf * 16 + l16;
      uint2 v0 = *(const uint2*)(Vb + VT(dcol, k0));
      uint2 v1 = *(const uint2*)(Vb + VT(dcol, k0 + 4));
      f16x8 vf = mk8f(v0.x, v0.y, v1.x, v1.y);
      acco[mf] = __builtin_amdgcn_mfma_f32_16x16x32_f16(vf, pb, acco[mf], 0, 0, 0);
    }
  }
#pragma unroll
  for (int mf = 0; mf < 4; ++mf)
    *(float4*)&o4[obase * 64 + mf * 16 + g * 4] =
        make_float4(acco[mf][0], acco[mf][1], acco[mf][2], acco[mf][3]);
}

// ---------------- combine hash rounds -> ctx fp16 [B,T,512] ----------------
__global__ __launch_bounds__(256) void k_combine(const float* __restrict__ o4, const float* __restrict__ lg,
                                                 u16* __restrict__ ctx16) {
  int tok = blockIdx.x * 4 + (threadIdx.x >> 6);   // over BHD*TSEQ
  int dd = threadIdx.x & 63;
  int bh = tok >> 11, t = tok & (TSEQ - 1);
  size_t base = (size_t)bh * NHASHK * TSEQ + t;
  float l0 = lg[base], l1 = lg[base + TSEQ], l2 = lg[base + 2 * TSEQ], l3 = lg[base + 3 * TSEQ];
  float m = fmaxf(fmaxf(l0, l1), fmaxf(l2, l3));
  float e0 = expf(l0 - m), e1 = expf(l1 - m), e2 = expf(l2 - m), e3 = expf(l3 - m);
  float inv = 1.0f / (e0 + e1 + e2 + e3);
  float o = (e0 * o4[base * 64 + dd] + e1 * o4[(base + TSEQ) * 64 + dd] +
             e2 * o4[(base + 2 * TSEQ) * 64 + dd] + e3 * o4[(base + 3 * TSEQ) * 64 + dd]) * inv;
  int b = bh >> 3, hh = bh & 7;
  ctx16[((size_t)(b * TSEQ + t)) * DIMM + hh * DHD + dd] = h16(o);
}

// ---------------- fused final-LN + column-mean stage 1: 512 blocks x 8 rows ----------------
__global__ __launch_bounds__(256) void k_colmean1(const float* __restrict__ x1, const float* __restrict__ x2,
                                                  float* __restrict__ part) {
  const int blk = blockIdx.x;            // bb*256 + ch
  const int bb = blk >> 8, ch = blk & 255;
  const int tid = threadIdx.x, lane = tid & 63, w = tid >> 6;
  __shared__ float red[8];
  float a0 = 0.f, a1 = 0.f;
  for (int i = 0; i < 8; ++i) {
    int row = bb * TSEQ + ch * 8 + i;
    size_t base = (size_t)row * DIMM;
    float v0 = 0.5f * (x1[base + tid] + x2[base + tid]);
    float v1 = 0.5f * (x1[base + tid + 256] + x2[base + tid + 256]);
    float s = v0 + v1;
#pragma unroll
    for (int o = 32; o; o >>= 1) s += __shfl_xor(s, o);
    if (lane == 0) red[w] = s;
    __syncthreads();
    float mu = (red[0] + red[1] + red[2] + red[3]) * (1.0f / DIMM);
    float d0 = v0 - mu, d1 = v1 - mu;
    float q = d0 * d0 + d1 * d1;
#pragma unroll
    for (int o = 32; o; o >>= 1) q += __shfl_xor(q, o);
    if (lane == 0) red[4 + w] = q;
    __syncthreads();
    float var = (red[4] + red[5] + red[6] + red[7]) * (1.0f / DIMM);
    float rstd = 1.0f / sqrtf(var + 1e-5f);
    a0 += d0 * rstd;
    a1 += d1 * rstd;
    __syncthreads();
  }
  part[(size_t)blk * DIMM + tid] = a0;
  part[(size_t)blk * DIMM + tid + 256] = a1;
}

__global__ __launch_bounds__(256) void k_colmean2(const float* __restrict__ part,
                                                  const float* __restrict__ g, const float* __restrict__ b,
                                                  float* __restrict__ hm) {
  int gidx = blockIdx.x * 256 + threadIdx.x;   // 8192 = 1024 outputs x 8
  int oid = gidx >> 3, sub = gidx & 7;
  int bb = oid >> 9, d = oid & 511;
  float s = 0.f;
  for (int c = sub; c < 256; c += 8) s += part[((size_t)(bb * 256 + c)) * DIMM + d];
  s += __shfl_xor(s, 1);
  s += __shfl_xor(s, 2);
  s += __shfl_xor(s, 4);
  if (sub == 0) hm[oid] = s * (1.0f / TSEQ) * g[d] + b[d];
}

// ---------------- head (split-K head1 + reducing head2) ----------------
__global__ __launch_bounds__(256) void k_head1(const float* __restrict__ hm, const float* __restrict__ Wf1,
                                               float* __restrict__ r1p) {
  int b = blockIdx.x & 1, kc = blockIdx.x >> 1;   // 16 blocks: 2 batch x 8 k-chunks
  int j = threadIdx.x;
  float acc = 0;
  for (int k = kc * 64; k < kc * 64 + 64; ++k) acc += hm[b * DIMM + k] * Wf1[k * 256 + j];
  r1p[(size_t)(kc * 2 + b) * 256 + j] = acc;
}

__global__ __launch_bounds__(256) void k_head2(const float* __restrict__ r1p, const float* __restrict__ bf1,
                                               const float* __restrict__ Wout, const float* __restrict__ bout,
                                               float* __restrict__ outp) {
  int b = blockIdx.x;
  int tid = threadIdx.x, lane = tid & 63, w = tid >> 6;
  float s = 0.f;
#pragma unroll
  for (int kc = 0; kc < 8; ++kc) s += r1p[(size_t)(kc * 2 + b) * 256 + tid];
  float v = fmaxf(s + bf1[tid], 0.0f) * Wout[tid];
#pragma unroll
  for (int o = 32; o; o >>= 1) v += __shfl_xor(v, o);
  __shared__ float red[4];
  if (lane == 0) red[w] = v;
  __syncthreads();
  if (tid == 0) outp[b] = red[0] + red[1] + red[2] + red[3] + bout[0];
}

extern "C" void kernel_launch(void* const* d_in, const int* in_sizes, int n_in,
                              void* d_out, int out_size, void* d_ws, size_t ws_size,
                              hipStream_t stream) {
  const int*   x         = (const int*)d_in[0];
  const float* token_emb = (const float*)d_in[1];
  const float* ln1_s     = (const float*)d_in[2];
  const float* ln1_b     = (const float*)d_in[3];
  const float* Wqk       = (const float*)d_in[4];
  const float* Wv        = (const float*)d_in[5];
  const float* Wo        = (const float*)d_in[6];
  const float* bo        = (const float*)d_in[7];
  const float* ln2_s     = (const float*)d_in[8];
  const float* ln2_b     = (const float*)d_in[9];
  const float* W1        = (const float*)d_in[10];
  const float* b1        = (const float*)d_in[11];
  const float* W2        = (const float*)d_in[12];
  const float* b2        = (const float*)d_in[13];
  const float* rotations = (const float*)d_in[14];
  const float* lnf_s     = (const float*)d_in[15];
  const float* lnf_b     = (const float*)d_in[16];
  const float* Wf1       = (const float*)d_in[17];
  const float* bf1       = (const float*)d_in[18];
  const float* Wout      = (const float*)d_in[19];
  const float* bout      = (const float*)d_in[20];
  float* out = (float*)d_out;

  char* ws = (char*)d_ws;
  size_t off = 0;
  auto alloc = [&](size_t nbytes) {
    char* p = ws + off;
    off += (nbytes + 255) & ~(size_t)255;
    return p;
  };
  float*  x1     = (float*)alloc((size_t)NROWS * DIMM * 4);
  float*  x2     = (float*)alloc((size_t)NROWS * DIMM * 4);
  u16*    xn16   = (u16*)alloc((size_t)NROWS * DIMM * 2);
  u16*    qk16   = (u16*)alloc((size_t)BHD * TSEQ * DHD * 2);
  u16*    v16    = (u16*)alloc((size_t)BHD * TSEQ * DHD * 2);
  u16*    ffh16  = (u16*)alloc((size_t)NROWS * FFD * 2);
  float*  o4     = (float*)alloc((size_t)BHD * NHASHK * TSEQ * DHD * 4);
  float*  lg     = (float*)alloc((size_t)BHD * NHASHK * TSEQ * 4);
  float*  sin_t  = (float*)alloc((size_t)TSEQ * 32 * 4);
  float*  cos_t  = (float*)alloc((size_t)TSEQ * 32 * 4);
  float*  part   = (float*)alloc((size_t)512 * DIMM * 4);
  float*  hm     = (float*)alloc(2 * DIMM * 4);
  float*  r1p    = (float*)alloc(16 * 256 * 4);
  int*    bucket = (int*)alloc((size_t)BHD * NHASHK * TSEQ * 4);
  int*    st     = (int*)alloc((size_t)BHD * NHASHK * TSEQ * 4);
  u16*    wt16   = (u16*)alloc((size_t)4 * WT_TOT * 2);
  u16*    rott16 = (u16*)alloc((size_t)4 * 64 * 64 * 2);
  u16*    ctx16  = xn16;   // alias: lifetimes disjoint

  k_embed<<<NROWS, 128, 0, stream>>>(x, token_emb, x1, x2);
  k_sincos<<<(TSEQ * 32) / 256, 256, 0, stream>>>(sin_t, cos_t);
  k_prep<<<4 * 2820, 256, 0, stream>>>(Wqk, Wv, Wo, W1, W2, rotations, wt16, rott16);

  for (int L = 0; L < 4; ++L) {
    u16* wt = wt16 + (size_t)L * WT_TOT;
    u16* rt = rott16 + (size_t)L * 4096;

    k_layernorm<<<NROWS, 256, 0, stream>>>(x2, ln1_s + L * DIMM, ln1_b + L * DIMM, xn16);
    // fused QK+V GEMM: B = [Wqk^T ; Wv^T] rows 0..1023
    k_gemm16<128, 5><<<dim3(32, 16), 256, 0, stream>>>(
        xn16, wt + OFF_WQK, nullptr, nullptr, nullptr, qk16, v16, 512, 1024, sin_t, cos_t);
    k_bucket_gemm<<<BHD * TSEQ / 128, 256, 0, stream>>>(qk16, rt, bucket);
    k_sort<<<BHD * NHASHK, 256, 0, stream>>>(bucket, st);
    k_attn<<<BHD * CHUNKS, 256, 0, stream>>>(qk16, v16, st, o4, lg);
    k_combine<<<(BHD * TSEQ) / 4, 256, 0, stream>>>(o4, lg, ctx16);
    k_gemm16<64, 1><<<dim3(64, 8), 256, 0, stream>>>(
        ctx16, wt + OFF_WO, bo + L * DIMM, x1, nullptr, nullptr, nullptr, 512, 512, nullptr, nullptr);
    k_layernorm<<<NROWS, 256, 0, stream>>>(x1, ln2_s + L * DIMM, ln2_b + L * DIMM, xn16);
    k_gemm16<128, 4><<<dim3(32, 32), 256, 0, stream>>>(
        xn16, wt + OFF_W1, b1 + L * FFD, nullptr, ffh16, nullptr, nullptr, 512, 2048, nullptr, nullptr);
    k_gemm16<64, 1><<<dim3(64, 8), 256, 0, stream>>>(
        ffh16, wt + OFF_W2, b2 + L * DIMM, x2, nullptr, nullptr, nullptr, 2048, 512, nullptr, nullptr);
  }

  k_colmean1<<<512, 256, 0, stream>>>(x1, x2, part);
  k_colmean2<<<32, 256, 0, stream>>>(part, lnf_s, lnf_b, hm);
  k_head1<<<16, 256, 0, stream>>>(hm, Wf1, r1p);
  k_head2<<<2, 256, 0, stream>>>(r1p, bf1, Wout, bout, out);
}

// Round 7
// 502.423 us; speedup vs baseline: 6.7538x; 1.1354x over previous
//
#include <hip/hip_runtime.h>
#include <math.h>

#define TSEQ   2048
#define DIMM   512
#define NHEAD  8
#define DHD    64
#define BHD    16      // BATCH*HEADS
#define NHASHK 4
#define CHUNKS 128     // NHASHK * (TSEQ/64)
#define FFD    2048
#define NROWS  4096    // BATCH*TSEQ

#define OFF_WQK 0
#define OFF_WV  262144
#define OFF_WO  524288
#define OFF_W1  786432
#define OFF_W2  1835008
#define WT_TOT  2883584

typedef unsigned short u16;
typedef _Float16 f16;
typedef __attribute__((ext_vector_type(8))) _Float16 f16x8;
typedef __attribute__((ext_vector_type(4))) float f32x4;
typedef __attribute__((ext_vector_type(8))) unsigned short ushort8v;
typedef __attribute__((ext_vector_type(4))) unsigned short ushort4v;

__device__ inline u16 h16(float f) {
  union { f16 h; u16 u; } x;
  x.h = (f16)f;
  return x.u;
}
__device__ inline float f16f(u16 u) {
  union { u16 u; f16 h; } x;
  x.u = u;
  return (float)x.h;
}
__device__ inline f16x8 mk8f(unsigned a, unsigned b, unsigned c, unsigned d) {
  union { unsigned u[4]; f16x8 v; } x;
  x.u[0] = a; x.u[1] = b; x.u[2] = c; x.u[3] = d;
  return x.v;
}
__device__ inline float gelu_exact(float v) {
  return 0.5f * v * (1.0f + erff(v * 0.70710678118654752f));
}
// XOR swizzle for 128-byte LDS rows: 16B slot index ^= (row&7) -> 2-way max (free)
__device__ inline int swz128(int row, int colbyte) {
  return row * 128 + (colbyte ^ ((row & 7) << 4));
}
// transposed V LDS: byte address of Vt[d][k] (u16), stride 264B + half offset
#define VT(d, k) ((d) * 264 + (((d) & 32) ? 8 : 0) + ((k) << 1))

// ---------------- embed ----------------
__global__ __launch_bounds__(128) void k_embed(const int* __restrict__ x, const float* __restrict__ emb,
                                               float* __restrict__ x1, float* __restrict__ x2) {
  int row = blockIdx.x;
  int tok = x[row];
  float4 v = ((const float4*)(emb + (size_t)tok * DIMM))[threadIdx.x];
  ((float4*)(x1 + (size_t)row * DIMM))[threadIdx.x] = v;
  ((float4*)(x2 + (size_t)row * DIMM))[threadIdx.x] = v;
}

// ---------------- sin/cos tables ----------------
__global__ __launch_bounds__(256) void k_sincos(float* __restrict__ sin_t, float* __restrict__ cos_t) {
  int idx = blockIdx.x * 256 + threadIdx.x;   // TSEQ*32
  int t = idx >> 5, i = idx & 31;
  float inv = powf(10000.0f, -(float)(2 * i) / 64.0f);
  float ang = (float)t * inv;
  sin_t[idx] = sinf(ang);
  cos_t[idx] = cosf(ang);
}

// ---------------- layernorm (row = 512) -> fp16 ----------------
__global__ __launch_bounds__(256) void k_layernorm(const float* __restrict__ x, const float* __restrict__ g,
                                                   const float* __restrict__ b, u16* __restrict__ dst) {
  int row = blockIdx.x, tid = threadIdx.x;
  const float* xr = x + (size_t)row * DIMM;
  float v0 = xr[tid], v1 = xr[tid + 256];
  int lane = tid & 63, w = tid >> 6;
  __shared__ float red[8];
  float s = v0 + v1;
#pragma unroll
  for (int o = 32; o; o >>= 1) s += __shfl_xor(s, o);
  if (lane == 0) red[w] = s;
  __syncthreads();
  float mu = (red[0] + red[1] + red[2] + red[3]) * (1.0f / DIMM);
  float d0 = v0 - mu, d1 = v1 - mu;
  float q = d0 * d0 + d1 * d1;
#pragma unroll
  for (int o = 32; o; o >>= 1) q += __shfl_xor(q, o);
  if (lane == 0) red[4 + w] = q;
  __syncthreads();
  float var = (red[4] + red[5] + red[6] + red[7]) * (1.0f / DIMM);
  float rstd = 1.0f / sqrtf(var + 1e-5f);
  size_t base = (size_t)row * DIMM;
  dst[base + tid] = h16(d0 * rstd * g[tid] + b[tid]);
  dst[base + tid + 256] = h16(d1 * rstd * g[tid + 256] + b[tid + 256]);
}

// ---------------- ALL-layer weight prep: transpose + fp16 (4 x 2820 blocks) ----------------
__global__ __launch_bounds__(256) void k_prep(const float* __restrict__ Wqk, const float* __restrict__ Wv,
                                              const float* __restrict__ Wo, const float* __restrict__ W1,
                                              const float* __restrict__ W2, const float* __restrict__ rot,
                                              u16* __restrict__ wt16, u16* __restrict__ rt16) {
  __shared__ float tile[32][33];
  const int L = blockIdx.x / 2820;
  const int idx = blockIdx.x - L * 2820;
  Wqk += (size_t)L * 262144;
  Wv  += (size_t)L * 262144;
  Wo  += (size_t)L * 262144;
  W1  += (size_t)L * 1048576;
  W2  += (size_t)L * 1048576;
  rot += (size_t)L * 4096;
  u16* wt = wt16 + (size_t)L * WT_TOT;
  u16* rt = rt16 + (size_t)L * 4096;
  const float* src;
  u16* dh;
  int K, N, k0, n0;
  if (idx < 768) {
    int w = idx >> 8, r = idx & 255;
    K = 512; N = 512; k0 = (r >> 4) << 5; n0 = (r & 15) << 5;
    src = (w == 0) ? Wqk : (w == 1) ? Wv : Wo;
    dh = wt + (size_t)w * 262144;
  } else if (idx < 1792) {
    int r = idx - 768;
    K = 512; N = 2048; k0 = (r >> 6) << 5; n0 = (r & 63) << 5;
    src = W1; dh = wt + OFF_W1;
  } else if (idx < 2816) {
    int r = idx - 1792;
    K = 2048; N = 512; k0 = (r >> 4) << 5; n0 = (r & 15) << 5;
    src = W2; dh = wt + OFF_W2;
  } else {
    int r = idx - 2816;
    K = 64; N = 64; k0 = (r >> 1) << 5; n0 = (r & 1) << 5;
    src = rot; dh = rt;
  }
  const int t = threadIdx.x;
  const int r = t >> 3, c4 = (t & 7) << 2;
  float4 v = *(const float4*)&src[(size_t)(k0 + r) * N + n0 + c4];
  tile[r][c4] = v.x; tile[r][c4 + 1] = v.y; tile[r][c4 + 2] = v.z; tile[r][c4 + 3] = v.w;
  __syncthreads();
  u16 hs[4];
#pragma unroll
  for (int i = 0; i < 4; ++i) hs[i] = h16(tile[c4 + i][r]);
  size_t o = (size_t)(n0 + r) * K + k0 + c4;
  *(ushort4v*)&dh[o] = (ushort4v){hs[0], hs[1], hs[2], hs[3]};
}

// ---------------- fp16 MFMA GEMM: C = A[M][K] * B^T (Bt[N][K]), BK=64, depth-2 prefetch ----------------
// STORE: 1 = out += val + bias (residual fp32); 4 = gelu(val+bias) -> fp16
//        5 = fused QKV: gn<512 -> rotary -> qk16 + fused LSH bucket; gn>=512 -> v16
template <int BM, int STORE>
__global__ __launch_bounds__(256) void k_gemm16(
    const u16* __restrict__ A, const u16* __restrict__ Bt,
    const float* __restrict__ bias, float* __restrict__ out,
    u16* __restrict__ out16, u16* __restrict__ qk16, u16* __restrict__ v16,
    int K, int N,
    const float* __restrict__ sin_t, const float* __restrict__ cos_t,
    const u16* __restrict__ rt16, int* __restrict__ bucket) {
  constexpr int MF = BM / 32;    // m-frags per wave
  constexpr int ACH = BM / 32;   // A 16B-chunks per thread per K-step
  __shared__ __align__(16) char AsB[BM * 128];
  __shared__ __align__(16) char BsB[64 * 128];
  const int bm = blockIdx.x * BM, bn = blockIdx.y << 6;
  const int tid = threadIdx.x, lane = tid & 63, wid = tid >> 6;
  const int wm = (wid >> 1) * (BM / 2), wn = (wid & 1) << 5;
  const int l16 = lane & 15, g = lane >> 4;
  f32x4 acc[MF][2];
#pragma unroll
  for (int m = 0; m < MF; ++m) { acc[m][0] = (f32x4){0,0,0,0}; acc[m][1] = (f32x4){0,0,0,0}; }

  const int srow = tid >> 3;            // 0..31
  const int scolb = (tid & 7) << 4;     // 16B chunk col within 128B row
  const u16* ap = A + (size_t)(bm + srow) * K + ((tid & 7) << 3);
  const u16* bp = Bt + (size_t)(bn + srow) * K + ((tid & 7) << 3);

  // two named in-flight register sets (depth-2 pipeline; no runtime indexing)
  ushort8v paA[ACH], pbA[2], paB[ACH], pbB[2];
#pragma unroll
  for (int i = 0; i < ACH; ++i) paA[i] = *(const ushort8v*)(ap + (size_t)(i << 5) * K);
#pragma unroll
  for (int i = 0; i < 2; ++i) pbA[i] = *(const ushort8v*)(bp + (size_t)(i << 5) * K);
#pragma unroll
  for (int i = 0; i < ACH; ++i) paB[i] = *(const ushort8v*)(ap + (size_t)(i << 5) * K + 64);
#pragma unroll
  for (int i = 0; i < 2; ++i) pbB[i] = *(const ushort8v*)(bp + (size_t)(i << 5) * K + 64);

  auto gstep = [&](ushort8v (&PA)[ACH], ushort8v (&PB)[2], int S) {
#pragma unroll
    for (int i = 0; i < ACH; ++i)
      *(ushort8v*)(AsB + swz128(srow + (i << 5), scolb)) = PA[i];
#pragma unroll
    for (int i = 0; i < 2; ++i)
      *(ushort8v*)(BsB + swz128(srow + (i << 5), scolb)) = PB[i];
    __syncthreads();
    const int kf = (S + 2) << 6;
    if (kf < K) {   // issue loads for step S+2 (in flight across ~2 K-steps)
#pragma unroll
      for (int i = 0; i < ACH; ++i) PA[i] = *(const ushort8v*)(ap + (size_t)(i << 5) * K + kf);
#pragma unroll
      for (int i = 0; i < 2; ++i) PB[i] = *(const ushort8v*)(bp + (size_t)(i << 5) * K + kf);
    }
    f16x8 af[MF][2], bfr[2][2];
#pragma unroll
    for (int m = 0; m < MF; ++m)
#pragma unroll
      for (int ks = 0; ks < 2; ++ks)
        af[m][ks] = *(const f16x8*)(AsB + swz128(wm + (m << 4) + l16, ((ks << 2) + g) << 4));
#pragma unroll
    for (int n = 0; n < 2; ++n)
#pragma unroll
      for (int ks = 0; ks < 2; ++ks)
        bfr[n][ks] = *(const f16x8*)(BsB + swz128(wn + (n << 4) + l16, ((ks << 2) + g) << 4));
#pragma unroll
    for (int m = 0; m < MF; ++m)
#pragma unroll
      for (int n = 0; n < 2; ++n)
#pragma unroll
        for (int ks = 0; ks < 2; ++ks)
          acc[m][n] = __builtin_amdgcn_mfma_f32_16x16x32_f16(af[m][ks], bfr[n][ks], acc[m][n], 0, 0, 0);
    __syncthreads();
  };

  const int nsteps = K >> 6;            // always even (K = 512 or 2048)
  for (int s = 0; s < nsteps; s += 2) {
    gstep(paA, pbA, s);
    gstep(paB, pbB, s + 1);
  }

  // bucket path: preload rot^T (8KB) into regs early to hide latency
  const bool do_bucket = (STORE == 5) && (bn < 512);
  ushort8v prt0{}, prt1{};
  if (do_bucket) {
    int i0 = tid, i1 = tid + 256;               // 16B chunk ids, 512 total
    prt0 = *(const ushort8v*)(rt16 + (i0 >> 3) * 64 + ((i0 & 7) << 3));
    prt1 = *(const ushort8v*)(rt16 + (i1 >> 3) * 64 + ((i1 & 7) << 3));
  }

  // epilogue (C/D: col = lane&15 -> B rows, row = (lane>>4)*4 + reg -> A rows)
#pragma unroll
  for (int m = 0; m < MF; ++m) {
#pragma unroll
    for (int n = 0; n < 2; ++n) {
      const int gn = bn + wn + (n << 4) + l16;
      float bv = 0.f;
      if (STORE == 1 || STORE == 4) bv = bias[gn];
#pragma unroll
      for (int r = 0; r < 4; ++r) {
        const int gm = bm + wm + (m << 4) + (g << 2) + r;
        float val = acc[m][n][r];
        if (STORE == 1) {
          out[(size_t)gm * N + gn] += val + bv;
        } else if (STORE == 4) {
          out16[(size_t)gm * N + gn] = h16(gelu_exact(val + bv));
        } else {  // STORE == 5
          const float pv = __shfl_xor(val, 1);
          const int bb = gm >> 11, tt = gm & (TSEQ - 1);
          if (gn < 512) {
            const int hh = gn >> 6, dd = gn & 63;
            const int ip = dd >> 1;
            float cz = cos_t[tt * 32 + ip], sz = sin_t[tt * 32 + ip];
            float o = (dd & 1) ? (val * cz + pv * sz) : (val * cz - pv * sz);
            u16 oh = h16(o);
            qk16[((size_t)((bb * NHEAD + hh) * TSEQ + tt)) * DHD + dd] = oh;
            // stage rotated qk row into AsB for the fused bucket GEMM
            *(u16*)(AsB + swz128(gm - bm, dd << 1)) = oh;
          } else {
            const int gnn = gn - 512;
            const int hh = gnn >> 6, dd = gnn & 63;
            v16[((size_t)((bb * NHEAD + hh) * TSEQ + tt)) * DHD + dd] = h16(val);
          }
        }
      }
    }
  }

  if (do_bucket) {
    // write rot^T into BsB (swizzled), then mini-GEMM 64x64 @ 64x64 + argmax
    {
      int i0 = tid, i1 = tid + 256;
      *(ushort8v*)(BsB + swz128(i0 >> 3, (i0 & 7) << 4)) = prt0;
      *(ushort8v*)(BsB + swz128(i1 >> 3, (i1 & 7) << 4)) = prt1;
    }
    __syncthreads();
    const int bwm = (wid >> 1) << 5;    // token rows 0/32
    const int bwn = (wid & 1) << 5;     // hash cols 0/32
    f32x4 bacc[2][2];
#pragma unroll
    for (int m = 0; m < 2; ++m) { bacc[m][0] = (f32x4){0,0,0,0}; bacc[m][1] = (f32x4){0,0,0,0}; }
#pragma unroll
    for (int ks = 0; ks < 2; ++ks) {
      f16x8 bfr[2];
#pragma unroll
      for (int n = 0; n < 2; ++n)
        bfr[n] = *(const f16x8*)(BsB + swz128(bwn + (n << 4) + l16, (ks << 6) + (g << 4)));
#pragma unroll
      for (int m = 0; m < 2; ++m) {
        f16x8 afr = *(const f16x8*)(AsB + swz128(bwm + (m << 4) + l16, (ks << 6) + (g << 4)));
#pragma unroll
        for (int n = 0; n < 2; ++n)
          bacc[m][n] = __builtin_amdgcn_mfma_f32_16x16x32_f16(afr, bfr[n], bacc[m][n], 0, 0, 0);
      }
    }
    const int bb = bm >> 11;
    const int hh = bn >> 6;
#pragma unroll
    for (int m = 0; m < 2; ++m)
#pragma unroll
      for (int n = 0; n < 2; ++n) {
        const int hcol = (bwn >> 4) + n;
#pragma unroll
        for (int r = 0; r < 4; ++r) {
          float v = bacc[m][n][r];
          float best = v; int bi = l16;
          if (-v > best) { best = -v; bi = 16 + l16; }
#pragma unroll
          for (int o = 1; o < 16; o <<= 1) {
            float ob = __shfl_xor(best, o);
            int obi = __shfl_xor(bi, o);
            if (ob > best || (ob == best && obi < bi)) { best = ob; bi = obi; }
          }
          if (l16 == 0) {
            int t = (bm & (TSEQ - 1)) + bwm + (m << 4) + (g << 2) + r;
            bucket[((size_t)((bb * NHEAD + hh) * NHASHK) + hcol) * TSEQ + t] = bi;
          }
        }
      }
  }
}

// ---------------- stable counting sort per (bh,h): 32 buckets, 2048 items ----------------
__global__ __launch_bounds__(256) void k_sort(const int* __restrict__ bucket, int* __restrict__ st) {
  __shared__ int hist[256][33];
  __shared__ int chunk[8][32];
  __shared__ int bbase[32];
  const int seg = blockIdx.x;
  const int tid = threadIdx.x;
  const int* bk = bucket + (size_t)seg * TSEQ;
  int4 u0 = *(const int4*)(bk + tid * 8);
  int4 u1 = *(const int4*)(bk + tid * 8 + 4);
  int myb[8] = {u0.x, u0.y, u0.z, u0.w, u1.x, u1.y, u1.z, u1.w};
#pragma unroll
  for (int j = 0; j < 33; ++j) hist[tid][j] = 0;
  __syncthreads();
#pragma unroll
  for (int i = 0; i < 8; ++i) hist[tid][myb[i]]++;
  __syncthreads();
  // two-level exclusive scan over producers (256) per bucket (32)
  const int b = tid & 31, c = tid >> 5;
  int ssum = 0;
  for (int g2 = c * 32; g2 < c * 32 + 32; ++g2) ssum += hist[g2][b];
  chunk[c][b] = ssum;
  __syncthreads();
  if (tid < 32) {
    int run = 0;
    for (int cc = 0; cc < 8; ++cc) { int v = chunk[cc][tid]; chunk[cc][tid] = run; run += v; }
    bbase[tid] = run;
  }
  __syncthreads();
  if (tid == 0) {
    int s = 0;
    for (int j = 0; j < 32; ++j) { int v = bbase[j]; bbase[j] = s; s += v; }
  }
  __syncthreads();
  int run = chunk[c][b];
  for (int g2 = c * 32; g2 < c * 32 + 32; ++g2) { int v = hist[g2][b]; hist[g2][b] = run; run += v; }
  __syncthreads();
  int* dst = st + (size_t)seg * TSEQ;
#pragma unroll
  for (int i = 0; i < 8; ++i) {
    int bb2 = myb[i];
    int p = bbase[bb2] + hist[tid][bb2];
    hist[tid][bb2]++;
    dst[p] = tid * 8 + i;
  }
}

// ---------------- chunked LSH attention (fp16 MFMA, K + transposed-V in LDS) ----------------
__global__ __launch_bounds__(256) void k_attn(const u16* __restrict__ qk16,
                                              const u16* __restrict__ v16,
                                              const int* __restrict__ st,
                                              u16* __restrict__ o4h, float* __restrict__ lg) {
  __shared__ __align__(16) char Kb[128 * 128];        // swizzled fp16 K rows
  __shared__ __align__(16) char Vb[64 * 264 + 16];    // transposed V: Vt[d][k]
  __shared__ float inv_norm[128];
  __shared__ int tids[128];
  __shared__ float pn[256];
  const int blk = blockIdx.x;
  const int c = blk & (CHUNKS - 1), bh = blk >> 7;
  const int h = c >> 5;
  const int tid = threadIdx.x, lane = tid & 63, wid = tid >> 6;
  const int l16 = lane & 15, g = lane >> 4;

  if (tid < 128) {
    int cc = (tid < 64) ? c : ((c + CHUNKS - 1) & (CHUNKS - 1));
    tids[tid] = st[bh * (NHASHK * TSEQ) + cc * 64 + (tid & 63)];
  }
  __syncthreads();
  {
    const int r = tid >> 1, hf = tid & 1;
    const u16* qsrc = qk16 + ((size_t)bh * TSEQ + tids[r]) * 64 + hf * 32;
    const u16* vsrc = v16 + ((size_t)bh * TSEQ + tids[r]) * 64 + hf * 32;
    float ss = 0.f;
#pragma unroll
    for (int i = 0; i < 4; ++i) {
      ushort8v u = *(const ushort8v*)(qsrc + i * 8);
      *(ushort8v*)(Kb + swz128(r, hf * 64 + i * 16)) = u;
#pragma unroll
      for (int j = 0; j < 8; ++j) { float f = f16f(u[j]); ss += f * f; }
      ushort8v vv8 = *(const ushort8v*)(vsrc + i * 8);
#pragma unroll
      for (int j = 0; j < 8; ++j)
        *(u16*)(Vb + VT(hf * 32 + i * 8 + j, r)) = vv8[j];
    }
    pn[tid] = ss;
  }
  __syncthreads();
  if (tid < 128) {
    float s2 = pn[2 * tid] + pn[2 * tid + 1];
    inv_norm[tid] = 1.0f / fmaxf(sqrtf(s2), 1e-12f);
  }
  __syncthreads();

  const int qrow = (wid << 4) + l16;
  const int tq = tids[qrow];
  const size_t obase = (size_t)(bh * NHASHK + h) * TSEQ + tq;

  // S^T = K_raw · Q^T : lane holds S[k][q] for its q-column
  f32x4 accs[8];
#pragma unroll
  for (int i = 0; i < 8; ++i) accs[i] = (f32x4){0, 0, 0, 0};
#pragma unroll
  for (int s = 0; s < 2; ++s) {
    f16x8 qf = *(const f16x8*)(Kb + swz128(qrow, ((s << 2) + g) << 4));
#pragma unroll
    for (int mf = 0; mf < 8; ++mf) {
      f16x8 afr = *(const f16x8*)(Kb + swz128(mf * 16 + l16, ((s << 2) + g) << 4));
      accs[mf] = __builtin_amdgcn_mfma_f32_16x16x32_f16(afr, qf, accs[mf], 0, 0, 0);
    }
  }
  float pv[8][4];
  float mx = -3e38f;
#pragma unroll
  for (int mf = 0; mf < 8; ++mf) {
    float4 invn = *(const float4*)&inv_norm[mf * 16 + g * 4];
    int4 tk = *(const int4*)&tids[mf * 16 + g * 4];
    float inva[4] = {invn.x, invn.y, invn.z, invn.w};
    int tka[4] = {tk.x, tk.y, tk.z, tk.w};
#pragma unroll
    for (int r = 0; r < 4; ++r) {
      float d = accs[mf][r] * inva[r] * 0.125f;
      if (tka[r] == tq) d = -5e4f;
      pv[mf][r] = d;
      mx = fmaxf(mx, d);
    }
  }
  mx = fmaxf(mx, __shfl_xor(mx, 16));
  mx = fmaxf(mx, __shfl_xor(mx, 32));
  float sum = 0.f;
#pragma unroll
  for (int mf = 0; mf < 8; ++mf)
#pragma unroll
    for (int r = 0; r < 4; ++r) {
      float e = __expf(pv[mf][r] - mx);
      pv[mf][r] = e;
      sum += e;
    }
  sum += __shfl_xor(sum, 16);
  sum += __shfl_xor(sum, 32);
  float lse = __logf(sum) + mx;
  float rs = 1.0f / sum;
  if (g == 0) lg[obase] = lse;
  // pack P pairs fp16: P2[mf][m] = (p_{2m}, p_{2m+1}) for k = 16mf + 4g + {2m,2m+1}
  unsigned P2[8][2];
#pragma unroll
  for (int mf = 0; mf < 8; ++mf)
#pragma unroll
    for (int m = 0; m < 2; ++m) {
      float p0 = pv[mf][2 * m] * rs, p1 = pv[mf][2 * m + 1] * rs;
      P2[mf][m] = (unsigned)h16(p0) | ((unsigned)h16(p1) << 16);
    }
  // PV: O^T = V^T · P^T  (A = V^T from transposed LDS, B = P via shfl redistribution)
  f32x4 acco[4];
#pragma unroll
  for (int i = 0; i < 4; ++i) acco[i] = (f32x4){0, 0, 0, 0};
#pragma unroll
  for (int s = 0; s < 4; ++s) {
    unsigned bw[4];
#pragma unroll
    for (int w = 0; w < 4; ++w) {
      int srl = l16 + (((2 * g + (w >> 1)) & 3) << 4);
      unsigned a0 = __shfl(P2[2 * s][w & 1], srl);
      unsigned a1 = __shfl(P2[2 * s + 1][w & 1], srl);
      bw[w] = (g >> 1) ? a1 : a0;
    }
    f16x8 pb = mk8f(bw[0], bw[1], bw[2], bw[3]);
    const int k0 = s * 32 + g * 8;
#pragma unroll
    for (int mf = 0; mf < 4; ++mf) {
      const int dcol = mf * 16 + l16;
      uint2 v0 = *(const uint2*)(Vb + VT(dcol, k0));
      uint2 v1 = *(const uint2*)(Vb + VT(dcol, k0 + 4));
      f16x8 vf = mk8f(v0.x, v0.y, v1.x, v1.y);
      acco[mf] = __builtin_amdgcn_mfma_f32_16x16x32_f16(vf, pb, acco[mf], 0, 0, 0);
    }
  }
#pragma unroll
  for (int mf = 0; mf < 4; ++mf) {
    ushort4v o4s = {h16(acco[mf][0]), h16(acco[mf][1]), h16(acco[mf][2]), h16(acco[mf][3])};
    *(ushort4v*)&o4h[obase * 64 + mf * 16 + g * 4] = o4s;
  }
}

// ---------------- combine hash rounds -> ctx fp16 [B,T,512] ----------------
__global__ __launch_bounds__(256) void k_combine(const u16* __restrict__ o4h, const float* __restrict__ lg,
                                                 u16* __restrict__ ctx16) {
  int tok = blockIdx.x * 4 + (threadIdx.x >> 6);   // over BHD*TSEQ
  int dd = threadIdx.x & 63;
  int bh = tok >> 11, t = tok & (TSEQ - 1);
  size_t base = (size_t)bh * NHASHK * TSEQ + t;
  float l0 = lg[base], l1 = lg[base + TSEQ], l2 = lg[base + 2 * TSEQ], l3 = lg[base + 3 * TSEQ];
  float m = fmaxf(fmaxf(l0, l1), fmaxf(l2, l3));
  float e0 = expf(l0 - m), e1 = expf(l1 - m), e2 = expf(l2 - m), e3 = expf(l3 - m);
  float inv = 1.0f / (e0 + e1 + e2 + e3);
  float o = (e0 * f16f(o4h[base * 64 + dd]) + e1 * f16f(o4h[(base + TSEQ) * 64 + dd]) +
             e2 * f16f(o4h[(base + 2 * TSEQ) * 64 + dd]) + e3 * f16f(o4h[(base + 3 * TSEQ) * 64 + dd])) * inv;
  int b = bh >> 3, hh = bh & 7;
  ctx16[((size_t)(b * TSEQ + t)) * DIMM + hh * DHD + dd] = h16(o);
}

// ---------------- fused final-LN + column-mean stage 1: 512 blocks x 8 rows ----------------
__global__ __launch_bounds__(256) void k_colmean1(const float* __restrict__ x1, const float* __restrict__ x2,
                                                  float* __restrict__ part) {
  const int blk = blockIdx.x;            // bb*256 + ch
  const int bb = blk >> 8, ch = blk & 255;
  const int tid = threadIdx.x, lane = tid & 63, w = tid >> 6;
  __shared__ float red[8];
  float a0 = 0.f, a1 = 0.f;
  for (int i = 0; i < 8; ++i) {
    int row = bb * TSEQ + ch * 8 + i;
    size_t base = (size_t)row * DIMM;
    float v0 = 0.5f * (x1[base + tid] + x2[base + tid]);
    float v1 = 0.5f * (x1[base + tid + 256] + x2[base + tid + 256]);
    float s = v0 + v1;
#pragma unroll
    for (int o = 32; o; o >>= 1) s += __shfl_xor(s, o);
    if (lane == 0) red[w] = s;
    __syncthreads();
    float mu = (red[0] + red[1] + red[2] + red[3]) * (1.0f / DIMM);
    float d0 = v0 - mu, d1 = v1 - mu;
    float q = d0 * d0 + d1 * d1;
#pragma unroll
    for (int o = 32; o; o >>= 1) q += __shfl_xor(q, o);
    if (lane == 0) red[4 + w] = q;
    __syncthreads();
    float var = (red[4] + red[5] + red[6] + red[7]) * (1.0f / DIMM);
    float rstd = 1.0f / sqrtf(var + 1e-5f);
    a0 += d0 * rstd;
    a1 += d1 * rstd;
    __syncthreads();
  }
  part[(size_t)blk * DIMM + tid] = a0;
  part[(size_t)blk * DIMM + tid + 256] = a1;
}

__global__ __launch_bounds__(256) void k_colmean2(const float* __restrict__ part,
                                                  const float* __restrict__ g, const float* __restrict__ b,
                                                  float* __restrict__ hm) {
  int gidx = blockIdx.x * 256 + threadIdx.x;   // 8192 = 1024 outputs x 8
  int oid = gidx >> 3, sub = gidx & 7;
  int bb = oid >> 9, d = oid & 511;
  float s = 0.f;
  for (int c = sub; c < 256; c += 8) s += part[((size_t)(bb * 256 + c)) * DIMM + d];
  s += __shfl_xor(s, 1);
  s += __shfl_xor(s, 2);
  s += __shfl_xor(s, 4);
  if (sub == 0) hm[oid] = s * (1.0f / TSEQ) * g[d] + b[d];
}

// ---------------- head (split-K head1 + reducing head2) ----------------
__global__ __launch_bounds__(256) void k_head1(const float* __restrict__ hm, const float* __restrict__ Wf1,
                                               float* __restrict__ r1p) {
  int b = blockIdx.x & 1, kc = blockIdx.x >> 1;   // 16 blocks: 2 batch x 8 k-chunks
  int j = threadIdx.x;
  float acc = 0;
  for (int k = kc * 64; k < kc * 64 + 64; ++k) acc += hm[b * DIMM + k] * Wf1[k * 256 + j];
  r1p[(size_t)(kc * 2 + b) * 256 + j] = acc;
}

__global__ __launch_bounds__(256) void k_head2(const float* __restrict__ r1p, const float* __restrict__ bf1,
                                               const float* __restrict__ Wout, const float* __restrict__ bout,
                                               float* __restrict__ outp) {
  int b = blockIdx.x;
  int tid = threadIdx.x, lane = tid & 63, w = tid >> 6;
  float s = 0.f;
#pragma unroll
  for (int kc = 0; kc < 8; ++kc) s += r1p[(size_t)(kc * 2 + b) * 256 + tid];
  float v = fmaxf(s + bf1[tid], 0.0f) * Wout[tid];
#pragma unroll
  for (int o = 32; o; o >>= 1) v += __shfl_xor(v, o);
  __shared__ float red[4];
  if (lane == 0) red[w] = v;
  __syncthreads();
  if (tid == 0) outp[b] = red[0] + red[1] + red[2] + red[3] + bout[0];
}

extern "C" void kernel_launch(void* const* d_in, const int* in_sizes, int n_in,
                              void* d_out, int out_size, void* d_ws, size_t ws_size,
                              hipStream_t stream) {
  const int*   x         = (const int*)d_in[0];
  const float* token_emb = (const float*)d_in[1];
  const float* ln1_s     = (const float*)d_in[2];
  const float* ln1_b     = (const float*)d_in[3];
  const float* Wqk       = (const float*)d_in[4];
  const float* Wv        = (const float*)d_in[5];
  const float* Wo        = (const float*)d_in[6];
  const float* bo        = (const float*)d_in[7];
  const float* ln2_s     = (const float*)d_in[8];
  const float* ln2_b     = (const float*)d_in[9];
  const float* W1        = (const float*)d_in[10];
  const float* b1        = (const float*)d_in[11];
  const float* W2        = (const float*)d_in[12];
  const float* b2        = (const float*)d_in[13];
  const float* rotations = (const float*)d_in[14];
  const float* lnf_s     = (const float*)d_in[15];
  const float* lnf_b     = (const float*)d_in[16];
  const float* Wf1       = (const float*)d_in[17];
  const float* bf1       = (const float*)d_in[18];
  const float* Wout      = (const float*)d_in[19];
  const float* bout      = (const float*)d_in[20];
  float* out = (float*)d_out;

  char* ws = (char*)d_ws;
  size_t off = 0;
  auto alloc = [&](size_t nbytes) {
    char* p = ws + off;
    off += (nbytes + 255) & ~(size_t)255;
    return p;
  };
  float*  x1     = (float*)alloc((size_t)NROWS * DIMM * 4);
  float*  x2     = (float*)alloc((size_t)NROWS * DIMM * 4);
  u16*    xn16   = (u16*)alloc((size_t)NROWS * DIMM * 2);
  u16*    qk16   = (u16*)alloc((size_t)BHD * TSEQ * DHD * 2);
  u16*    v16    = (u16*)alloc((size_t)BHD * TSEQ * DHD * 2);
  u16*    ffh16  = (u16*)alloc((size_t)NROWS * FFD * 2);
  u16*    o4h    = (u16*)alloc((size_t)BHD * NHASHK * TSEQ * DHD * 2);
  float*  lg     = (float*)alloc((size_t)BHD * NHASHK * TSEQ * 4);
  float*  sin_t  = (float*)alloc((size_t)TSEQ * 32 * 4);
  float*  cos_t  = (float*)alloc((size_t)TSEQ * 32 * 4);
  float*  part   = (float*)alloc((size_t)512 * DIMM * 4);
  float*  hm     = (float*)alloc(2 * DIMM * 4);
  float*  r1p    = (float*)alloc(16 * 256 * 4);
  int*    bucket = (int*)alloc((size_t)BHD * NHASHK * TSEQ * 4);
  int*    st     = (int*)alloc((size_t)BHD * NHASHK * TSEQ * 4);
  u16*    wt16   = (u16*)alloc((size_t)4 * WT_TOT * 2);
  u16*    rott16 = (u16*)alloc((size_t)4 * 64 * 64 * 2);
  u16*    ctx16  = xn16;   // alias: lifetimes disjoint

  k_embed<<<NROWS, 128, 0, stream>>>(x, token_emb, x1, x2);
  k_sincos<<<(TSEQ * 32) / 256, 256, 0, stream>>>(sin_t, cos_t);
  k_prep<<<4 * 2820, 256, 0, stream>>>(Wqk, Wv, Wo, W1, W2, rotations, wt16, rott16);

  for (int L = 0; L < 4; ++L) {
    u16* wt = wt16 + (size_t)L * WT_TOT;
    u16* rt = rott16 + (size_t)L * 4096;

    k_layernorm<<<NROWS, 256, 0, stream>>>(x2, ln1_s + L * DIMM, ln1_b + L * DIMM, xn16);
    // fused QK+V GEMM (+LSH bucket in qk-half epilogues): B = [Wqk^T ; Wv^T]
    k_gemm16<64, 5><<<dim3(64, 16), 256, 0, stream>>>(
        xn16, wt + OFF_WQK, nullptr, nullptr, nullptr, qk16, v16, 512, 1024, sin_t, cos_t, rt, bucket);
    k_sort<<<BHD * NHASHK, 256, 0, stream>>>(bucket, st);
    k_attn<<<BHD * CHUNKS, 256, 0, stream>>>(qk16, v16, st, o4h, lg);
    k_combine<<<(BHD * TSEQ) / 4, 256, 0, stream>>>(o4h, lg, ctx16);
    k_gemm16<64, 1><<<dim3(64, 8), 256, 0, stream>>>(
        ctx16, wt + OFF_WO, bo + L * DIMM, x1, nullptr, nullptr, nullptr, 512, 512, nullptr, nullptr, nullptr, nullptr);
    k_layernorm<<<NROWS, 256, 0, stream>>>(x1, ln2_s + L * DIMM, ln2_b + L * DIMM, xn16);
    k_gemm16<64, 4><<<dim3(64, 32), 256, 0, stream>>>(
        xn16, wt + OFF_W1, b1 + L * FFD, nullptr, ffh16, nullptr, nullptr, 512, 2048, nullptr, nullptr, nullptr, nullptr);
    k_gemm16<64, 1><<<dim3(64, 8), 256, 0, stream>>>(
        ffh16, wt + OFF_W2, b2 + L * DIMM, x2, nullptr, nullptr, nullptr, 2048, 512, nullptr, nullptr, nullptr, nullptr);
  }

  k_colmean1<<<512, 256, 0, stream>>>(x1, x2, part);
  k_colmean2<<<32, 256, 0, stream>>>(part, lnf_s, lnf_b, hm);
  k_head1<<<16, 256, 0, stream>>>(hm, Wf1, r1p);
  k_head2<<<2, 256, 0, stream>>>(r1p, bf1, Wout, bout, out);
}